// Round 6
// baseline (2301.132 us; speedup 1.0000x reference)
//
#include <hip/hip_runtime.h>
#include <hip/hip_bf16.h>

#define NN  50000
#define EE  320000
#define E2  (EE + NN)
#define DIN 128
#define DD  256

typedef __attribute__((ext_vector_type(8))) short          bf16x8;
typedef __attribute__((ext_vector_type(8))) unsigned short u16x8;
typedef __attribute__((ext_vector_type(4))) float          f32x4;

// ---------------- helpers ----------------

static __device__ __forceinline__ float bf2f(unsigned short u) {
  return __builtin_bit_cast(float, (unsigned)u << 16);
}

static __device__ __forceinline__ unsigned short f2bf(float f) {
  unsigned u = __builtin_bit_cast(unsigned, f);
  return (unsigned short)((u + 0x7fffu + ((u >> 16) & 1u)) >> 16);
}

static __device__ __forceinline__ void load_lds16(const void* g, void* l) {
  __builtin_amdgcn_global_load_lds(
      (const __attribute__((address_space(1))) void*)g,
      (__attribute__((address_space(3))) void*)l, 16, 0, 0);
}

// ---------------- weight/activation cast fp32 -> bf16 ----------------

__global__ void k_cast(const float* __restrict__ in, unsigned short* __restrict__ out, int n) {
  int i = blockIdx.x * blockDim.x + threadIdx.x;
  if (i >= n) return;
  out[i] = f2bf(in[i]);
}

// ---------------- CSR build ----------------

__global__ void k_deg(const int* __restrict__ ei, int* __restrict__ deg) {
  int i = blockIdx.x * blockDim.x + threadIdx.x;
  if (i >= E2) return;
  int dst = (i < EE) ? ei[EE + i] : (i - EE);
  atomicAdd(&deg[dst], 1);
}

__global__ __launch_bounds__(1024) void k_scan_tile(const int* __restrict__ in,
                                                    int* __restrict__ out,
                                                    int* __restrict__ tsum, int n) {
  __shared__ int sm[1024];
  int tid = threadIdx.x;
  int g = blockIdx.x * 1024 + tid;
  sm[tid] = (g < n) ? in[g] : 0;
  __syncthreads();
  for (int off = 1; off < 1024; off <<= 1) {
    int t = (tid >= off) ? sm[tid - off] : 0;
    __syncthreads();
    sm[tid] += t;
    __syncthreads();
  }
  if (g < n) out[g] = sm[tid];
  if (tid == 1023) tsum[blockIdx.x] = sm[1023];
}

__global__ void k_scan_sums(int* __restrict__ tsum, int nb) {
  int tid = threadIdx.x;           // single wave of 64, nb <= 64
  int v = (tid < nb) ? tsum[tid] : 0;
  for (int off = 1; off < 64; off <<= 1) {
    int t = __shfl_up(v, off);
    if (tid >= off) v += t;
  }
  if (tid < nb) tsum[tid] = v;
}

__global__ void k_scan_add(int* __restrict__ out, const int* __restrict__ tsum, int n) {
  int g = blockIdx.x * blockDim.x + threadIdx.x;
  if (g >= n || g < 1024) return;
  out[g] += tsum[(g >> 10) - 1];
}

__global__ void k_scatter(const int* __restrict__ ei, const int* __restrict__ deg,
                          const int* __restrict__ inc, int* __restrict__ cur,
                          int* __restrict__ ssrc) {
  int i = blockIdx.x * blockDim.x + threadIdx.x;
  if (i >= E2) return;
  int src, dst;
  if (i < EE) { src = ei[i]; dst = ei[EE + i]; } else { src = dst = i - EE; }
  int pos = atomicAdd(&cur[dst], 1);
  ssrc[inc[dst] - deg[dst] + pos] = src;
}

// ---------------- GAT pieces (h in bf16) ----------------

__global__ __launch_bounds__(256) void k_dots(const unsigned short* __restrict__ hb,
                                              const float* __restrict__ asrc,
                                              const float* __restrict__ adst,
                                              float* __restrict__ hs, float* __restrict__ hd) {
  int node = blockIdx.x * 4 + (threadIdx.x >> 6);
  if (node >= NN) return;
  int lane = threadIdx.x & 63;
  ushort4 hv = *reinterpret_cast<const ushort4*>(hb + (size_t)node * DD + lane * 4);
  float v0 = bf2f(hv.x), v1 = bf2f(hv.y), v2 = bf2f(hv.z), v3 = bf2f(hv.w);
  const float* as = asrc + lane * 4;
  const float* ad = adst + lane * 4;
  float s1 = v0 * as[0] + v1 * as[1] + v2 * as[2] + v3 * as[3];
  float s2 = v0 * ad[0] + v1 * ad[1] + v2 * ad[2] + v3 * ad[3];
  for (int off = 32; off; off >>= 1) {
    s1 += __shfl_xor(s1, off);
    s2 += __shfl_xor(s2, off);
  }
  if (lane == 0) { hs[node] = s1; hd[node] = s2; }
}

// Fused edge-softmax + aggregation: one wave per dst node.
__global__ __launch_bounds__(256) void k_gat(const unsigned short* __restrict__ hb,
                                             const int* __restrict__ ssrc,
                                             const int* __restrict__ deg,
                                             const int* __restrict__ inc,
                                             const float* __restrict__ hs,
                                             const float* __restrict__ hd,
                                             const float* __restrict__ bias,
                                             unsigned short* __restrict__ out) {
  __shared__ float sE[4][256];
  __shared__ int   sI[4][256];
  int w = threadIdx.x >> 6;
  int d = blockIdx.x * 4 + w;
  if (d >= NN) return;
  int lane = threadIdx.x & 63;
  int end = inc[d], cnt = deg[d], base = end - cnt;
  if (cnt > 256) cnt = 256;
  float hdd = hd[d];

  float m = -1e30f;
  for (int i0 = 0; i0 < cnt; i0 += 64) {
    int i = i0 + lane;
    float sc = -1e30f;
    if (i < cnt) {
      int s = ssrc[base + i];
      float v = hs[s] + hdd;
      sc = (v < 0.f) ? 0.2f * v : v;
      sI[w][i] = s;
      sE[w][i] = sc;
    }
    float mm = sc;
    for (int o = 32; o; o >>= 1) mm = fmaxf(mm, __shfl_xor(mm, o));
    m = fmaxf(m, mm);
  }
  float sum = 0.f;
  for (int i0 = 0; i0 < cnt; i0 += 64) {
    int i = i0 + lane;
    float e = 0.f;
    if (i < cnt) {
      e = __expf(sE[w][i] - m);
      sE[w][i] = e;
    }
    for (int o = 32; o; o >>= 1) e += __shfl_xor(e, o);
    sum += e;
  }
  float inv = 1.f / sum;

  float a0 = 0.f, a1 = 0.f, a2 = 0.f, a3 = 0.f;
  for (int i = 0; i < cnt; ++i) {
    float a = sE[w][i];
    int s = sI[w][i];
    ushort4 hv = *reinterpret_cast<const ushort4*>(hb + (size_t)s * DD + lane * 4);
    a0 += a * bf2f(hv.x);
    a1 += a * bf2f(hv.y);
    a2 += a * bf2f(hv.z);
    a3 += a * bf2f(hv.w);
  }
  const float* bp = bias + lane * 4;
  float r0 = a0 * inv + bp[0], r1 = a1 * inv + bp[1];
  float r2 = a2 * inv + bp[2], r3 = a3 * inv + bp[3];
  ushort4 o;
  o.x = f2bf(r0 > 0.f ? r0 : 0.f);
  o.y = f2bf(r1 > 0.f ? r1 : 0.f);
  o.z = f2bf(r2 > 0.f ? r2 : 0.f);
  o.w = f2bf(r3 > 0.f ? r3 : 0.f);
  *reinterpret_cast<ushort4*>(out + (size_t)d * DD + lane * 4) = o;
}

// LDS k-chunk swizzle (bank-conflict-free fragment reads):
// LDS slot (row, c) holds global k-chunk  c ^ ((row>>1)&3)  within each 32-k group.
// Fragment read of logical chunk q at row (16-aligned base + m_lane):
//   position = q ^ ((m_lane>>1)&3).
// Row stride MUST be 64 B ([*][32 shorts]) for conflict-free b128 reads.

// ---------------- LDS-staged bf16 MFMA GEMM, XCD-swizzled grid ----------------
// C = act(A @ B^T + bias);  A bf16 [M x K] lda, B bf16 [N x K], C bf16 [M x ldc].
// 128x128 tile, BK=32, 4 waves, double-buffered staging.

__global__ __launch_bounds__(256) void k_gemm128(
    const unsigned short* __restrict__ A, int lda,
    const unsigned short* __restrict__ B,
    const float* __restrict__ bias,
    unsigned short* __restrict__ C, int ldc,
    int M, int N, int K, int act) {
  __shared__ unsigned short As[2][128 * 32];
  __shared__ unsigned short Bs[2][128 * 32];

  const int id  = blockIdx.y * gridDim.x + blockIdx.x;
  const int nn  = gridDim.x;
  const int sid = id >> 3;
  const int jn  = sid % nn;
  const int im  = (id & 7) + ((sid / nn) << 3);
  if (im >= ((M + 127) >> 7)) return;
  const int m0 = im * 128;
  const int n0 = jn * 128;

  const int tid    = threadIdx.x;
  const int lane   = tid & 63;
  const int w      = tid >> 6;
  const int m_lane = lane & 15;
  const int quad   = lane >> 4;
  const int wm     = (w >> 1) * 64;
  const int wn     = (w & 1) * 64;

  const int idx0 = tid, idx1 = 256 + tid;
  const int kc = (((tid & 3) ^ ((tid >> 3) & 3))) * 8;   // same for idx0/idx1
  int rowA0 = m0 + (idx0 >> 2); if (rowA0 >= M) rowA0 = M - 1;
  int rowA1 = m0 + (idx1 >> 2); if (rowA1 >= M) rowA1 = M - 1;
  const unsigned short* gA0 = A + (size_t)rowA0 * lda + kc;
  const unsigned short* gA1 = A + (size_t)rowA1 * lda + kc;
  const unsigned short* gB0 = B + (size_t)(n0 + (idx0 >> 2)) * K + kc;
  const unsigned short* gB1 = B + (size_t)(n0 + (idx1 >> 2)) * K + kc;

  const int la0 = (w * 64) * 8;          // LDS slot offsets (shorts)
  const int la1 = (256 + w * 64) * 8;

  const int swz = (quad ^ ((m_lane >> 1) & 3)) * 8;

  f32x4 acc[4][4] = {};

  const int nk = K >> 5;

  // prologue: stage k-tile 0 into buffer 0
  load_lds16(gA0, &As[0][la0]);
  load_lds16(gA1, &As[0][la1]);
  load_lds16(gB0, &Bs[0][la0]);
  load_lds16(gB1, &Bs[0][la1]);
  gA0 += 32; gA1 += 32; gB0 += 32; gB1 += 32;
  __syncthreads();

  int cur = 0;
  for (int t = 0; t < nk; ++t) {
    if (t + 1 < nk) {   // issue next-tile stage BEFORE compute of current tile
      load_lds16(gA0, &As[cur ^ 1][la0]);
      load_lds16(gA1, &As[cur ^ 1][la1]);
      load_lds16(gB0, &Bs[cur ^ 1][la0]);
      load_lds16(gB1, &Bs[cur ^ 1][la1]);
      gA0 += 32; gA1 += 32; gB0 += 32; gB1 += 32;
    }
    bf16x8 af[4], bg[4];
#pragma unroll
    for (int i = 0; i < 4; ++i)
      af[i] = *reinterpret_cast<const bf16x8*>(&As[cur][(wm + i * 16 + m_lane) * 32 + swz]);
#pragma unroll
    for (int j = 0; j < 4; ++j)
      bg[j] = *reinterpret_cast<const bf16x8*>(&Bs[cur][(wn + j * 16 + m_lane) * 32 + swz]);
#pragma unroll
    for (int i = 0; i < 4; ++i)
#pragma unroll
      for (int j = 0; j < 4; ++j)
        acc[i][j] = __builtin_amdgcn_mfma_f32_16x16x32_bf16(af[i], bg[j], acc[i][j], 0, 0, 0);
    __syncthreads();   // drains this iter's stage (vmcnt) after MFMA work hid it
    cur ^= 1;
  }

#pragma unroll
  for (int i = 0; i < 4; ++i) {
#pragma unroll
    for (int j = 0; j < 4; ++j) {
      int col = n0 + wn + j * 16 + m_lane;
      float bv = bias ? bias[col] : 0.f;
#pragma unroll
      for (int r = 0; r < 4; ++r) {
        int row = m0 + wm + i * 16 + quad * 4 + r;
        if (row < M) {
          float v = acc[i][j][r] + bv;
          if (act) v = v > 0.f ? v : 0.f;
          C[(size_t)row * ldc + col] = f2bf(v);
        }
      }
    }
  }
}

// ---------------- fused GEMM(+bias+residual)+LayerNorm, N=256 exactly ----------------
// 64-row blocks, 4 waves each owning a 32x128 sub-tile. Double-buffered staging.

__global__ __launch_bounds__(256) void k_gemm_ln(
    const unsigned short* __restrict__ A, int lda,
    const unsigned short* __restrict__ B,           // [256 x K]
    const float* __restrict__ bias,                 // [256]
    const unsigned short* __restrict__ R, int ldr,  // residual bf16 [M x ldr]
    const float* __restrict__ gam, const float* __restrict__ bet,
    unsigned short* __restrict__ C, int ldc,
    int M, int K) {
  __shared__ unsigned short As[2][64 * 32];     // 8 KB
  __shared__ unsigned short Bs[2][256 * 32];    // 32 KB
  __shared__ float sSum[2][64];
  __shared__ float sSq[2][64];

  const int tid  = threadIdx.x;
  const int lane = tid & 63;
  const int w    = tid >> 6;
  const int ml   = lane & 15;
  const int quad = lane >> 4;
  const int m0   = blockIdx.x * 64;
  const int rb   = (w & 1) * 32;     // wave row base within tile
  const int cb   = (w >> 1) * 128;   // wave col base

  int arow = m0 + (tid >> 2); if (arow >= M) arow = M - 1;
  const int kcs = ((tid & 3) ^ ((tid >> 3) & 3)) * 8;
  const unsigned short* gA  = A + (size_t)arow * lda + kcs;
  const unsigned short* gB0 = B + (size_t)((0 * 256 + tid) >> 2) * K + kcs;
  const unsigned short* gB1 = B + (size_t)((1 * 256 + tid) >> 2) * K + kcs;
  const unsigned short* gB2 = B + (size_t)((2 * 256 + tid) >> 2) * K + kcs;
  const unsigned short* gB3 = B + (size_t)((3 * 256 + tid) >> 2) * K + kcs;

  const int laA = (w * 64) * 8;
  const int lb0 = (0 * 256 + w * 64) * 8;
  const int lb1 = (1 * 256 + w * 64) * 8;
  const int lb2 = (2 * 256 + w * 64) * 8;
  const int lb3 = (3 * 256 + w * 64) * 8;

  const int swz = (quad ^ ((ml >> 1) & 3)) * 8;

  f32x4 acc[2][8] = {};

  const int nk = K >> 5;

  // prologue
  load_lds16(gA,  &As[0][laA]);
  load_lds16(gB0, &Bs[0][lb0]);
  load_lds16(gB1, &Bs[0][lb1]);
  load_lds16(gB2, &Bs[0][lb2]);
  load_lds16(gB3, &Bs[0][lb3]);
  gA += 32; gB0 += 32; gB1 += 32; gB2 += 32; gB3 += 32;
  __syncthreads();

  int cur = 0;
  for (int t = 0; t < nk; ++t) {
    if (t + 1 < nk) {
      load_lds16(gA,  &As[cur ^ 1][laA]);
      load_lds16(gB0, &Bs[cur ^ 1][lb0]);
      load_lds16(gB1, &Bs[cur ^ 1][lb1]);
      load_lds16(gB2, &Bs[cur ^ 1][lb2]);
      load_lds16(gB3, &Bs[cur ^ 1][lb3]);
      gA += 32; gB0 += 32; gB1 += 32; gB2 += 32; gB3 += 32;
    }
    bf16x8 af[2], bg[8];
#pragma unroll
    for (int i = 0; i < 2; ++i)
      af[i] = *reinterpret_cast<const bf16x8*>(&As[cur][(rb + i * 16 + ml) * 32 + swz]);
#pragma unroll
    for (int j = 0; j < 8; ++j)
      bg[j] = *reinterpret_cast<const bf16x8*>(&Bs[cur][(cb + j * 16 + ml) * 32 + swz]);
#pragma unroll
    for (int i = 0; i < 2; ++i)
#pragma unroll
      for (int j = 0; j < 8; ++j)
        acc[i][j] = __builtin_amdgcn_mfma_f32_16x16x32_bf16(af[i], bg[j], acc[i][j], 0, 0, 0);
    __syncthreads();
    cur ^= 1;
  }

  // bias + residual; per-row partial stats over this wave's 128 cols
#pragma unroll
  for (int i = 0; i < 2; ++i)
#pragma unroll
    for (int r = 0; r < 4; ++r) {
      int rw = rb + i * 16 + quad * 4 + r;
      int row = m0 + rw;
      int rr2 = row < M ? row : M - 1;
      float s = 0.f, s2 = 0.f;
#pragma unroll
      for (int j = 0; j < 8; ++j) {
        int col = cb + j * 16 + ml;
        float t = acc[i][j][r] + bias[col] + bf2f(R[(size_t)rr2 * ldr + col]);
        acc[i][j][r] = t;
        s += t; s2 += t * t;
      }
#pragma unroll
      for (int o = 1; o < 16; o <<= 1) {
        s  += __shfl_xor(s, o);
        s2 += __shfl_xor(s2, o);
      }
      if (ml == 0) { sSum[w >> 1][rw] = s; sSq[w >> 1][rw] = s2; }
    }
  __syncthreads();

#pragma unroll
  for (int i = 0; i < 2; ++i)
#pragma unroll
    for (int r = 0; r < 4; ++r) {
      int rw = rb + i * 16 + quad * 4 + r;
      int row = m0 + rw;
      if (row >= M) continue;
      float s  = sSum[0][rw] + sSum[1][rw];
      float s2 = sSq[0][rw]  + sSq[1][rw];
      float mean = s * (1.f / 256.f);
      float var  = s2 * (1.f / 256.f) - mean * mean;
      float inv  = rsqrtf(var + 1e-5f);
#pragma unroll
      for (int j = 0; j < 8; ++j) {
        int col = cb + j * 16 + ml;
        C[(size_t)row * ldc + col] = f2bf((acc[i][j][r] - mean) * inv * gam[col] + bet[col]);
      }
    }
}

// ---------------- fused FFN: relu(A@W1^T+b1)@W2^T + b2 + residual(A) + LN ----------
// A = seqc [M x 256] bf16, in-place. W1 [1024 x 256], W2 [256 x 1024] bf16.
// 128-ROW blocks, 8 waves (512 thr), 128 KB LDS (gfx950 allows 160 KB/WG),
// 1 block/CU. Halves block count (W re-read traffic 600->300 MB/dispatch) and
// doubles MFMA per barrier phase vs the 64-row version (which was phase-bound:
// occupancy 15->31% gave exactly 0 delta). K-grouped [8 grp][128 row][32] LDS.

__global__ __launch_bounds__(512, 2) void k_ff(
    unsigned short* __restrict__ A,
    const unsigned short* __restrict__ W1,
    const float* __restrict__ b1,
    const unsigned short* __restrict__ W2,
    const float* __restrict__ b2,
    const float* __restrict__ gam, const float* __restrict__ bet,
    int M) {
  __shared__ unsigned short As[8 * 128 * 32];   // 64 KB  [kgrp][row][32]
  __shared__ unsigned short Hs[8 * 128 * 32];   // 64 KB  (reused as LN scratch)

  const int tid  = threadIdx.x;
  const int lane = tid & 63;
  const int w    = tid >> 6;        // 0..7
  const int ml   = lane & 15;
  const int quad = lane >> 4;
  const int m0   = blockIdx.x * 128;
  const int swz  = (quad ^ ((ml >> 1) & 3)) << 3;

  // ---- stage A tile 128x256: thread tid -> row tid>>2, chunk tid&3, 8 kgroups
  {
    int rg = m0 + (tid >> 2); if (rg >= M) rg = M - 1;
    int cs = (tid & 3) ^ ((tid >> 3) & 3);
    const unsigned short* gsrc = A + (size_t)rg * 256 + (cs << 3);
    unsigned short* ldst = As + (size_t)(w * 64) * 8;   // w*512 shorts; HW adds lane*16B
#pragma unroll
    for (int g = 0; g < 8; ++g)
      load_lds16(gsrc + (g << 5), ldst + (size_t)g * 4096);
  }
  __syncthreads();

  f32x4 acc2[8][2] = {};

  for (int kb = 0; kb < 4; ++kb) {
    // ---- GEMM1: wave w computes H^T for hidden rows kb*256 + w*32 .. +31
    //      over all 128 seq rows (8 j-frags)
    f32x4 acc1[2][8] = {};
    const unsigned short* W1p = W1 + (size_t)(kb * 256 + w * 32 + ml) * 256 + quad * 8;
#pragma unroll 2
    for (int ks = 0; ks < 8; ++ks) {
      bf16x8 af[2], bg[8];
#pragma unroll
      for (int i = 0; i < 2; ++i)
        af[i] = *reinterpret_cast<const bf16x8*>(W1p + (size_t)i * 16 * 256 + ks * 32);
#pragma unroll
      for (int j = 0; j < 8; ++j)
        bg[j] = *reinterpret_cast<const bf16x8*>(&As[ks * 4096 + (j * 16 + ml) * 32 + swz]);
#pragma unroll
      for (int i = 0; i < 2; ++i)
#pragma unroll
        for (int j = 0; j < 8; ++j)
          acc1[i][j] = __builtin_amdgcn_mfma_f32_16x16x32_bf16(af[i], bg[j], acc1[i][j], 0, 0, 0);
    }

    __syncthreads();   // previous GEMM2 readers of Hs are done

    // ---- relu(acc1 + b1) -> Hs: wave w owns h-group w (hidden w*32..+31)
#pragma unroll
    for (int i = 0; i < 2; ++i) {
      float4 bv = *reinterpret_cast<const float4*>(b1 + kb * 256 + w * 32 + i * 16 + quad * 4);
      int c  = i * 2 + (quad >> 1);
      int lo = (quad & 1) * 4;
#pragma unroll
      for (int j = 0; j < 8; ++j) {
        int seqrow = j * 16 + ml;
        int chsw = c ^ ((ml >> 1) & 3);
        int addr = w * 4096 + seqrow * 32 + (chsw << 3) + lo;
        float t0 = acc1[i][j][0] + bv.x; t0 = t0 > 0.f ? t0 : 0.f;
        float t1 = acc1[i][j][1] + bv.y; t1 = t1 > 0.f ? t1 : 0.f;
        float t2 = acc1[i][j][2] + bv.z; t2 = t2 > 0.f ? t2 : 0.f;
        float t3 = acc1[i][j][3] + bv.w; t3 = t3 > 0.f ? t3 : 0.f;
        ushort4 hv;
        hv.x = f2bf(t0); hv.y = f2bf(t1); hv.z = f2bf(t2); hv.w = f2bf(t3);
        *reinterpret_cast<ushort4*>(&Hs[addr]) = hv;
      }
    }
    __syncthreads();   // Hs visible to all waves

    // ---- GEMM2: acc2 += H @ W2slice^T; wave w owns out-cols w*32..+31,
    //      all 128 rows (8 i-frags)
    const unsigned short* W2p = W2 + (size_t)(w * 32 + ml) * 1024 + kb * 256 + quad * 8;
#pragma unroll 2
    for (int ks = 0; ks < 8; ++ks) {
      bf16x8 af[8], bg[2];
#pragma unroll
      for (int i = 0; i < 8; ++i)
        af[i] = *reinterpret_cast<const bf16x8*>(&Hs[ks * 4096 + (i * 16 + ml) * 32 + swz]);
#pragma unroll
      for (int j = 0; j < 2; ++j)
        bg[j] = *reinterpret_cast<const bf16x8*>(W2p + (size_t)j * 16 * 1024 + ks * 32);
#pragma unroll
      for (int i = 0; i < 8; ++i)
#pragma unroll
        for (int j = 0; j < 2; ++j)
          acc2[i][j] = __builtin_amdgcn_mfma_f32_16x16x32_bf16(af[i], bg[j], acc2[i][j], 0, 0, 0);
    }
  }

  __syncthreads();   // all Hs reads done -> reuse Hs as LN scratch
  float* sS = reinterpret_cast<float*>(Hs);   // [8][128]
  float* sQ = sS + 1024;                       // [8][128]

  float b2v[2], gv[2], btv[2];
#pragma unroll
  for (int j = 0; j < 2; ++j) {
    int col = w * 32 + j * 16 + ml;
    b2v[j] = b2[col]; gv[j] = gam[col]; btv[j] = bet[col];
  }

  // bias + residual (from As LDS) + per-row partial stats over this wave's 32 cols
#pragma unroll
  for (int i = 0; i < 8; ++i)
#pragma unroll
    for (int r = 0; r < 4; ++r) {
      int row = i * 16 + quad * 4 + r;
      float s = 0.f, s2 = 0.f;
#pragma unroll
      for (int j = 0; j < 2; ++j) {
        int c_r = j * 2 + (ml >> 3);
        float t = acc2[i][j][r] + b2v[j] +
                  bf2f(As[w * 4096 + row * 32 + ((c_r ^ ((row >> 1) & 3)) << 3) + (ml & 7)]);
        acc2[i][j][r] = t;
        s += t; s2 += t * t;
      }
#pragma unroll
      for (int o = 1; o < 16; o <<= 1) { s += __shfl_xor(s, o); s2 += __shfl_xor(s2, o); }
      if (ml == 0) { sS[w * 128 + row] = s; sQ[w * 128 + row] = s2; }
    }
  __syncthreads();

#pragma unroll
  for (int i = 0; i < 8; ++i)
#pragma unroll
    for (int r = 0; r < 4; ++r) {
      int row = i * 16 + quad * 4 + r;
      int rg = m0 + row;
      if (rg >= M) continue;
      float s = 0.f, s2 = 0.f;
#pragma unroll
      for (int ww = 0; ww < 8; ++ww) { s += sS[ww * 128 + row]; s2 += sQ[ww * 128 + row]; }
      float mean = s * (1.f / 256.f);
      float var  = s2 * (1.f / 256.f) - mean * mean;
      float inv  = rsqrtf(var + 1e-5f);
#pragma unroll
      for (int j = 0; j < 2; ++j) {
        int col = w * 32 + j * 16 + ml;
        A[(size_t)rg * 256 + col] = f2bf((acc2[i][j][r] - mean) * inv * gv[j] + btv[j]);
      }
    }
}

// ---------------- transformer pieces (bf16 activations, dense layouts) ----------------

__global__ void k_seqbuild(const unsigned short* __restrict__ x1,
                           const unsigned short* __restrict__ x2,
                           const float* __restrict__ cls, const float* __restrict__ pos,
                           unsigned short* __restrict__ seqc, int n0, int cn) {
  int idx = blockIdx.x * blockDim.x + threadIdx.x;
  int total = cn * 3 * DD;
  if (idx >= total) return;
  int c = idx & (DD - 1);
  int r = idx >> 8;
  int t = r % 3, ln = r / 3;
  int n = n0 + ln;
  float v;
  if (t == 0)      v = cls[c];
  else if (t == 1) v = bf2f(x1[(size_t)n * DD + c]);
  else             v = bf2f(x2[(size_t)n * DD + c]);
  seqc[idx] = f2bf(v + pos[t * DD + c]);
}

// qkv: [3 rows x 768] per node; attention output overwrites the q slot in place.
__global__ __launch_bounds__(256) void k_attn(unsigned short* __restrict__ qkvb) {
  __shared__ float qkv[3][768];
  __shared__ float lg[4][3][3];
  __shared__ float aw[4][3][3];
  int tid = threadIdx.x;
  size_t r0 = (size_t)blockIdx.x * 3;
  const unsigned short* src = qkvb + r0 * 768;
  float* qf = &qkv[0][0];
  for (int i = tid; i < 288; i += 256) {         // 2304 shorts = 288 x ushort8
    u16x8 v = *reinterpret_cast<const u16x8*>(src + (size_t)i * 8);
#pragma unroll
    for (int j = 0; j < 8; ++j) qf[i * 8 + j] = bf2f(v[j]);
  }
  __syncthreads();
  int h = tid >> 6, lane = tid & 63;
#pragma unroll
  for (int ti = 0; ti < 3; ++ti)
#pragma unroll
    for (int j = 0; j < 3; ++j) {
      float p = qkv[ti][h * 64 + lane] * qkv[j][256 + h * 64 + lane];
      for (int off = 32; off; off >>= 1) p += __shfl_xor(p, off);
      if (lane == 0) lg[h][ti][j] = p * 0.125f;
    }
  __syncthreads();
  if (lane < 3) {
    int ti = lane;
    float l0 = lg[h][ti][0], l1 = lg[h][ti][1], l2 = lg[h][ti][2];
    float m = fmaxf(l0, fmaxf(l1, l2));
    float e0 = __expf(l0 - m), e1 = __expf(l1 - m), e2 = __expf(l2 - m);
    float inv = 1.f / (e0 + e1 + e2);
    aw[h][ti][0] = e0 * inv; aw[h][ti][1] = e1 * inv; aw[h][ti][2] = e2 * inv;
  }
  __syncthreads();
  int c = tid;
#pragma unroll
  for (int ti = 0; ti < 3; ++ti) {
    float o = aw[h][ti][0] * qkv[0][512 + c] +
              aw[h][ti][1] * qkv[1][512 + c] +
              aw[h][ti][2] * qkv[2][512 + c];
    qkvb[(r0 + ti) * 768 + c] = f2bf(o);   // overwrite q slot
  }
}

__global__ __launch_bounds__(256) void k_final(const unsigned short* __restrict__ seqc,
                                               int n0, int cn,
                                               const float* __restrict__ g,
                                               const float* __restrict__ b,
                                               float* __restrict__ out) {
  int ln = blockIdx.x * 4 + (threadIdx.x >> 6);
  if (ln >= cn) return;
  int lane = threadIdx.x & 63;
  const unsigned short* p = seqc + (size_t)ln * 3 * DD;   // token 0 row
  float v[4];
  float s = 0.f, s2 = 0.f;
#pragma unroll
  for (int i = 0; i < 4; ++i) {
    v[i] = bf2f(p[i * 64 + lane]);
    s += v[i]; s2 += v[i] * v[i];
  }
  for (int off = 32; off; off >>= 1) { s += __shfl_xor(s, off); s2 += __shfl_xor(s2, off); }
  float mean = s * (1.f / 256.f);
  float var  = s2 * (1.f / 256.f) - mean * mean;
  float inv  = rsqrtf(var + 1e-5f);
#pragma unroll
  for (int i = 0; i < 4; ++i) {
    int c = i * 64 + lane;
    out[(size_t)(n0 + ln) * DD + c] = (v[i] - mean) * inv * g[c] + b[c];
  }
}

// ---------------- host ----------------

extern "C" void kernel_launch(void* const* d_in, const int* in_sizes, int n_in,
                              void* d_out, int out_size, void* d_ws, size_t ws_size,
                              hipStream_t stream) {
  const float* x       = (const float*)d_in[0];
  const int*   ei      = (const int*)d_in[1];
  const float* gat1_W  = (const float*)d_in[2];
  const float* gat1_b  = (const float*)d_in[3];
  const float* gat1_as = (const float*)d_in[4];
  const float* gat1_ad = (const float*)d_in[5];
  const float* gat2_W  = (const float*)d_in[6];
  const float* gat2_b  = (const float*)d_in[7];
  const float* gat2_as = (const float*)d_in[8];
  const float* gat2_ad = (const float*)d_in[9];
  const float* cls     = (const float*)d_in[10];
  const float* pos     = (const float*)d_in[11];
  const float* Wqkv    = (const float*)d_in[12];
  const float* bqkv    = (const float*)d_in[13];
  const float* Wo      = (const float*)d_in[14];
  const float* bo      = (const float*)d_in[15];
  const float* ln1_g   = (const float*)d_in[16];
  const float* ln1_b   = (const float*)d_in[17];
  const float* ln2_g   = (const float*)d_in[18];
  const float* ln2_b   = (const float*)d_in[19];
  const float* Wff1    = (const float*)d_in[20];
  const float* bff1    = (const float*)d_in[21];
  const float* Wff2    = (const float*)d_in[22];
  const float* bff2    = (const float*)d_in[23];
  const float* norm_g  = (const float*)d_in[24];
  const float* norm_b  = (const float*)d_in[25];
  float* out = (float*)d_out;

  char* ws = (char*)d_ws;
  size_t off = 0;
  auto alloc = [&](size_t bytes) -> void* {
    off = (off + 255) & ~(size_t)255;
    void* p = ws + off;
    off += bytes;
    return p;
  };

  unsigned short* wb_g1  = (unsigned short*)alloc(sizeof(unsigned short) * 256 * 128);
  unsigned short* wb_g2  = (unsigned short*)alloc(sizeof(unsigned short) * 256 * 256);
  unsigned short* wb_qkv = (unsigned short*)alloc(sizeof(unsigned short) * 2 * 768 * 256);
  unsigned short* wb_o   = (unsigned short*)alloc(sizeof(unsigned short) * 2 * 256 * 256);
  unsigned short* wb_f1  = (unsigned short*)alloc(sizeof(unsigned short) * 2 * 1024 * 256);
  unsigned short* wb_f2  = (unsigned short*)alloc(sizeof(unsigned short) * 2 * 256 * 1024);
  unsigned short* xb  = (unsigned short*)alloc(sizeof(unsigned short) * (size_t)NN * DIN);
  unsigned short* hb  = (unsigned short*)alloc(sizeof(unsigned short) * (size_t)NN * DD);
  unsigned short* x1b = (unsigned short*)alloc(sizeof(unsigned short) * (size_t)NN * DD);
  unsigned short* x2b = (unsigned short*)alloc(sizeof(unsigned short) * (size_t)NN * DD);
  float* hs  = (float*)alloc(sizeof(float) * NN);
  float* hd  = (float*)alloc(sizeof(float) * NN);
  int* deg   = (int*)alloc(sizeof(int) * NN);
  int* inc   = (int*)alloc(sizeof(int) * NN);
  int* cur   = (int*)alloc(sizeof(int) * NN);
  int* tsum  = (int*)alloc(sizeof(int) * 64);
  int* ssrc  = (int*)alloc(sizeof(int) * E2);

  // transformer chunking (L3 residency of per-chunk activations)
  size_t fixed = (off + 255) & ~(size_t)255;
  size_t rem = (ws_size > fixed + 4096) ? (ws_size - fixed - 4096) : 0;
  const size_t per_node = (size_t)3 * (256 + 768) * 2;
  size_t cn_max = rem / per_node;
  if (cn_max < 1) cn_max = 1;
  if (cn_max > 12500) cn_max = 12500;
  int nc = (int)((NN + cn_max - 1) / cn_max);
  int cn = (NN + nc - 1) / nc;
  unsigned short* seqc = (unsigned short*)alloc(sizeof(unsigned short) * (size_t)3 * cn * 256);
  unsigned short* qkvb = (unsigned short*)alloc(sizeof(unsigned short) * (size_t)3 * cn * 768);

  // ---- casts ----
  auto cast = [&](const float* src, unsigned short* dst, int n) {
    k_cast<<<(n + 255) / 256, 256, 0, stream>>>(src, dst, n);
  };
  cast(gat1_W, wb_g1, 256 * 128);
  cast(gat2_W, wb_g2, 256 * 256);
  cast(Wqkv, wb_qkv, 2 * 768 * 256);
  cast(Wo, wb_o, 2 * 256 * 256);
  cast(Wff1, wb_f1, 2 * 1024 * 256);
  cast(Wff2, wb_f2, 2 * 256 * 1024);
  cast(x, xb, NN * DIN);

  // ---- CSR build ----
  hipMemsetAsync(deg, 0, sizeof(int) * NN, stream);
  hipMemsetAsync(cur, 0, sizeof(int) * NN, stream);
  k_deg<<<(E2 + 255) / 256, 256, 0, stream>>>(ei, deg);
  int nb = (NN + 1023) / 1024;
  k_scan_tile<<<nb, 1024, 0, stream>>>(deg, inc, tsum, NN);
  k_scan_sums<<<1, 64, 0, stream>>>(tsum, nb);
  k_scan_add<<<(NN + 255) / 256, 256, 0, stream>>>(inc, tsum, NN);
  k_scatter<<<(E2 + 255) / 256, 256, 0, stream>>>(ei, deg, inc, cur, ssrc);

  auto gemm = [&](const unsigned short* A, int lda, const unsigned short* B,
                  const float* bias, unsigned short* C, int ldc,
                  int M, int N, int K, int act) {
    int nm = (M + 127) / 128;
    int nmp = (nm + 7) & ~7;
    dim3 grid(N / 128, nmp);
    k_gemm128<<<grid, 256, 0, stream>>>(A, lda, B, bias, C, ldc, M, N, K, act);
  };

  // ---- GAT layer 1: hb = xb @ W1^T (K=128) ----
  gemm(xb, DIN, wb_g1, nullptr, hb, DD, NN, DD, DIN, 0);
  k_dots<<<(NN + 3) / 4, 256, 0, stream>>>(hb, gat1_as, gat1_ad, hs, hd);
  k_gat<<<(NN + 3) / 4, 256, 0, stream>>>(hb, ssrc, deg, inc, hs, hd, gat1_b, x1b);

  // ---- GAT layer 2: hb = x1b @ W2^T (K=256) ----
  gemm(x1b, DD, wb_g2, nullptr, hb, DD, NN, DD, DD, 0);
  k_dots<<<(NN + 3) / 4, 256, 0, stream>>>(hb, gat2_as, gat2_ad, hs, hd);
  k_gat<<<(NN + 3) / 4, 256, 0, stream>>>(hb, ssrc, deg, inc, hs, hd, gat2_b, x2b);

  // ---- transformer (chunked) ----
  for (int n0 = 0; n0 < NN; n0 += cn) {
    int c = NN - n0 < cn ? NN - n0 : cn;
    int Mch = 3 * c;
    int mblk64 = (Mch + 63) / 64;
    int mblk128 = (Mch + 127) / 128;
    k_seqbuild<<<(c * 3 * DD + 255) / 256, 256, 0, stream>>>(x1b, x2b, cls, pos, seqc, n0, c);
    for (int l = 0; l < 2; ++l) {
      // qkv: N=768, K=256
      gemm(seqc, DD, wb_qkv + (size_t)l * 768 * 256, bqkv + l * 768,
           qkvb, 768, Mch, 768, DD, 0);
      k_attn<<<c, 256, 0, stream>>>(qkvb);
      // o-proj + residual + ln1 fused (K=256)
      k_gemm_ln<<<mblk64, 256, 0, stream>>>(
          qkvb, 768, wb_o + (size_t)l * 256 * 256, bo + l * 256,
          seqc, DD, ln1_g + l * 256, ln1_b + l * 256, seqc, DD, Mch, DD);
      // fused ff1+relu+ff2+residual+ln2 (no global intermediate), 128-row blocks
      k_ff<<<mblk128, 512, 0, stream>>>(
          seqc, wb_f1 + (size_t)l * 1024 * 256, bff1 + l * 1024,
          wb_f2 + (size_t)l * 256 * 1024, bff2 + l * 256,
          ln2_g + l * 256, ln2_b + l * 256, Mch);
    }
    k_final<<<(c + 3) / 4, 256, 0, stream>>>(seqc, n0, c, norm_g, norm_b, out);
  }
}

// Round 7
// 2298.873 us; speedup vs baseline: 1.0010x; 1.0010x over previous
//
#include <hip/hip_runtime.h>
#include <hip/hip_bf16.h>

#define NN  50000
#define EE  320000
#define E2  (EE + NN)
#define DIN 128
#define DD  256

typedef __attribute__((ext_vector_type(8))) short          bf16x8;
typedef __attribute__((ext_vector_type(8))) unsigned short u16x8;
typedef __attribute__((ext_vector_type(4))) float          f32x4;

// ---------------- helpers ----------------

static __device__ __forceinline__ float bf2f(unsigned short u) {
  return __builtin_bit_cast(float, (unsigned)u << 16);
}

static __device__ __forceinline__ unsigned short f2bf(float f) {
  unsigned u = __builtin_bit_cast(unsigned, f);
  return (unsigned short)((u + 0x7fffu + ((u >> 16) & 1u)) >> 16);
}

static __device__ __forceinline__ void load_lds16(const void* g, void* l) {
  __builtin_amdgcn_global_load_lds(
      (const __attribute__((address_space(1))) void*)g,
      (__attribute__((address_space(3))) void*)l, 16, 0, 0);
}

static __device__ __forceinline__ float wredsum(float v) {
  for (int o = 32; o; o >>= 1) v += __shfl_xor(v, o);
  return v;
}

// ---------------- weight/activation cast fp32 -> bf16 ----------------

__global__ void k_cast(const float* __restrict__ in, unsigned short* __restrict__ out, int n) {
  int i = blockIdx.x * blockDim.x + threadIdx.x;
  if (i >= n) return;
  out[i] = f2bf(in[i]);
}

// ---------------- CSR build ----------------

__global__ void k_deg(const int* __restrict__ ei, int* __restrict__ deg) {
  int i = blockIdx.x * blockDim.x + threadIdx.x;
  if (i >= E2) return;
  int dst = (i < EE) ? ei[EE + i] : (i - EE);
  atomicAdd(&deg[dst], 1);
}

__global__ __launch_bounds__(1024) void k_scan_tile(const int* __restrict__ in,
                                                    int* __restrict__ out,
                                                    int* __restrict__ tsum, int n) {
  __shared__ int sm[1024];
  int tid = threadIdx.x;
  int g = blockIdx.x * 1024 + tid;
  sm[tid] = (g < n) ? in[g] : 0;
  __syncthreads();
  for (int off = 1; off < 1024; off <<= 1) {
    int t = (tid >= off) ? sm[tid - off] : 0;
    __syncthreads();
    sm[tid] += t;
    __syncthreads();
  }
  if (g < n) out[g] = sm[tid];
  if (tid == 1023) tsum[blockIdx.x] = sm[1023];
}

__global__ void k_scan_sums(int* __restrict__ tsum, int nb) {
  int tid = threadIdx.x;           // single wave of 64, nb <= 64
  int v = (tid < nb) ? tsum[tid] : 0;
  for (int off = 1; off < 64; off <<= 1) {
    int t = __shfl_up(v, off);
    if (tid >= off) v += t;
  }
  if (tid < nb) tsum[tid] = v;
}

__global__ void k_scan_add(int* __restrict__ out, const int* __restrict__ tsum, int n) {
  int g = blockIdx.x * blockDim.x + threadIdx.x;
  if (g >= n || g < 1024) return;
  out[g] += tsum[(g >> 10) - 1];
}

__global__ void k_scatter(const int* __restrict__ ei, const int* __restrict__ deg,
                          const int* __restrict__ inc, int* __restrict__ cur,
                          int* __restrict__ ssrc) {
  int i = blockIdx.x * blockDim.x + threadIdx.x;
  if (i >= E2) return;
  int src, dst;
  if (i < EE) { src = ei[i]; dst = ei[EE + i]; } else { src = dst = i - EE; }
  int pos = atomicAdd(&cur[dst], 1);
  ssrc[inc[dst] - deg[dst] + pos] = src;
}

// ---------------- GAT pieces (h in bf16) ----------------

__global__ __launch_bounds__(256) void k_dots(const unsigned short* __restrict__ hb,
                                              const float* __restrict__ asrc,
                                              const float* __restrict__ adst,
                                              float* __restrict__ hs, float* __restrict__ hd) {
  int node = blockIdx.x * 4 + (threadIdx.x >> 6);
  if (node >= NN) return;
  int lane = threadIdx.x & 63;
  ushort4 hv = *reinterpret_cast<const ushort4*>(hb + (size_t)node * DD + lane * 4);
  float v0 = bf2f(hv.x), v1 = bf2f(hv.y), v2 = bf2f(hv.z), v3 = bf2f(hv.w);
  const float* as = asrc + lane * 4;
  const float* ad = adst + lane * 4;
  float s1 = v0 * as[0] + v1 * as[1] + v2 * as[2] + v3 * as[3];
  float s2 = v0 * ad[0] + v1 * ad[1] + v2 * ad[2] + v3 * ad[3];
  for (int off = 32; off; off >>= 1) {
    s1 += __shfl_xor(s1, off);
    s2 += __shfl_xor(s2, off);
  }
  if (lane == 0) { hs[node] = s1; hd[node] = s2; }
}

// Fused edge-softmax + aggregation: one wave per dst node.
__global__ __launch_bounds__(256) void k_gat(const unsigned short* __restrict__ hb,
                                             const int* __restrict__ ssrc,
                                             const int* __restrict__ deg,
                                             const int* __restrict__ inc,
                                             const float* __restrict__ hs,
                                             const float* __restrict__ hd,
                                             const float* __restrict__ bias,
                                             unsigned short* __restrict__ out) {
  __shared__ float sE[4][256];
  __shared__ int   sI[4][256];
  int w = threadIdx.x >> 6;
  int d = blockIdx.x * 4 + w;
  if (d >= NN) return;
  int lane = threadIdx.x & 63;
  int end = inc[d], cnt = deg[d], base = end - cnt;
  if (cnt > 256) cnt = 256;
  float hdd = hd[d];

  float m = -1e30f;
  for (int i0 = 0; i0 < cnt; i0 += 64) {
    int i = i0 + lane;
    float sc = -1e30f;
    if (i < cnt) {
      int s = ssrc[base + i];
      float v = hs[s] + hdd;
      sc = (v < 0.f) ? 0.2f * v : v;
      sI[w][i] = s;
      sE[w][i] = sc;
    }
    float mm = sc;
    for (int o = 32; o; o >>= 1) mm = fmaxf(mm, __shfl_xor(mm, o));
    m = fmaxf(m, mm);
  }
  float sum = 0.f;
  for (int i0 = 0; i0 < cnt; i0 += 64) {
    int i = i0 + lane;
    float e = 0.f;
    if (i < cnt) {
      e = __expf(sE[w][i] - m);
      sE[w][i] = e;
    }
    for (int o = 32; o; o >>= 1) e += __shfl_xor(e, o);
    sum += e;
  }
  float inv = 1.f / sum;

  float a0 = 0.f, a1 = 0.f, a2 = 0.f, a3 = 0.f;
  for (int i = 0; i < cnt; ++i) {
    float a = sE[w][i];
    int s = sI[w][i];
    ushort4 hv = *reinterpret_cast<const ushort4*>(hb + (size_t)s * DD + lane * 4);
    a0 += a * bf2f(hv.x);
    a1 += a * bf2f(hv.y);
    a2 += a * bf2f(hv.z);
    a3 += a * bf2f(hv.w);
  }
  const float* bp = bias + lane * 4;
  float r0 = a0 * inv + bp[0], r1 = a1 * inv + bp[1];
  float r2 = a2 * inv + bp[2], r3 = a3 * inv + bp[3];
  ushort4 o;
  o.x = f2bf(r0 > 0.f ? r0 : 0.f);
  o.y = f2bf(r1 > 0.f ? r1 : 0.f);
  o.z = f2bf(r2 > 0.f ? r2 : 0.f);
  o.w = f2bf(r3 > 0.f ? r3 : 0.f);
  *reinterpret_cast<ushort4*>(out + (size_t)d * DD + lane * 4) = o;
}

// LDS k-chunk swizzle (bank-conflict-free fragment reads):
// LDS slot (row, c) holds global k-chunk  c ^ ((row>>1)&3)  within each 32-k group.
// Fragment read of logical chunk q at row (16-aligned base + m_lane):
//   position = q ^ ((m_lane>>1)&3).
// Row stride MUST be 64 B ([*][32 shorts]) for conflict-free b128 reads.

// ---------------- LDS-staged bf16 MFMA GEMM, XCD-swizzled grid ----------------
// C = act(A @ B^T + bias);  A bf16 [M x K] lda, B bf16 [N x K], C bf16 [M x ldc].
// 128x128 tile, BK=32, 4 waves, double-buffered staging.

__global__ __launch_bounds__(256) void k_gemm128(
    const unsigned short* __restrict__ A, int lda,
    const unsigned short* __restrict__ B,
    const float* __restrict__ bias,
    unsigned short* __restrict__ C, int ldc,
    int M, int N, int K, int act) {
  __shared__ unsigned short As[2][128 * 32];
  __shared__ unsigned short Bs[2][128 * 32];

  const int id  = blockIdx.y * gridDim.x + blockIdx.x;
  const int nn  = gridDim.x;
  const int sid = id >> 3;
  const int jn  = sid % nn;
  const int im  = (id & 7) + ((sid / nn) << 3);
  if (im >= ((M + 127) >> 7)) return;
  const int m0 = im * 128;
  const int n0 = jn * 128;

  const int tid    = threadIdx.x;
  const int lane   = tid & 63;
  const int w      = tid >> 6;
  const int m_lane = lane & 15;
  const int quad   = lane >> 4;
  const int wm     = (w >> 1) * 64;
  const int wn     = (w & 1) * 64;

  const int idx0 = tid, idx1 = 256 + tid;
  const int kc = (((tid & 3) ^ ((tid >> 3) & 3))) * 8;   // same for idx0/idx1
  int rowA0 = m0 + (idx0 >> 2); if (rowA0 >= M) rowA0 = M - 1;
  int rowA1 = m0 + (idx1 >> 2); if (rowA1 >= M) rowA1 = M - 1;
  const unsigned short* gA0 = A + (size_t)rowA0 * lda + kc;
  const unsigned short* gA1 = A + (size_t)rowA1 * lda + kc;
  const unsigned short* gB0 = B + (size_t)(n0 + (idx0 >> 2)) * K + kc;
  const unsigned short* gB1 = B + (size_t)(n0 + (idx1 >> 2)) * K + kc;

  const int la0 = (w * 64) * 8;          // LDS slot offsets (shorts)
  const int la1 = (256 + w * 64) * 8;

  const int swz = (quad ^ ((m_lane >> 1) & 3)) * 8;

  f32x4 acc[4][4] = {};

  const int nk = K >> 5;

  // prologue: stage k-tile 0 into buffer 0
  load_lds16(gA0, &As[0][la0]);
  load_lds16(gA1, &As[0][la1]);
  load_lds16(gB0, &Bs[0][la0]);
  load_lds16(gB1, &Bs[0][la1]);
  gA0 += 32; gA1 += 32; gB0 += 32; gB1 += 32;
  __syncthreads();

  int cur = 0;
  for (int t = 0; t < nk; ++t) {
    if (t + 1 < nk) {   // issue next-tile stage BEFORE compute of current tile
      load_lds16(gA0, &As[cur ^ 1][la0]);
      load_lds16(gA1, &As[cur ^ 1][la1]);
      load_lds16(gB0, &Bs[cur ^ 1][la0]);
      load_lds16(gB1, &Bs[cur ^ 1][la1]);
      gA0 += 32; gA1 += 32; gB0 += 32; gB1 += 32;
    }
    bf16x8 af[4], bg[4];
#pragma unroll
    for (int i = 0; i < 4; ++i)
      af[i] = *reinterpret_cast<const bf16x8*>(&As[cur][(wm + i * 16 + m_lane) * 32 + swz]);
#pragma unroll
    for (int j = 0; j < 4; ++j)
      bg[j] = *reinterpret_cast<const bf16x8*>(&Bs[cur][(wn + j * 16 + m_lane) * 32 + swz]);
#pragma unroll
    for (int i = 0; i < 4; ++i)
#pragma unroll
      for (int j = 0; j < 4; ++j)
        acc[i][j] = __builtin_amdgcn_mfma_f32_16x16x32_bf16(af[i], bg[j], acc[i][j], 0, 0, 0);
    __syncthreads();   // drains this iter's stage (vmcnt) after MFMA work hid it
    cur ^= 1;
  }

#pragma unroll
  for (int i = 0; i < 4; ++i) {
#pragma unroll
    for (int j = 0; j < 4; ++j) {
      int col = n0 + wn + j * 16 + m_lane;
      float bv = bias ? bias[col] : 0.f;
#pragma unroll
      for (int r = 0; r < 4; ++r) {
        int row = m0 + wm + i * 16 + quad * 4 + r;
        if (row < M) {
          float v = acc[i][j][r] + bv;
          if (act) v = v > 0.f ? v : 0.f;
          C[(size_t)row * ldc + col] = f2bf(v);
        }
      }
    }
  }
}

// ---------------- fused GEMM(+bias+residual)+LayerNorm, N=256 exactly ----------------
// 64-row blocks, 4 waves each owning a 32x128 sub-tile. Double-buffered staging.
// (still used for... nothing now except kept for potential reuse; actually removed
//  from host path for o-proj, retained for ff fallback—not launched.)

// ---------------- fused attention + o-proj + bias + residual + LayerNorm ----------
// Replaces k_attn + o-proj k_gemm_ln. 48-row blocks = 16 nodes, 256 thr / 4 waves.
// Phase 1: per-node 4-head 3x3 attention from raw qkvb rows (lane = head dim),
//          mixed rows written bf16 into swizzled k-grouped As tile.
// Phase 2: [48x256] @ Wo^T (K=256, dbuf B panels) + bo + residual(seqc) + LN,
//          wave w owns all 48 rows x 64 cols (cb = w*64).

__global__ __launch_bounds__(256) void k_oproj(
    const unsigned short* __restrict__ qkvb,   // [M x 768] raw q|k|v
    const unsigned short* __restrict__ Wo,     // [256 x 256]
    const float* __restrict__ bo,
    const float* __restrict__ gam, const float* __restrict__ bet,
    unsigned short* __restrict__ seqc,         // residual in / out, [M x 256]
    int M) {
  __shared__ unsigned short As[8 * 48 * 32];   // 24 KB attention-out, [kgrp][row][32]
  __shared__ unsigned short Bs[2][256 * 32];   // 32 KB Wo k-panels
  __shared__ float sSum[4 * 48];
  __shared__ float sSq[4 * 48];

  const int tid  = threadIdx.x;
  const int lane = tid & 63;
  const int w    = tid >> 6;
  const int ml   = lane & 15;
  const int quad = lane >> 4;
  const int m0   = blockIdx.x * 48;
  const int swz  = (quad ^ ((ml >> 1) & 3)) * 8;

  // ---- issue Wo panel-0 stage first (latency hides under attention phase) ----
  const int kcs = ((tid & 3) ^ ((tid >> 3) & 3)) * 8;
  const unsigned short* gB0 = Wo + (size_t)((0 * 256 + tid) >> 2) * 256 + kcs;
  const unsigned short* gB1 = Wo + (size_t)((1 * 256 + tid) >> 2) * 256 + kcs;
  const unsigned short* gB2 = Wo + (size_t)((2 * 256 + tid) >> 2) * 256 + kcs;
  const unsigned short* gB3 = Wo + (size_t)((3 * 256 + tid) >> 2) * 256 + kcs;
  const int lb0 = (0 * 256 + w * 64) * 8;
  const int lb1 = (1 * 256 + w * 64) * 8;
  const int lb2 = (2 * 256 + w * 64) * 8;
  const int lb3 = (3 * 256 + w * 64) * 8;
  load_lds16(gB0, &Bs[0][lb0]);
  load_lds16(gB1, &Bs[0][lb1]);
  load_lds16(gB2, &Bs[0][lb2]);
  load_lds16(gB3, &Bs[0][lb3]);
  gB0 += 32; gB1 += 32; gB2 += 32; gB3 += 32;

  // ---- phase 1: attention for this wave's 4 nodes (lane = head-dim d) ----
  const int d = lane;
  for (int i = 0; i < 4; ++i) {
    int r0 = (w * 4 + i) * 3;                  // local row of token 0
    size_t rowg[3];
#pragma unroll
    for (int t = 0; t < 3; ++t) {
      int rg = m0 + r0 + t;
      rowg[t] = (size_t)(rg < M ? rg : M - 1);
    }
#pragma unroll
    for (int h = 0; h < 4; ++h) {
      float q[3], k[3], v[3];
#pragma unroll
      for (int t = 0; t < 3; ++t) {
        size_t base = rowg[t] * 768 + h * 64 + d;
        q[t] = bf2f(qkvb[base]);
        k[t] = bf2f(qkvb[base + 256]);
        v[t] = bf2f(qkvb[base + 512]);
      }
      float l[3][3];
#pragma unroll
      for (int a = 0; a < 3; ++a)
#pragma unroll
        for (int b = 0; b < 3; ++b)
          l[a][b] = wredsum(q[a] * k[b]) * 0.125f;
#pragma unroll
      for (int a = 0; a < 3; ++a) {
        float mx = fmaxf(l[a][0], fmaxf(l[a][1], l[a][2]));
        float e0 = __expf(l[a][0] - mx);
        float e1 = __expf(l[a][1] - mx);
        float e2 = __expf(l[a][2] - mx);
        float inv = 1.f / (e0 + e1 + e2);
        float o = (e0 * v[0] + e1 * v[1] + e2 * v[2]) * inv;
        int row = r0 + a;
        int col = h * 64 + d;
        int g = col >> 5, c = (col >> 3) & 3;
        As[((g * 48 + row) * 32) + ((c ^ ((row >> 1) & 3)) << 3) + (col & 7)] = f2bf(o);
      }
    }
  }
  __syncthreads();   // As complete; Bs[0] stage drained

  // ---- phase 2: GEMM [48 x 256] @ Wo^T, K=256 in 8 panels, dbuf B ----
  f32x4 acc[3][4] = {};
  int cur = 0;
  for (int t = 0; t < 8; ++t) {
    if (t + 1 < 8) {
      load_lds16(gB0, &Bs[cur ^ 1][lb0]);
      load_lds16(gB1, &Bs[cur ^ 1][lb1]);
      load_lds16(gB2, &Bs[cur ^ 1][lb2]);
      load_lds16(gB3, &Bs[cur ^ 1][lb3]);
      gB0 += 32; gB1 += 32; gB2 += 32; gB3 += 32;
    }
    bf16x8 af[3], bg[4];
#pragma unroll
    for (int i = 0; i < 3; ++i)
      af[i] = *reinterpret_cast<const bf16x8*>(&As[(t * 48 + i * 16 + ml) * 32 + swz]);
#pragma unroll
    for (int j = 0; j < 4; ++j)
      bg[j] = *reinterpret_cast<const bf16x8*>(&Bs[cur][(w * 64 + j * 16 + ml) * 32 + swz]);
#pragma unroll
    for (int i = 0; i < 3; ++i)
#pragma unroll
      for (int j = 0; j < 4; ++j)
        acc[i][j] = __builtin_amdgcn_mfma_f32_16x16x32_bf16(af[i], bg[j], acc[i][j], 0, 0, 0);
    __syncthreads();
    cur ^= 1;
  }

  // ---- bias + residual + per-row partial stats over this wave's 64 cols ----
  float bov[4], gv[4], btv[4];
#pragma unroll
  for (int j = 0; j < 4; ++j) {
    int col = w * 64 + j * 16 + ml;
    bov[j] = bo[col]; gv[j] = gam[col]; btv[j] = bet[col];
  }

#pragma unroll
  for (int i = 0; i < 3; ++i)
#pragma unroll
    for (int r = 0; r < 4; ++r) {
      int row = i * 16 + quad * 4 + r;
      int rg = m0 + row;
      size_t rr2 = (size_t)(rg < M ? rg : M - 1);
      float s = 0.f, s2 = 0.f;
#pragma unroll
      for (int j = 0; j < 4; ++j) {
        int col = w * 64 + j * 16 + ml;
        float t = acc[i][j][r] + bov[j] + bf2f(seqc[rr2 * 256 + col]);
        acc[i][j][r] = t;
        s += t; s2 += t * t;
      }
#pragma unroll
      for (int o = 1; o < 16; o <<= 1) { s += __shfl_xor(s, o); s2 += __shfl_xor(s2, o); }
      if (ml == 0) { sSum[w * 48 + row] = s; sSq[w * 48 + row] = s2; }
    }
  __syncthreads();

#pragma unroll
  for (int i = 0; i < 3; ++i)
#pragma unroll
    for (int r = 0; r < 4; ++r) {
      int row = i * 16 + quad * 4 + r;
      int rg = m0 + row;
      if (rg >= M) continue;
      float s  = sSum[row] + sSum[48 + row] + sSum[96 + row] + sSum[144 + row];
      float s2 = sSq[row]  + sSq[48 + row]  + sSq[96 + row]  + sSq[144 + row];
      float mean = s * (1.f / 256.f);
      float var  = s2 * (1.f / 256.f) - mean * mean;
      float inv  = rsqrtf(var + 1e-5f);
#pragma unroll
      for (int j = 0; j < 4; ++j) {
        int col = w * 64 + j * 16 + ml;
        seqc[(size_t)rg * 256 + col] = f2bf((acc[i][j][r] - mean) * inv * gv[j] + btv[j]);
      }
    }
}

// ---------------- fused FFN: relu(A@W1^T+b1)@W2^T + b2 + residual(A) + LN ----------
// A = seqc [M x 256] bf16, in-place. W1 [1024 x 256], W2 [256 x 1024] bf16.
// 128-row blocks, 8 waves, 128 KB LDS. K-grouped [8 grp][128 row][32] layout.
// Runs at ~327 TF — on the measured m102 shape-curve for K=256/BK=32 GEMMs.

__global__ __launch_bounds__(512, 2) void k_ff(
    unsigned short* __restrict__ A,
    const unsigned short* __restrict__ W1,
    const float* __restrict__ b1,
    const unsigned short* __restrict__ W2,
    const float* __restrict__ b2,
    const float* __restrict__ gam, const float* __restrict__ bet,
    int M) {
  __shared__ unsigned short As[8 * 128 * 32];   // 64 KB  [kgrp][row][32]
  __shared__ unsigned short Hs[8 * 128 * 32];   // 64 KB  (reused as LN scratch)

  const int tid  = threadIdx.x;
  const int lane = tid & 63;
  const int w    = tid >> 6;        // 0..7
  const int ml   = lane & 15;
  const int quad = lane >> 4;
  const int m0   = blockIdx.x * 128;
  const int swz  = (quad ^ ((ml >> 1) & 3)) << 3;

  // ---- stage A tile 128x256: thread tid -> row tid>>2, chunk tid&3, 8 kgroups
  {
    int rg = m0 + (tid >> 2); if (rg >= M) rg = M - 1;
    int cs = (tid & 3) ^ ((tid >> 3) & 3);
    const unsigned short* gsrc = A + (size_t)rg * 256 + (cs << 3);
    unsigned short* ldst = As + (size_t)(w * 64) * 8;   // w*512 shorts; HW adds lane*16B
#pragma unroll
    for (int g = 0; g < 8; ++g)
      load_lds16(gsrc + (g << 5), ldst + (size_t)g * 4096);
  }
  __syncthreads();

  f32x4 acc2[8][2] = {};

  for (int kb = 0; kb < 4; ++kb) {
    f32x4 acc1[2][8] = {};
    const unsigned short* W1p = W1 + (size_t)(kb * 256 + w * 32 + ml) * 256 + quad * 8;
#pragma unroll 2
    for (int ks = 0; ks < 8; ++ks) {
      bf16x8 af[2], bg[8];
#pragma unroll
      for (int i = 0; i < 2; ++i)
        af[i] = *reinterpret_cast<const bf16x8*>(W1p + (size_t)i * 16 * 256 + ks * 32);
#pragma unroll
      for (int j = 0; j < 8; ++j)
        bg[j] = *reinterpret_cast<const bf16x8*>(&As[ks * 4096 + (j * 16 + ml) * 32 + swz]);
#pragma unroll
      for (int i = 0; i < 2; ++i)
#pragma unroll
        for (int j = 0; j < 8; ++j)
          acc1[i][j] = __builtin_amdgcn_mfma_f32_16x16x32_bf16(af[i], bg[j], acc1[i][j], 0, 0, 0);
    }

    __syncthreads();   // previous GEMM2 readers of Hs are done

#pragma unroll
    for (int i = 0; i < 2; ++i) {
      float4 bv = *reinterpret_cast<const float4*>(b1 + kb * 256 + w * 32 + i * 16 + quad * 4);
      int c  = i * 2 + (quad >> 1);
      int lo = (quad & 1) * 4;
#pragma unroll
      for (int j = 0; j < 8; ++j) {
        int seqrow = j * 16 + ml;
        int chsw = c ^ ((ml >> 1) & 3);
        int addr = w * 4096 + seqrow * 32 + (chsw << 3) + lo;
        float t0 = acc1[i][j][0] + bv.x; t0 = t0 > 0.f ? t0 : 0.f;
        float t1 = acc1[i][j][1] + bv.y; t1 = t1 > 0.f ? t1 : 0.f;
        float t2 = acc1[i][j][2] + bv.z; t2 = t2 > 0.f ? t2 : 0.f;
        float t3 = acc1[i][j][3] + bv.w; t3 = t3 > 0.f ? t3 : 0.f;
        ushort4 hv;
        hv.x = f2bf(t0); hv.y = f2bf(t1); hv.z = f2bf(t2); hv.w = f2bf(t3);
        *reinterpret_cast<ushort4*>(&Hs[addr]) = hv;
      }
    }
    __syncthreads();   // Hs visible to all waves

    const unsigned short* W2p = W2 + (size_t)(w * 32 + ml) * 1024 + kb * 256 + quad * 8;
#pragma unroll 2
    for (int ks = 0; ks < 8; ++ks) {
      bf16x8 af[8], bg[2];
#pragma unroll
      for (int i = 0; i < 8; ++i)
        af[i] = *reinterpret_cast<const bf16x8*>(&Hs[ks * 4096 + (i * 16 + ml) * 32 + swz]);
#pragma unroll
      for (int j = 0; j < 2; ++j)
        bg[j] = *reinterpret_cast<const bf16x8*>(W2p + (size_t)j * 16 * 1024 + ks * 32);
#pragma unroll
      for (int i = 0; i < 8; ++i)
#pragma unroll
        for (int j = 0; j < 2; ++j)
          acc2[i][j] = __builtin_amdgcn_mfma_f32_16x16x32_bf16(af[i], bg[j], acc2[i][j], 0, 0, 0);
    }
  }

  __syncthreads();   // all Hs reads done -> reuse Hs as LN scratch
  float* sS = reinterpret_cast<float*>(Hs);   // [8][128]
  float* sQ = sS + 1024;                       // [8][128]

  float b2v[2], gv[2], btv[2];
#pragma unroll
  for (int j = 0; j < 2; ++j) {
    int col = w * 32 + j * 16 + ml;
    b2v[j] = b2[col]; gv[j] = gam[col]; btv[j] = bet[col];
  }

#pragma unroll
  for (int i = 0; i < 8; ++i)
#pragma unroll
    for (int r = 0; r < 4; ++r) {
      int row = i * 16 + quad * 4 + r;
      float s = 0.f, s2 = 0.f;
#pragma unroll
      for (int j = 0; j < 2; ++j) {
        int c_r = j * 2 + (ml >> 3);
        float t = acc2[i][j][r] + b2v[j] +
                  bf2f(As[w * 4096 + row * 32 + ((c_r ^ ((row >> 1) & 3)) << 3) + (ml & 7)]);
        acc2[i][j][r] = t;
        s += t; s2 += t * t;
      }
#pragma unroll
      for (int o = 1; o < 16; o <<= 1) { s += __shfl_xor(s, o); s2 += __shfl_xor(s2, o); }
      if (ml == 0) { sS[w * 128 + row] = s; sQ[w * 128 + row] = s2; }
    }
  __syncthreads();

#pragma unroll
  for (int i = 0; i < 8; ++i)
#pragma unroll
    for (int r = 0; r < 4; ++r) {
      int row = i * 16 + quad * 4 + r;
      int rg = m0 + row;
      if (rg >= M) continue;
      float s = 0.f, s2 = 0.f;
#pragma unroll
      for (int ww = 0; ww < 8; ++ww) { s += sS[ww * 128 + row]; s2 += sQ[ww * 128 + row]; }
      float mean = s * (1.f / 256.f);
      float var  = s2 * (1.f / 256.f) - mean * mean;
      float inv  = rsqrtf(var + 1e-5f);
#pragma unroll
      for (int j = 0; j < 2; ++j) {
        int col = w * 32 + j * 16 + ml;
        A[(size_t)rg * 256 + col] = f2bf((acc2[i][j][r] - mean) * inv * gv[j] + btv[j]);
      }
    }
}

// ---------------- transformer pieces (bf16 activations, dense layouts) ----------------

__global__ void k_seqbuild(const unsigned short* __restrict__ x1,
                           const unsigned short* __restrict__ x2,
                           const float* __restrict__ cls, const float* __restrict__ pos,
                           unsigned short* __restrict__ seqc, int n0, int cn) {
  int idx = blockIdx.x * blockDim.x + threadIdx.x;
  int total = cn * 3 * DD;
  if (idx >= total) return;
  int c = idx & (DD - 1);
  int r = idx >> 8;
  int t = r % 3, ln = r / 3;
  int n = n0 + ln;
  float v;
  if (t == 0)      v = cls[c];
  else if (t == 1) v = bf2f(x1[(size_t)n * DD + c]);
  else             v = bf2f(x2[(size_t)n * DD + c]);
  seqc[idx] = f2bf(v + pos[t * DD + c]);
}

__global__ __launch_bounds__(256) void k_final(const unsigned short* __restrict__ seqc,
                                               int n0, int cn,
                                               const float* __restrict__ g,
                                               const float* __restrict__ b,
                                               float* __restrict__ out) {
  int ln = blockIdx.x * 4 + (threadIdx.x >> 6);
  if (ln >= cn) return;
  int lane = threadIdx.x & 63;
  const unsigned short* p = seqc + (size_t)ln * 3 * DD;   // token 0 row
  float v[4];
  float s = 0.f, s2 = 0.f;
#pragma unroll
  for (int i = 0; i < 4; ++i) {
    v[i] = bf2f(p[i * 64 + lane]);
    s += v[i]; s2 += v[i] * v[i];
  }
  for (int off = 32; off; off >>= 1) { s += __shfl_xor(s, off); s2 += __shfl_xor(s2, off); }
  float mean = s * (1.f / 256.f);
  float var  = s2 * (1.f / 256.f) - mean * mean;
  float inv  = rsqrtf(var + 1e-5f);
#pragma unroll
  for (int i = 0; i < 4; ++i) {
    int c = i * 64 + lane;
    out[(size_t)(n0 + ln) * DD + c] = (v[i] - mean) * inv * g[c] + b[c];
  }
}

// ---------------- host ----------------

extern "C" void kernel_launch(void* const* d_in, const int* in_sizes, int n_in,
                              void* d_out, int out_size, void* d_ws, size_t ws_size,
                              hipStream_t stream) {
  const float* x       = (const float*)d_in[0];
  const int*   ei      = (const int*)d_in[1];
  const float* gat1_W  = (const float*)d_in[2];
  const float* gat1_b  = (const float*)d_in[3];
  const float* gat1_as = (const float*)d_in[4];
  const float* gat1_ad = (const float*)d_in[5];
  const float* gat2_W  = (const float*)d_in[6];
  const float* gat2_b  = (const float*)d_in[7];
  const float* gat2_as = (const float*)d_in[8];
  const float* gat2_ad = (const float*)d_in[9];
  const float* cls     = (const float*)d_in[10];
  const float* pos     = (const float*)d_in[11];
  const float* Wqkv    = (const float*)d_in[12];
  const float* bqkv    = (const float*)d_in[13];
  const float* Wo      = (const float*)d_in[14];
  const float* bo      = (const float*)d_in[15];
  const float* ln1_g   = (const float*)d_in[16];
  const float* ln1_b   = (const float*)d_in[17];
  const float* ln2_g   = (const float*)d_in[18];
  const float* ln2_b   = (const float*)d_in[19];
  const float* Wff1    = (const float*)d_in[20];
  const float* bff1    = (const float*)d_in[21];
  const float* Wff2    = (const float*)d_in[22];
  const float* bff2    = (const float*)d_in[23];
  const float* norm_g  = (const float*)d_in[24];
  const float* norm_b  = (const float*)d_in[25];
  float* out = (float*)d_out;

  char* ws = (char*)d_ws;
  size_t off = 0;
  auto alloc = [&](size_t bytes) -> void* {
    off = (off + 255) & ~(size_t)255;
    void* p = ws + off;
    off += bytes;
    return p;
  };

  unsigned short* wb_g1  = (unsigned short*)alloc(sizeof(unsigned short) * 256 * 128);
  unsigned short* wb_g2  = (unsigned short*)alloc(sizeof(unsigned short) * 256 * 256);
  unsigned short* wb_qkv = (unsigned short*)alloc(sizeof(unsigned short) * 2 * 768 * 256);
  unsigned short* wb_o   = (unsigned short*)alloc(sizeof(unsigned short) * 2 * 256 * 256);
  unsigned short* wb_f1  = (unsigned short*)alloc(sizeof(unsigned short) * 2 * 1024 * 256);
  unsigned short* wb_f2  = (unsigned short*)alloc(sizeof(unsigned short) * 2 * 256 * 1024);
  unsigned short* xb  = (unsigned short*)alloc(sizeof(unsigned short) * (size_t)NN * DIN);
  unsigned short* hb  = (unsigned short*)alloc(sizeof(unsigned short) * (size_t)NN * DD);
  unsigned short* x1b = (unsigned short*)alloc(sizeof(unsigned short) * (size_t)NN * DD);
  unsigned short* x2b = (unsigned short*)alloc(sizeof(unsigned short) * (size_t)NN * DD);
  float* hs  = (float*)alloc(sizeof(float) * NN);
  float* hd  = (float*)alloc(sizeof(float) * NN);
  int* deg   = (int*)alloc(sizeof(int) * NN);
  int* inc   = (int*)alloc(sizeof(int) * NN);
  int* cur   = (int*)alloc(sizeof(int) * NN);
  int* tsum  = (int*)alloc(sizeof(int) * 64);
  int* ssrc  = (int*)alloc(sizeof(int) * E2);

  // transformer chunking (L3 residency of per-chunk activations)
  size_t fixed = (off + 255) & ~(size_t)255;
  size_t rem = (ws_size > fixed + 4096) ? (ws_size - fixed - 4096) : 0;
  const size_t per_node = (size_t)3 * (256 + 768) * 2;
  size_t cn_max = rem / per_node;
  if (cn_max < 1) cn_max = 1;
  if (cn_max > 12500) cn_max = 12500;
  int nc = (int)((NN + cn_max - 1) / cn_max);
  int cn = (NN + nc - 1) / nc;
  unsigned short* seqc = (unsigned short*)alloc(sizeof(unsigned short) * (size_t)3 * cn * 256);
  unsigned short* qkvb = (unsigned short*)alloc(sizeof(unsigned short) * (size_t)3 * cn * 768);

  // ---- casts ----
  auto cast = [&](const float* src, unsigned short* dst, int n) {
    k_cast<<<(n + 255) / 256, 256, 0, stream>>>(src, dst, n);
  };
  cast(gat1_W, wb_g1, 256 * 128);
  cast(gat2_W, wb_g2, 256 * 256);
  cast(Wqkv, wb_qkv, 2 * 768 * 256);
  cast(Wo, wb_o, 2 * 256 * 256);
  cast(Wff1, wb_f1, 2 * 1024 * 256);
  cast(Wff2, wb_f2, 2 * 256 * 1024);
  cast(x, xb, NN * DIN);

  // ---- CSR build ----
  hipMemsetAsync(deg, 0, sizeof(int) * NN, stream);
  hipMemsetAsync(cur, 0, sizeof(int) * NN, stream);
  k_deg<<<(E2 + 255) / 256, 256, 0, stream>>>(ei, deg);
  int nb = (NN + 1023) / 1024;
  k_scan_tile<<<nb, 1024, 0, stream>>>(deg, inc, tsum, NN);
  k_scan_sums<<<1, 64, 0, stream>>>(tsum, nb);
  k_scan_add<<<(NN + 255) / 256, 256, 0, stream>>>(inc, tsum, NN);
  k_scatter<<<(E2 + 255) / 256, 256, 0, stream>>>(ei, deg, inc, cur, ssrc);

  auto gemm = [&](const unsigned short* A, int lda, const unsigned short* B,
                  const float* bias, unsigned short* C, int ldc,
                  int M, int N, int K, int act) {
    int nm = (M + 127) / 128;
    int nmp = (nm + 7) & ~7;
    dim3 grid(N / 128, nmp);
    k_gemm128<<<grid, 256, 0, stream>>>(A, lda, B, bias, C, ldc, M, N, K, act);
  };

  // ---- GAT layer 1: hb = xb @ W1^T (K=128) ----
  gemm(xb, DIN, wb_g1, nullptr, hb, DD, NN, DD, DIN, 0);
  k_dots<<<(NN + 3) / 4, 256, 0, stream>>>(hb, gat1_as, gat1_ad, hs, hd);
  k_gat<<<(NN + 3) / 4, 256, 0, stream>>>(hb, ssrc, deg, inc, hs, hd, gat1_b, x1b);

  // ---- GAT layer 2: hb = x1b @ W2^T (K=256) ----
  gemm(x1b, DD, wb_g2, nullptr, hb, DD, NN, DD, DD, 0);
  k_dots<<<(NN + 3) / 4, 256, 0, stream>>>(hb, gat2_as, gat2_ad, hs, hd);
  k_gat<<<(NN + 3) / 4, 256, 0, stream>>>(hb, ssrc, deg, inc, hs, hd, gat2_b, x2b);

  // ---- transformer (chunked) ----
  for (int n0 = 0; n0 < NN; n0 += cn) {
    int c = NN - n0 < cn ? NN - n0 : cn;
    int Mch = 3 * c;
    int mblk48 = (Mch + 47) / 48;
    int mblk128 = (Mch + 127) / 128;
    k_seqbuild<<<(c * 3 * DD + 255) / 256, 256, 0, stream>>>(x1b, x2b, cls, pos, seqc, n0, c);
    for (int l = 0; l < 2; ++l) {
      // qkv: N=768, K=256 (raw q|k|v, no separate attention pass)
      gemm(seqc, DD, wb_qkv + (size_t)l * 768 * 256, bqkv + l * 768,
           qkvb, 768, Mch, 768, DD, 0);
      // fused attention + o-proj + residual + ln1
      k_oproj<<<mblk48, 256, 0, stream>>>(
          qkvb, wb_o + (size_t)l * 256 * 256, bo + l * 256,
          ln1_g + l * 256, ln1_b + l * 256, seqc, Mch);
      // fused ff1+relu+ff2+residual+ln2 (no global intermediate)
      k_ff<<<mblk128, 512, 0, stream>>>(
          seqc, wb_f1 + (size_t)l * 1024 * 256, bff1 + l * 1024,
          wb_f2 + (size_t)l * 256 * 1024, bff2 + l * 256,
          ln2_g + l * 256, ln2_b + l * 256, Mch);
    }
    k_final<<<(c + 3) / 4, 256, 0, stream>>>(seqc, n0, c, norm_g, norm_b, out);
  }
}

// Round 8
// 2053.671 us; speedup vs baseline: 1.1205x; 1.1194x over previous
//
#include <hip/hip_runtime.h>
#include <hip/hip_bf16.h>

#define NN  50000
#define EE  320000
#define E2  (EE + NN)
#define DIN 128
#define DD  256

typedef __attribute__((ext_vector_type(8))) short          bf16x8;
typedef __attribute__((ext_vector_type(8))) unsigned short u16x8;
typedef __attribute__((ext_vector_type(4))) float          f32x4;

// ---------------- helpers ----------------

static __device__ __forceinline__ float bf2f(unsigned short u) {
  return __builtin_bit_cast(float, (unsigned)u << 16);
}

static __device__ __forceinline__ unsigned short f2bf(float f) {
  unsigned u = __builtin_bit_cast(unsigned, f);
  return (unsigned short)((u + 0x7fffu + ((u >> 16) & 1u)) >> 16);
}

static __device__ __forceinline__ void load_lds16(const void* g, void* l) {
  __builtin_amdgcn_global_load_lds(
      (const __attribute__((address_space(1))) void*)g,
      (__attribute__((address_space(3))) void*)l, 16, 0, 0);
}

static __device__ __forceinline__ float wredsum(float v) {
  for (int o = 32; o; o >>= 1) v += __shfl_xor(v, o);
  return v;
}

// ---------------- weight/activation cast fp32 -> bf16 ----------------

__global__ void k_cast(const float* __restrict__ in, unsigned short* __restrict__ out, int n) {
  int i = blockIdx.x * blockDim.x + threadIdx.x;
  if (i >= n) return;
  out[i] = f2bf(in[i]);
}

// ---------------- CSR build ----------------

__global__ void k_deg(const int* __restrict__ ei, int* __restrict__ deg) {
  int i = blockIdx.x * blockDim.x + threadIdx.x;
  if (i >= E2) return;
  int dst = (i < EE) ? ei[EE + i] : (i - EE);
  atomicAdd(&deg[dst], 1);
}

__global__ __launch_bounds__(1024) void k_scan_tile(const int* __restrict__ in,
                                                    int* __restrict__ out,
                                                    int* __restrict__ tsum, int n) {
  __shared__ int sm[1024];
  int tid = threadIdx.x;
  int g = blockIdx.x * 1024 + tid;
  sm[tid] = (g < n) ? in[g] : 0;
  __syncthreads();
  for (int off = 1; off < 1024; off <<= 1) {
    int t = (tid >= off) ? sm[tid - off] : 0;
    __syncthreads();
    sm[tid] += t;
    __syncthreads();
  }
  if (g < n) out[g] = sm[tid];
  if (tid == 1023) tsum[blockIdx.x] = sm[1023];
}

__global__ void k_scan_sums(int* __restrict__ tsum, int nb) {
  int tid = threadIdx.x;           // single wave of 64, nb <= 64
  int v = (tid < nb) ? tsum[tid] : 0;
  for (int off = 1; off < 64; off <<= 1) {
    int t = __shfl_up(v, off);
    if (tid >= off) v += t;
  }
  if (tid < nb) tsum[tid] = v;
}

__global__ void k_scan_add(int* __restrict__ out, const int* __restrict__ tsum, int n) {
  int g = blockIdx.x * blockDim.x + threadIdx.x;
  if (g >= n || g < 1024) return;
  out[g] += tsum[(g >> 10) - 1];
}

__global__ void k_scatter(const int* __restrict__ ei, const int* __restrict__ deg,
                          const int* __restrict__ inc, int* __restrict__ cur,
                          int* __restrict__ ssrc) {
  int i = blockIdx.x * blockDim.x + threadIdx.x;
  if (i >= E2) return;
  int src, dst;
  if (i < EE) { src = ei[i]; dst = ei[EE + i]; } else { src = dst = i - EE; }
  int pos = atomicAdd(&cur[dst], 1);
  ssrc[inc[dst] - deg[dst] + pos] = src;
}

// ---------------- GAT pieces (h in bf16) ----------------

__global__ __launch_bounds__(256) void k_dots(const unsigned short* __restrict__ hb,
                                              const float* __restrict__ asrc,
                                              const float* __restrict__ adst,
                                              float* __restrict__ hs, float* __restrict__ hd) {
  int node = blockIdx.x * 4 + (threadIdx.x >> 6);
  if (node >= NN) return;
  int lane = threadIdx.x & 63;
  ushort4 hv = *reinterpret_cast<const ushort4*>(hb + (size_t)node * DD + lane * 4);
  float v0 = bf2f(hv.x), v1 = bf2f(hv.y), v2 = bf2f(hv.z), v3 = bf2f(hv.w);
  const float* as = asrc + lane * 4;
  const float* ad = adst + lane * 4;
  float s1 = v0 * as[0] + v1 * as[1] + v2 * as[2] + v3 * as[3];
  float s2 = v0 * ad[0] + v1 * ad[1] + v2 * ad[2] + v3 * ad[3];
  for (int off = 32; off; off >>= 1) {
    s1 += __shfl_xor(s1, off);
    s2 += __shfl_xor(s2, off);
  }
  if (lane == 0) { hs[node] = s1; hd[node] = s2; }
}

// Fused edge-softmax + aggregation: one wave per dst node.
__global__ __launch_bounds__(256) void k_gat(const unsigned short* __restrict__ hb,
                                             const int* __restrict__ ssrc,
                                             const int* __restrict__ deg,
                                             const int* __restrict__ inc,
                                             const float* __restrict__ hs,
                                             const float* __restrict__ hd,
                                             const float* __restrict__ bias,
                                             unsigned short* __restrict__ out) {
  __shared__ float sE[4][256];
  __shared__ int   sI[4][256];
  int w = threadIdx.x >> 6;
  int d = blockIdx.x * 4 + w;
  if (d >= NN) return;
  int lane = threadIdx.x & 63;
  int end = inc[d], cnt = deg[d], base = end - cnt;
  if (cnt > 256) cnt = 256;
  float hdd = hd[d];

  float m = -1e30f;
  for (int i0 = 0; i0 < cnt; i0 += 64) {
    int i = i0 + lane;
    float sc = -1e30f;
    if (i < cnt) {
      int s = ssrc[base + i];
      float v = hs[s] + hdd;
      sc = (v < 0.f) ? 0.2f * v : v;
      sI[w][i] = s;
      sE[w][i] = sc;
    }
    float mm = sc;
    for (int o = 32; o; o >>= 1) mm = fmaxf(mm, __shfl_xor(mm, o));
    m = fmaxf(m, mm);
  }
  float sum = 0.f;
  for (int i0 = 0; i0 < cnt; i0 += 64) {
    int i = i0 + lane;
    float e = 0.f;
    if (i < cnt) {
      e = __expf(sE[w][i] - m);
      sE[w][i] = e;
    }
    for (int o = 32; o; o >>= 1) e += __shfl_xor(e, o);
    sum += e;
  }
  float inv = 1.f / sum;

  float a0 = 0.f, a1 = 0.f, a2 = 0.f, a3 = 0.f;
  for (int i = 0; i < cnt; ++i) {
    float a = sE[w][i];
    int s = sI[w][i];
    ushort4 hv = *reinterpret_cast<const ushort4*>(hb + (size_t)s * DD + lane * 4);
    a0 += a * bf2f(hv.x);
    a1 += a * bf2f(hv.y);
    a2 += a * bf2f(hv.z);
    a3 += a * bf2f(hv.w);
  }
  const float* bp = bias + lane * 4;
  float r0 = a0 * inv + bp[0], r1 = a1 * inv + bp[1];
  float r2 = a2 * inv + bp[2], r3 = a3 * inv + bp[3];
  ushort4 o;
  o.x = f2bf(r0 > 0.f ? r0 : 0.f);
  o.y = f2bf(r1 > 0.f ? r1 : 0.f);
  o.z = f2bf(r2 > 0.f ? r2 : 0.f);
  o.w = f2bf(r3 > 0.f ? r3 : 0.f);
  *reinterpret_cast<ushort4*>(out + (size_t)d * DD + lane * 4) = o;
}

// LDS k-chunk swizzle (bank-conflict-free fragment reads):
// LDS slot (row, c) holds global k-chunk  c ^ ((row>>1)&3)  within each 32-k group.
// Fragment read of logical chunk q at row (16-aligned base + m_lane):
//   position = q ^ ((m_lane>>1)&3).
// Row stride MUST be 64 B ([*][32 shorts]) for conflict-free b128 reads.

// ---------------- LDS-staged bf16 MFMA GEMM, XCD-swizzled grid ----------------
// C = act(A @ B^T + bias);  A bf16 [M x K] lda, B bf16 [N x K], C bf16 [M x ldc].
// 128x128 tile, BK=32, 4 waves, double-buffered staging.

__global__ __launch_bounds__(256) void k_gemm128(
    const unsigned short* __restrict__ A, int lda,
    const unsigned short* __restrict__ B,
    const float* __restrict__ bias,
    unsigned short* __restrict__ C, int ldc,
    int M, int N, int K, int act) {
  __shared__ unsigned short As[2][128 * 32];
  __shared__ unsigned short Bs[2][128 * 32];

  const int id  = blockIdx.y * gridDim.x + blockIdx.x;
  const int nn  = gridDim.x;
  const int sid = id >> 3;
  const int jn  = sid % nn;
  const int im  = (id & 7) + ((sid / nn) << 3);
  if (im >= ((M + 127) >> 7)) return;
  const int m0 = im * 128;
  const int n0 = jn * 128;

  const int tid    = threadIdx.x;
  const int lane   = tid & 63;
  const int w      = tid >> 6;
  const int m_lane = lane & 15;
  const int quad   = lane >> 4;
  const int wm     = (w >> 1) * 64;
  const int wn     = (w & 1) * 64;

  const int idx0 = tid, idx1 = 256 + tid;
  const int kc = (((tid & 3) ^ ((tid >> 3) & 3))) * 8;   // same for idx0/idx1
  int rowA0 = m0 + (idx0 >> 2); if (rowA0 >= M) rowA0 = M - 1;
  int rowA1 = m0 + (idx1 >> 2); if (rowA1 >= M) rowA1 = M - 1;
  const unsigned short* gA0 = A + (size_t)rowA0 * lda + kc;
  const unsigned short* gA1 = A + (size_t)rowA1 * lda + kc;
  const unsigned short* gB0 = B + (size_t)(n0 + (idx0 >> 2)) * K + kc;
  const unsigned short* gB1 = B + (size_t)(n0 + (idx1 >> 2)) * K + kc;

  const int la0 = (w * 64) * 8;          // LDS slot offsets (shorts)
  const int la1 = (256 + w * 64) * 8;

  const int swz = (quad ^ ((m_lane >> 1) & 3)) * 8;

  f32x4 acc[4][4] = {};

  const int nk = K >> 5;

  // prologue: stage k-tile 0 into buffer 0
  load_lds16(gA0, &As[0][la0]);
  load_lds16(gA1, &As[0][la1]);
  load_lds16(gB0, &Bs[0][la0]);
  load_lds16(gB1, &Bs[0][la1]);
  gA0 += 32; gA1 += 32; gB0 += 32; gB1 += 32;
  __syncthreads();

  int cur = 0;
  for (int t = 0; t < nk; ++t) {
    if (t + 1 < nk) {   // issue next-tile stage BEFORE compute of current tile
      load_lds16(gA0, &As[cur ^ 1][la0]);
      load_lds16(gA1, &As[cur ^ 1][la1]);
      load_lds16(gB0, &Bs[cur ^ 1][la0]);
      load_lds16(gB1, &Bs[cur ^ 1][la1]);
      gA0 += 32; gA1 += 32; gB0 += 32; gB1 += 32;
    }
    bf16x8 af[4], bg[4];
#pragma unroll
    for (int i = 0; i < 4; ++i)
      af[i] = *reinterpret_cast<const bf16x8*>(&As[cur][(wm + i * 16 + m_lane) * 32 + swz]);
#pragma unroll
    for (int j = 0; j < 4; ++j)
      bg[j] = *reinterpret_cast<const bf16x8*>(&Bs[cur][(wn + j * 16 + m_lane) * 32 + swz]);
#pragma unroll
    for (int i = 0; i < 4; ++i)
#pragma unroll
      for (int j = 0; j < 4; ++j)
        acc[i][j] = __builtin_amdgcn_mfma_f32_16x16x32_bf16(af[i], bg[j], acc[i][j], 0, 0, 0);
    __syncthreads();   // drains this iter's stage (vmcnt) after MFMA work hid it
    cur ^= 1;
  }

#pragma unroll
  for (int i = 0; i < 4; ++i) {
#pragma unroll
    for (int j = 0; j < 4; ++j) {
      int col = n0 + wn + j * 16 + m_lane;
      float bv = bias ? bias[col] : 0.f;
#pragma unroll
      for (int r = 0; r < 4; ++r) {
        int row = m0 + wm + i * 16 + quad * 4 + r;
        if (row < M) {
          float v = acc[i][j][r] + bv;
          if (act) v = v > 0.f ? v : 0.f;
          C[(size_t)row * ldc + col] = f2bf(v);
        }
      }
    }
  }
}

// ---------------- fused attention + o-proj + bias + residual + LayerNorm ----------
// 48-row blocks = 16 nodes, 256 thr / 4 waves.
// Phase 1: per-node 4-head 3x3 attention from raw qkvb rows (lane = head dim),
//          mixed rows written bf16 into swizzled k-grouped As tile.
// Phase 2: [48x256] @ Wo^T (K=256, dbuf B panels) + bo + residual(seqc) + LN.

__global__ __launch_bounds__(256) void k_oproj(
    const unsigned short* __restrict__ qkvb,   // [M x 768] raw q|k|v
    const unsigned short* __restrict__ Wo,     // [256 x 256]
    const float* __restrict__ bo,
    const float* __restrict__ gam, const float* __restrict__ bet,
    unsigned short* __restrict__ seqc,         // residual in / out, [M x 256]
    int M) {
  __shared__ unsigned short As[8 * 48 * 32];   // 24 KB attention-out, [kgrp][row][32]
  __shared__ unsigned short Bs[2][256 * 32];   // 32 KB Wo k-panels
  __shared__ float sSum[4 * 48];
  __shared__ float sSq[4 * 48];

  const int tid  = threadIdx.x;
  const int lane = tid & 63;
  const int w    = tid >> 6;
  const int ml   = lane & 15;
  const int quad = lane >> 4;
  const int m0   = blockIdx.x * 48;
  const int swz  = (quad ^ ((ml >> 1) & 3)) * 8;

  // ---- issue Wo panel-0 stage first (latency hides under attention phase) ----
  const int kcs = ((tid & 3) ^ ((tid >> 3) & 3)) * 8;
  const unsigned short* gB0 = Wo + (size_t)((0 * 256 + tid) >> 2) * 256 + kcs;
  const unsigned short* gB1 = Wo + (size_t)((1 * 256 + tid) >> 2) * 256 + kcs;
  const unsigned short* gB2 = Wo + (size_t)((2 * 256 + tid) >> 2) * 256 + kcs;
  const unsigned short* gB3 = Wo + (size_t)((3 * 256 + tid) >> 2) * 256 + kcs;
  const int lb0 = (0 * 256 + w * 64) * 8;
  const int lb1 = (1 * 256 + w * 64) * 8;
  const int lb2 = (2 * 256 + w * 64) * 8;
  const int lb3 = (3 * 256 + w * 64) * 8;
  load_lds16(gB0, &Bs[0][lb0]);
  load_lds16(gB1, &Bs[0][lb1]);
  load_lds16(gB2, &Bs[0][lb2]);
  load_lds16(gB3, &Bs[0][lb3]);
  gB0 += 32; gB1 += 32; gB2 += 32; gB3 += 32;

  // ---- phase 1: attention for this wave's 4 nodes (lane = head-dim d) ----
  const int d = lane;
  for (int i = 0; i < 4; ++i) {
    int r0 = (w * 4 + i) * 3;                  // local row of token 0
    size_t rowg[3];
#pragma unroll
    for (int t = 0; t < 3; ++t) {
      int rg = m0 + r0 + t;
      rowg[t] = (size_t)(rg < M ? rg : M - 1);
    }
#pragma unroll
    for (int h = 0; h < 4; ++h) {
      float q[3], k[3], v[3];
#pragma unroll
      for (int t = 0; t < 3; ++t) {
        size_t base = rowg[t] * 768 + h * 64 + d;
        q[t] = bf2f(qkvb[base]);
        k[t] = bf2f(qkvb[base + 256]);
        v[t] = bf2f(qkvb[base + 512]);
      }
      float l[3][3];
#pragma unroll
      for (int a = 0; a < 3; ++a)
#pragma unroll
        for (int b = 0; b < 3; ++b)
          l[a][b] = wredsum(q[a] * k[b]) * 0.125f;
#pragma unroll
      for (int a = 0; a < 3; ++a) {
        float mx = fmaxf(l[a][0], fmaxf(l[a][1], l[a][2]));
        float e0 = __expf(l[a][0] - mx);
        float e1 = __expf(l[a][1] - mx);
        float e2 = __expf(l[a][2] - mx);
        float inv = 1.f / (e0 + e1 + e2);
        float o = (e0 * v[0] + e1 * v[1] + e2 * v[2]) * inv;
        int row = r0 + a;
        int col = h * 64 + d;
        int g = col >> 5, c = (col >> 3) & 3;
        As[((g * 48 + row) * 32) + ((c ^ ((row >> 1) & 3)) << 3) + (col & 7)] = f2bf(o);
      }
    }
  }
  __syncthreads();   // As complete; Bs[0] stage drained

  // ---- phase 2: GEMM [48 x 256] @ Wo^T, K=256 in 8 panels, dbuf B ----
  f32x4 acc[3][4] = {};
  int cur = 0;
  for (int t = 0; t < 8; ++t) {
    if (t + 1 < 8) {
      load_lds16(gB0, &Bs[cur ^ 1][lb0]);
      load_lds16(gB1, &Bs[cur ^ 1][lb1]);
      load_lds16(gB2, &Bs[cur ^ 1][lb2]);
      load_lds16(gB3, &Bs[cur ^ 1][lb3]);
      gB0 += 32; gB1 += 32; gB2 += 32; gB3 += 32;
    }
    bf16x8 af[3], bg[4];
#pragma unroll
    for (int i = 0; i < 3; ++i)
      af[i] = *reinterpret_cast<const bf16x8*>(&As[(t * 48 + i * 16 + ml) * 32 + swz]);
#pragma unroll
    for (int j = 0; j < 4; ++j)
      bg[j] = *reinterpret_cast<const bf16x8*>(&Bs[cur][(w * 64 + j * 16 + ml) * 32 + swz]);
#pragma unroll
    for (int i = 0; i < 3; ++i)
#pragma unroll
      for (int j = 0; j < 4; ++j)
        acc[i][j] = __builtin_amdgcn_mfma_f32_16x16x32_bf16(af[i], bg[j], acc[i][j], 0, 0, 0);
    __syncthreads();
    cur ^= 1;
  }

  // ---- bias + residual + per-row partial stats over this wave's 64 cols ----
  float bov[4], gv[4], btv[4];
#pragma unroll
  for (int j = 0; j < 4; ++j) {
    int col = w * 64 + j * 16 + ml;
    bov[j] = bo[col]; gv[j] = gam[col]; btv[j] = bet[col];
  }

#pragma unroll
  for (int i = 0; i < 3; ++i)
#pragma unroll
    for (int r = 0; r < 4; ++r) {
      int row = i * 16 + quad * 4 + r;
      int rg = m0 + row;
      size_t rr2 = (size_t)(rg < M ? rg : M - 1);
      float s = 0.f, s2 = 0.f;
#pragma unroll
      for (int j = 0; j < 4; ++j) {
        int col = w * 64 + j * 16 + ml;
        float t = acc[i][j][r] + bov[j] + bf2f(seqc[rr2 * 256 + col]);
        acc[i][j][r] = t;
        s += t; s2 += t * t;
      }
#pragma unroll
      for (int o = 1; o < 16; o <<= 1) { s += __shfl_xor(s, o); s2 += __shfl_xor(s2, o); }
      if (ml == 0) { sSum[w * 48 + row] = s; sSq[w * 48 + row] = s2; }
    }
  __syncthreads();

#pragma unroll
  for (int i = 0; i < 3; ++i)
#pragma unroll
    for (int r = 0; r < 4; ++r) {
      int row = i * 16 + quad * 4 + r;
      int rg = m0 + row;
      if (rg >= M) continue;
      float s  = sSum[row] + sSum[48 + row] + sSum[96 + row] + sSum[144 + row];
      float s2 = sSq[row]  + sSq[48 + row]  + sSq[96 + row]  + sSq[144 + row];
      float mean = s * (1.f / 256.f);
      float var  = s2 * (1.f / 256.f) - mean * mean;
      float inv  = rsqrtf(var + 1e-5f);
#pragma unroll
      for (int j = 0; j < 4; ++j) {
        int col = w * 64 + j * 16 + ml;
        seqc[(size_t)rg * 256 + col] = f2bf((acc[i][j][r] - mean) * inv * gv[j] + btv[j]);
      }
    }
}

// ---------------- fused FFN: relu(A@W1^T+b1)@W2^T + b2 + residual(A) + LN ----------
// A = seqc [M x 256] bf16, in-place. W1 [1024 x 256], W2 [256 x 1024] bf16.
// 80-ROW tile, 8 waves (512 thr), LDS = As 40 KB + Hs 40 KB = 80 KB
// -> EXACTLY 2 co-resident blocks/CU (160 KB), grid 469 -> max 2 blocks/CU.
// Both throughput hypotheses (stall-filling pairs / balance) predict ~75-85 us
// per dispatch vs 119 at 128-row. LN scratch MUST alias Hs (keeps 80 KB).
// K-grouped [8 grp][80 row][32] layout (row stride 64 B, conflict-free).

__global__ __launch_bounds__(512, 4) void k_ff(
    unsigned short* __restrict__ A,
    const unsigned short* __restrict__ W1,
    const float* __restrict__ b1,
    const unsigned short* __restrict__ W2,
    const float* __restrict__ b2,
    const float* __restrict__ gam, const float* __restrict__ bet,
    int M) {
  __shared__ unsigned short As[8 * 80 * 32];   // 40 KB  [kgrp][row][32]
  __shared__ unsigned short Hs[8 * 80 * 32];   // 40 KB  (reused as LN scratch)

  const int tid  = threadIdx.x;
  const int lane = tid & 63;
  const int w    = tid >> 6;        // 0..7
  const int ml   = lane & 15;
  const int quad = lane >> 4;
  const int m0   = blockIdx.x * 80;
  const int swz  = (quad ^ ((ml >> 1) & 3)) << 3;

  // ---- stage A tile 80x256: threads 0..319 own (row = tid>>2, chunk = tid&3)
  //      per k-group; waves 0..4 stage (wave-uniform LDS base w*512 shorts).
  if (tid < 320) {
    int rg = m0 + (tid >> 2); if (rg >= M) rg = M - 1;
    int cs = (tid & 3) ^ ((tid >> 3) & 3);
    const unsigned short* gsrc = A + (size_t)rg * 256 + (cs << 3);
    unsigned short* ldst = As + (size_t)(w * 64) * 8;   // HW adds lane*16B
#pragma unroll
    for (int g = 0; g < 8; ++g)
      load_lds16(gsrc + (g << 5), ldst + (size_t)g * 2560);
  }
  __syncthreads();

  f32x4 acc2[5][2] = {};

  for (int kb = 0; kb < 4; ++kb) {
    // ---- GEMM1: wave w computes H^T for hidden rows kb*256 + w*32 .. +31
    //      over all 80 seq rows (5 j-frags)
    f32x4 acc1[2][5] = {};
    const unsigned short* W1p = W1 + (size_t)(kb * 256 + w * 32 + ml) * 256 + quad * 8;
#pragma unroll 2
    for (int ks = 0; ks < 8; ++ks) {
      bf16x8 af[2], bg[5];
#pragma unroll
      for (int i = 0; i < 2; ++i)
        af[i] = *reinterpret_cast<const bf16x8*>(W1p + (size_t)i * 16 * 256 + ks * 32);
#pragma unroll
      for (int j = 0; j < 5; ++j)
        bg[j] = *reinterpret_cast<const bf16x8*>(&As[ks * 2560 + (j * 16 + ml) * 32 + swz]);
#pragma unroll
      for (int i = 0; i < 2; ++i)
#pragma unroll
        for (int j = 0; j < 5; ++j)
          acc1[i][j] = __builtin_amdgcn_mfma_f32_16x16x32_bf16(af[i], bg[j], acc1[i][j], 0, 0, 0);
    }

    __syncthreads();   // previous GEMM2 readers of Hs are done

    // ---- relu(acc1 + b1) -> Hs: wave w owns hidden k-group w (hidden w*32..+31)
#pragma unroll
    for (int i = 0; i < 2; ++i) {
      float4 bv = *reinterpret_cast<const float4*>(b1 + kb * 256 + w * 32 + i * 16 + quad * 4);
      int c  = i * 2 + (quad >> 1);
      int lo = (quad & 1) * 4;
#pragma unroll
      for (int j = 0; j < 5; ++j) {
        int seqrow = j * 16 + ml;
        int chsw = c ^ ((ml >> 1) & 3);
        int addr = w * 2560 + seqrow * 32 + (chsw << 3) + lo;
        float t0 = acc1[i][j][0] + bv.x; t0 = t0 > 0.f ? t0 : 0.f;
        float t1 = acc1[i][j][1] + bv.y; t1 = t1 > 0.f ? t1 : 0.f;
        float t2 = acc1[i][j][2] + bv.z; t2 = t2 > 0.f ? t2 : 0.f;
        float t3 = acc1[i][j][3] + bv.w; t3 = t3 > 0.f ? t3 : 0.f;
        ushort4 hv;
        hv.x = f2bf(t0); hv.y = f2bf(t1); hv.z = f2bf(t2); hv.w = f2bf(t3);
        *reinterpret_cast<ushort4*>(&Hs[addr]) = hv;
      }
    }
    __syncthreads();   // Hs visible to all waves

    // ---- GEMM2: acc2 += H @ W2slice^T; wave w owns out-cols w*32..+31,
    //      all 80 rows (5 i-frags)
    const unsigned short* W2p = W2 + (size_t)(w * 32 + ml) * 1024 + kb * 256 + quad * 8;
#pragma unroll 2
    for (int ks = 0; ks < 8; ++ks) {
      bf16x8 af[5], bg[2];
#pragma unroll
      for (int i = 0; i < 5; ++i)
        af[i] = *reinterpret_cast<const bf16x8*>(&Hs[ks * 2560 + (i * 16 + ml) * 32 + swz]);
#pragma unroll
      for (int j = 0; j < 2; ++j)
        bg[j] = *reinterpret_cast<const bf16x8*>(W2p + (size_t)j * 16 * 1024 + ks * 32);
#pragma unroll
      for (int i = 0; i < 5; ++i)
#pragma unroll
        for (int j = 0; j < 2; ++j)
          acc2[i][j] = __builtin_amdgcn_mfma_f32_16x16x32_bf16(af[i], bg[j], acc2[i][j], 0, 0, 0);
    }
  }

  __syncthreads();   // all Hs reads done -> reuse Hs as LN scratch
  float* sS = reinterpret_cast<float*>(Hs);   // [8][80]
  float* sQ = sS + 640;                        // [8][80]

  float b2v[2], gv[2], btv[2];
#pragma unroll
  for (int j = 0; j < 2; ++j) {
    int col = w * 32 + j * 16 + ml;
    b2v[j] = b2[col]; gv[j] = gam[col]; btv[j] = bet[col];
  }

  // bias + residual (from As LDS) + per-row partial stats over this wave's 32 cols
#pragma unroll
  for (int i = 0; i < 5; ++i)
#pragma unroll
    for (int r = 0; r < 4; ++r) {
      int row = i * 16 + quad * 4 + r;
      float s = 0.f, s2 = 0.f;
#pragma unroll
      for (int j = 0; j < 2; ++j) {
        int c_r = j * 2 + (ml >> 3);
        float t = acc2[i][j][r] + b2v[j] +
                  bf2f(As[w * 2560 + row * 32 + ((c_r ^ ((row >> 1) & 3)) << 3) + (ml & 7)]);
        acc2[i][j][r] = t;
        s += t; s2 += t * t;
      }
#pragma unroll
      for (int o = 1; o < 16; o <<= 1) { s += __shfl_xor(s, o); s2 += __shfl_xor(s2, o); }
      if (ml == 0) { sS[w * 80 + row] = s; sQ[w * 80 + row] = s2; }
    }
  __syncthreads();

#pragma unroll
  for (int i = 0; i < 5; ++i)
#pragma unroll
    for (int r = 0; r < 4; ++r) {
      int row = i * 16 + quad * 4 + r;
      int rg = m0 + row;
      if (rg >= M) continue;
      float s = 0.f, s2 = 0.f;
#pragma unroll
      for (int ww = 0; ww < 8; ++ww) { s += sS[ww * 80 + row]; s2 += sQ[ww * 80 + row]; }
      float mean = s * (1.f / 256.f);
      float var  = s2 * (1.f / 256.f) - mean * mean;
      float inv  = rsqrtf(var + 1e-5f);
#pragma unroll
      for (int j = 0; j < 2; ++j) {
        int col = w * 32 + j * 16 + ml;
        A[(size_t)rg * 256 + col] = f2bf((acc2[i][j][r] - mean) * inv * gv[j] + btv[j]);
      }
    }
}

// ---------------- transformer pieces (bf16 activations, dense layouts) ----------------

__global__ void k_seqbuild(const unsigned short* __restrict__ x1,
                           const unsigned short* __restrict__ x2,
                           const float* __restrict__ cls, const float* __restrict__ pos,
                           unsigned short* __restrict__ seqc, int n0, int cn) {
  int idx = blockIdx.x * blockDim.x + threadIdx.x;
  int total = cn * 3 * DD;
  if (idx >= total) return;
  int c = idx & (DD - 1);
  int r = idx >> 8;
  int t = r % 3, ln = r / 3;
  int n = n0 + ln;
  float v;
  if (t == 0)      v = cls[c];
  else if (t == 1) v = bf2f(x1[(size_t)n * DD + c]);
  else             v = bf2f(x2[(size_t)n * DD + c]);
  seqc[idx] = f2bf(v + pos[t * DD + c]);
}

__global__ __launch_bounds__(256) void k_final(const unsigned short* __restrict__ seqc,
                                               int n0, int cn,
                                               const float* __restrict__ g,
                                               const float* __restrict__ b,
                                               float* __restrict__ out) {
  int ln = blockIdx.x * 4 + (threadIdx.x >> 6);
  if (ln >= cn) return;
  int lane = threadIdx.x & 63;
  const unsigned short* p = seqc + (size_t)ln * 3 * DD;   // token 0 row
  float v[4];
  float s = 0.f, s2 = 0.f;
#pragma unroll
  for (int i = 0; i < 4; ++i) {
    v[i] = bf2f(p[i * 64 + lane]);
    s += v[i]; s2 += v[i] * v[i];
  }
  for (int off = 32; off; off >>= 1) { s += __shfl_xor(s, off); s2 += __shfl_xor(s2, off); }
  float mean = s * (1.f / 256.f);
  float var  = s2 * (1.f / 256.f) - mean * mean;
  float inv  = rsqrtf(var + 1e-5f);
#pragma unroll
  for (int i = 0; i < 4; ++i) {
    int c = i * 64 + lane;
    out[(size_t)(n0 + ln) * DD + c] = (v[i] - mean) * inv * g[c] + b[c];
  }
}

// ---------------- host ----------------

extern "C" void kernel_launch(void* const* d_in, const int* in_sizes, int n_in,
                              void* d_out, int out_size, void* d_ws, size_t ws_size,
                              hipStream_t stream) {
  const float* x       = (const float*)d_in[0];
  const int*   ei      = (const int*)d_in[1];
  const float* gat1_W  = (const float*)d_in[2];
  const float* gat1_b  = (const float*)d_in[3];
  const float* gat1_as = (const float*)d_in[4];
  const float* gat1_ad = (const float*)d_in[5];
  const float* gat2_W  = (const float*)d_in[6];
  const float* gat2_b  = (const float*)d_in[7];
  const float* gat2_as = (const float*)d_in[8];
  const float* gat2_ad = (const float*)d_in[9];
  const float* cls     = (const float*)d_in[10];
  const float* pos     = (const float*)d_in[11];
  const float* Wqkv    = (const float*)d_in[12];
  const float* bqkv    = (const float*)d_in[13];
  const float* Wo      = (const float*)d_in[14];
  const float* bo      = (const float*)d_in[15];
  const float* ln1_g   = (const float*)d_in[16];
  const float* ln1_b   = (const float*)d_in[17];
  const float* ln2_g   = (const float*)d_in[18];
  const float* ln2_b   = (const float*)d_in[19];
  const float* Wff1    = (const float*)d_in[20];
  const float* bff1    = (const float*)d_in[21];
  const float* Wff2    = (const float*)d_in[22];
  const float* bff2    = (const float*)d_in[23];
  const float* norm_g  = (const float*)d_in[24];
  const float* norm_b  = (const float*)d_in[25];
  float* out = (float*)d_out;

  char* ws = (char*)d_ws;
  size_t off = 0;
  auto alloc = [&](size_t bytes) -> void* {
    off = (off + 255) & ~(size_t)255;
    void* p = ws + off;
    off += bytes;
    return p;
  };

  unsigned short* wb_g1  = (unsigned short*)alloc(sizeof(unsigned short) * 256 * 128);
  unsigned short* wb_g2  = (unsigned short*)alloc(sizeof(unsigned short) * 256 * 256);
  unsigned short* wb_qkv = (unsigned short*)alloc(sizeof(unsigned short) * 2 * 768 * 256);
  unsigned short* wb_o   = (unsigned short*)alloc(sizeof(unsigned short) * 2 * 256 * 256);
  unsigned short* wb_f1  = (unsigned short*)alloc(sizeof(unsigned short) * 2 * 1024 * 256);
  unsigned short* wb_f2  = (unsigned short*)alloc(sizeof(unsigned short) * 2 * 256 * 1024);
  unsigned short* xb  = (unsigned short*)alloc(sizeof(unsigned short) * (size_t)NN * DIN);
  unsigned short* hb  = (unsigned short*)alloc(sizeof(unsigned short) * (size_t)NN * DD);
  unsigned short* x1b = (unsigned short*)alloc(sizeof(unsigned short) * (size_t)NN * DD);
  unsigned short* x2b = (unsigned short*)alloc(sizeof(unsigned short) * (size_t)NN * DD);
  float* hs  = (float*)alloc(sizeof(float) * NN);
  float* hd  = (float*)alloc(sizeof(float) * NN);
  int* deg   = (int*)alloc(sizeof(int) * NN);
  int* inc   = (int*)alloc(sizeof(int) * NN);
  int* cur   = (int*)alloc(sizeof(int) * NN);
  int* tsum  = (int*)alloc(sizeof(int) * 64);
  int* ssrc  = (int*)alloc(sizeof(int) * E2);

  // transformer chunking (L3 residency of per-chunk activations)
  size_t fixed = (off + 255) & ~(size_t)255;
  size_t rem = (ws_size > fixed + 4096) ? (ws_size - fixed - 4096) : 0;
  const size_t per_node = (size_t)3 * (256 + 768) * 2;
  size_t cn_max = rem / per_node;
  if (cn_max < 1) cn_max = 1;
  if (cn_max > 12500) cn_max = 12500;
  int nc = (int)((NN + cn_max - 1) / cn_max);
  int cn = (NN + nc - 1) / nc;
  unsigned short* seqc = (unsigned short*)alloc(sizeof(unsigned short) * (size_t)3 * cn * 256);
  unsigned short* qkvb = (unsigned short*)alloc(sizeof(unsigned short) * (size_t)3 * cn * 768);

  // ---- casts ----
  auto cast = [&](const float* src, unsigned short* dst, int n) {
    k_cast<<<(n + 255) / 256, 256, 0, stream>>>(src, dst, n);
  };
  cast(gat1_W, wb_g1, 256 * 128);
  cast(gat2_W, wb_g2, 256 * 256);
  cast(Wqkv, wb_qkv, 2 * 768 * 256);
  cast(Wo, wb_o, 2 * 256 * 256);
  cast(Wff1, wb_f1, 2 * 1024 * 256);
  cast(Wff2, wb_f2, 2 * 256 * 1024);
  cast(x, xb, NN * DIN);

  // ---- CSR build ----
  hipMemsetAsync(deg, 0, sizeof(int) * NN, stream);
  hipMemsetAsync(cur, 0, sizeof(int) * NN, stream);
  k_deg<<<(E2 + 255) / 256, 256, 0, stream>>>(ei, deg);
  int nb = (NN + 1023) / 1024;
  k_scan_tile<<<nb, 1024, 0, stream>>>(deg, inc, tsum, NN);
  k_scan_sums<<<1, 64, 0, stream>>>(tsum, nb);
  k_scan_add<<<(NN + 255) / 256, 256, 0, stream>>>(inc, tsum, NN);
  k_scatter<<<(E2 + 255) / 256, 256, 0, stream>>>(ei, deg, inc, cur, ssrc);

  auto gemm = [&](const unsigned short* A, int lda, const unsigned short* B,
                  const float* bias, unsigned short* C, int ldc,
                  int M, int N, int K, int act) {
    int nm = (M + 127) / 128;
    int nmp = (nm + 7) & ~7;
    dim3 grid(N / 128, nmp);
    k_gemm128<<<grid, 256, 0, stream>>>(A, lda, B, bias, C, ldc, M, N, K, act);
  };

  // ---- GAT layer 1: hb = xb @ W1^T (K=128) ----
  gemm(xb, DIN, wb_g1, nullptr, hb, DD, NN, DD, DIN, 0);
  k_dots<<<(NN + 3) / 4, 256, 0, stream>>>(hb, gat1_as, gat1_ad, hs, hd);
  k_gat<<<(NN + 3) / 4, 256, 0, stream>>>(hb, ssrc, deg, inc, hs, hd, gat1_b, x1b);

  // ---- GAT layer 2: hb = x1b @ W2^T (K=256) ----
  gemm(x1b, DD, wb_g2, nullptr, hb, DD, NN, DD, DD, 0);
  k_dots<<<(NN + 3) / 4, 256, 0, stream>>>(hb, gat2_as, gat2_ad, hs, hd);
  k_gat<<<(NN + 3) / 4, 256, 0, stream>>>(hb, ssrc, deg, inc, hs, hd, gat2_b, x2b);

  // ---- transformer (chunked) ----
  for (int n0 = 0; n0 < NN; n0 += cn) {
    int c = NN - n0 < cn ? NN - n0 : cn;
    int Mch = 3 * c;
    int mblk48 = (Mch + 47) / 48;
    int mblk80 = (Mch + 79) / 80;
    k_seqbuild<<<(c * 3 * DD + 255) / 256, 256, 0, stream>>>(x1b, x2b, cls, pos, seqc, n0, c);
    for (int l = 0; l < 2; ++l) {
      // qkv: N=768, K=256 (raw q|k|v, no separate attention pass)
      gemm(seqc, DD, wb_qkv + (size_t)l * 768 * 256, bqkv + l * 768,
           qkvb, 768, Mch, 768, DD, 0);
      // fused attention + o-proj + residual + ln1
      k_oproj<<<mblk48, 256, 0, stream>>>(
          qkvb, wb_o + (size_t)l * 256 * 256, bo + l * 256,
          ln1_g + l * 256, ln1_b + l * 256, seqc, Mch);
      // fused ff1+relu+ff2+residual+ln2 (no global intermediate), 80-row tiles
      k_ff<<<mblk80, 512, 0, stream>>>(
          seqc, wb_f1 + (size_t)l * 1024 * 256, bff1 + l * 1024,
          wb_f2 + (size_t)l * 256 * 1024, bff2 + l * 256,
          ln2_g + l * 256, ln2_b + l * 256, Mch);
    }
    k_final<<<(c + 3) / 4, 256, 0, stream>>>(seqc, n0, c, norm_g, norm_b, out);
  }
}

// Round 10
// 1965.069 us; speedup vs baseline: 1.1710x; 1.0451x over previous
//
#include <hip/hip_runtime.h>
#include <hip/hip_bf16.h>

#define NN  50000
#define EE  320000
#define E2  (EE + NN)
#define DIN 128
#define DD  256

typedef __attribute__((ext_vector_type(8))) short          bf16x8;
typedef __attribute__((ext_vector_type(8))) unsigned short u16x8;
typedef __attribute__((ext_vector_type(4))) float          f32x4;

// ---------------- helpers ----------------

static __device__ __forceinline__ float bf2f(unsigned short u) {
  return __builtin_bit_cast(float, (unsigned)u << 16);
}

static __device__ __forceinline__ unsigned short f2bf(float f) {
  unsigned u = __builtin_bit_cast(unsigned, f);
  return (unsigned short)((u + 0x7fffu + ((u >> 16) & 1u)) >> 16);
}

static __device__ __forceinline__ void load_lds16(const void* g, void* l) {
  __builtin_amdgcn_global_load_lds(
      (const __attribute__((address_space(1))) void*)g,
      (__attribute__((address_space(3))) void*)l, 16, 0, 0);
}

static __device__ __forceinline__ float wredsum(float v) {
  for (int o = 32; o; o >>= 1) v += __shfl_xor(v, o);
  return v;
}

// ---------------- weight/activation cast fp32 -> bf16 ----------------

__global__ void k_cast(const float* __restrict__ in, unsigned short* __restrict__ out, int n) {
  int i = blockIdx.x * blockDim.x + threadIdx.x;
  if (i >= n) return;
  out[i] = f2bf(in[i]);
}

// ---------------- CSR build ----------------

__global__ void k_deg(const int* __restrict__ ei, int* __restrict__ deg) {
  int i = blockIdx.x * blockDim.x + threadIdx.x;
  if (i >= E2) return;
  int dst = (i < EE) ? ei[EE + i] : (i - EE);
  atomicAdd(&deg[dst], 1);
}

__global__ __launch_bounds__(1024) void k_scan_tile(const int* __restrict__ in,
                                                    int* __restrict__ out,
                                                    int* __restrict__ tsum, int n) {
  __shared__ int sm[1024];
  int tid = threadIdx.x;
  int g = blockIdx.x * 1024 + tid;
  sm[tid] = (g < n) ? in[g] : 0;
  __syncthreads();
  for (int off = 1; off < 1024; off <<= 1) {
    int t = (tid >= off) ? sm[tid - off] : 0;
    __syncthreads();
    sm[tid] += t;
    __syncthreads();
  }
  if (g < n) out[g] = sm[tid];
  if (tid == 1023) tsum[blockIdx.x] = sm[1023];
}

__global__ void k_scan_sums(int* __restrict__ tsum, int nb) {
  int tid = threadIdx.x;           // single wave of 64, nb <= 64
  int v = (tid < nb) ? tsum[tid] : 0;
  for (int off = 1; off < 64; off <<= 1) {
    int t = __shfl_up(v, off);
    if (tid >= off) v += t;
  }
  if (tid < nb) tsum[tid] = v;
}

__global__ void k_scan_add(int* __restrict__ out, const int* __restrict__ tsum, int n) {
  int g = blockIdx.x * blockDim.x + threadIdx.x;
  if (g >= n || g < 1024) return;
  out[g] += tsum[(g >> 10) - 1];
}

__global__ void k_scatter(const int* __restrict__ ei, const int* __restrict__ deg,
                          const int* __restrict__ inc, int* __restrict__ cur,
                          int* __restrict__ ssrc) {
  int i = blockIdx.x * blockDim.x + threadIdx.x;
  if (i >= E2) return;
  int src, dst;
  if (i < EE) { src = ei[i]; dst = ei[EE + i]; } else { src = dst = i - EE; }
  int pos = atomicAdd(&cur[dst], 1);
  ssrc[inc[dst] - deg[dst] + pos] = src;
}

// ---------------- GAT pieces (h in bf16) ----------------

__global__ __launch_bounds__(256) void k_dots(const unsigned short* __restrict__ hb,
                                              const float* __restrict__ asrc,
                                              const float* __restrict__ adst,
                                              float* __restrict__ hs, float* __restrict__ hd) {
  int node = blockIdx.x * 4 + (threadIdx.x >> 6);
  if (node >= NN) return;
  int lane = threadIdx.x & 63;
  ushort4 hv = *reinterpret_cast<const ushort4*>(hb + (size_t)node * DD + lane * 4);
  float v0 = bf2f(hv.x), v1 = bf2f(hv.y), v2 = bf2f(hv.z), v3 = bf2f(hv.w);
  const float* as = asrc + lane * 4;
  const float* ad = adst + lane * 4;
  float s1 = v0 * as[0] + v1 * as[1] + v2 * as[2] + v3 * as[3];
  float s2 = v0 * ad[0] + v1 * ad[1] + v2 * ad[2] + v3 * ad[3];
  for (int off = 32; off; off >>= 1) {
    s1 += __shfl_xor(s1, off);
    s2 += __shfl_xor(s2, off);
  }
  if (lane == 0) { hs[node] = s1; hd[node] = s2; }
}

// Fused edge-softmax + aggregation: one wave per dst node.
__global__ __launch_bounds__(256) void k_gat(const unsigned short* __restrict__ hb,
                                             const int* __restrict__ ssrc,
                                             const int* __restrict__ deg,
                                             const int* __restrict__ inc,
                                             const float* __restrict__ hs,
                                             const float* __restrict__ hd,
                                             const float* __restrict__ bias,
                                             unsigned short* __restrict__ out) {
  __shared__ float sE[4][256];
  __shared__ int   sI[4][256];
  int w = threadIdx.x >> 6;
  int d = blockIdx.x * 4 + w;
  if (d >= NN) return;
  int lane = threadIdx.x & 63;
  int end = inc[d], cnt = deg[d], base = end - cnt;
  if (cnt > 256) cnt = 256;
  float hdd = hd[d];

  float m = -1e30f;
  for (int i0 = 0; i0 < cnt; i0 += 64) {
    int i = i0 + lane;
    float sc = -1e30f;
    if (i < cnt) {
      int s = ssrc[base + i];
      float v = hs[s] + hdd;
      sc = (v < 0.f) ? 0.2f * v : v;
      sI[w][i] = s;
      sE[w][i] = sc;
    }
    float mm = sc;
    for (int o = 32; o; o >>= 1) mm = fmaxf(mm, __shfl_xor(mm, o));
    m = fmaxf(m, mm);
  }
  float sum = 0.f;
  for (int i0 = 0; i0 < cnt; i0 += 64) {
    int i = i0 + lane;
    float e = 0.f;
    if (i < cnt) {
      e = __expf(sE[w][i] - m);
      sE[w][i] = e;
    }
    for (int o = 32; o; o >>= 1) e += __shfl_xor(e, o);
    sum += e;
  }
  float inv = 1.f / sum;

  float a0 = 0.f, a1 = 0.f, a2 = 0.f, a3 = 0.f;
  for (int i = 0; i < cnt; ++i) {
    float a = sE[w][i];
    int s = sI[w][i];
    ushort4 hv = *reinterpret_cast<const ushort4*>(hb + (size_t)s * DD + lane * 4);
    a0 += a * bf2f(hv.x);
    a1 += a * bf2f(hv.y);
    a2 += a * bf2f(hv.z);
    a3 += a * bf2f(hv.w);
  }
  const float* bp = bias + lane * 4;
  float r0 = a0 * inv + bp[0], r1 = a1 * inv + bp[1];
  float r2 = a2 * inv + bp[2], r3 = a3 * inv + bp[3];
  ushort4 o;
  o.x = f2bf(r0 > 0.f ? r0 : 0.f);
  o.y = f2bf(r1 > 0.f ? r1 : 0.f);
  o.z = f2bf(r2 > 0.f ? r2 : 0.f);
  o.w = f2bf(r3 > 0.f ? r3 : 0.f);
  *reinterpret_cast<ushort4*>(out + (size_t)d * DD + lane * 4) = o;
}

// LDS k-chunk swizzle (bank-conflict-free fragment reads):
// LDS slot (row, c) holds global k-chunk  c ^ ((row>>1)&3)  within each 32-k group.
// Fragment read of logical chunk q at row (16-aligned base + m_lane):
//   position = q ^ ((m_lane>>1)&3).
// Row stride MUST be 64 B ([*][32 shorts]) for conflict-free b128 reads.

// ---------------- LDS-staged bf16 MFMA GEMM, XCD-swizzled grid ----------------
// C = act(A @ B^T + bias);  A bf16 [M x K] lda, B bf16 [N x K], C bf16 [M x ldc].
// 128x128 tile, BK=32, 4 waves, double-buffered staging.

__global__ __launch_bounds__(256) void k_gemm128(
    const unsigned short* __restrict__ A, int lda,
    const unsigned short* __restrict__ B,
    const float* __restrict__ bias,
    unsigned short* __restrict__ C, int ldc,
    int M, int N, int K, int act) {
  __shared__ unsigned short As[2][128 * 32];
  __shared__ unsigned short Bs[2][128 * 32];

  const int id  = blockIdx.y * gridDim.x + blockIdx.x;
  const int nn  = gridDim.x;
  const int sid = id >> 3;
  const int jn  = sid % nn;
  const int im  = (id & 7) + ((sid / nn) << 3);
  if (im >= ((M + 127) >> 7)) return;
  const int m0 = im * 128;
  const int n0 = jn * 128;

  const int tid    = threadIdx.x;
  const int lane   = tid & 63;
  const int w      = tid >> 6;
  const int m_lane = lane & 15;
  const int quad   = lane >> 4;
  const int wm     = (w >> 1) * 64;
  const int wn     = (w & 1) * 64;

  const int idx0 = tid, idx1 = 256 + tid;
  const int kc = (((tid & 3) ^ ((tid >> 3) & 3))) * 8;   // same for idx0/idx1
  int rowA0 = m0 + (idx0 >> 2); if (rowA0 >= M) rowA0 = M - 1;
  int rowA1 = m0 + (idx1 >> 2); if (rowA1 >= M) rowA1 = M - 1;
  const unsigned short* gA0 = A + (size_t)rowA0 * lda + kc;
  const unsigned short* gA1 = A + (size_t)rowA1 * lda + kc;
  const unsigned short* gB0 = B + (size_t)(n0 + (idx0 >> 2)) * K + kc;
  const unsigned short* gB1 = B + (size_t)(n0 + (idx1 >> 2)) * K + kc;

  const int la0 = (w * 64) * 8;          // LDS slot offsets (shorts)
  const int la1 = (256 + w * 64) * 8;

  const int swz = (quad ^ ((m_lane >> 1) & 3)) * 8;

  f32x4 acc[4][4] = {};

  const int nk = K >> 5;

  // prologue: stage k-tile 0 into buffer 0
  load_lds16(gA0, &As[0][la0]);
  load_lds16(gA1, &As[0][la1]);
  load_lds16(gB0, &Bs[0][la0]);
  load_lds16(gB1, &Bs[0][la1]);
  gA0 += 32; gA1 += 32; gB0 += 32; gB1 += 32;
  __syncthreads();

  int cur = 0;
  for (int t = 0; t < nk; ++t) {
    if (t + 1 < nk) {   // issue next-tile stage BEFORE compute of current tile
      load_lds16(gA0, &As[cur ^ 1][la0]);
      load_lds16(gA1, &As[cur ^ 1][la1]);
      load_lds16(gB0, &Bs[cur ^ 1][la0]);
      load_lds16(gB1, &Bs[cur ^ 1][la1]);
      gA0 += 32; gA1 += 32; gB0 += 32; gB1 += 32;
    }
    bf16x8 af[4], bg[4];
#pragma unroll
    for (int i = 0; i < 4; ++i)
      af[i] = *reinterpret_cast<const bf16x8*>(&As[cur][(wm + i * 16 + m_lane) * 32 + swz]);
#pragma unroll
    for (int j = 0; j < 4; ++j)
      bg[j] = *reinterpret_cast<const bf16x8*>(&Bs[cur][(wn + j * 16 + m_lane) * 32 + swz]);
#pragma unroll
    for (int i = 0; i < 4; ++i)
#pragma unroll
      for (int j = 0; j < 4; ++j)
        acc[i][j] = __builtin_amdgcn_mfma_f32_16x16x32_bf16(af[i], bg[j], acc[i][j], 0, 0, 0);
    __syncthreads();   // drains this iter's stage (vmcnt) after MFMA work hid it
    cur ^= 1;
  }

#pragma unroll
  for (int i = 0; i < 4; ++i) {
#pragma unroll
    for (int j = 0; j < 4; ++j) {
      int col = n0 + wn + j * 16 + m_lane;
      float bv = bias ? bias[col] : 0.f;
#pragma unroll
      for (int r = 0; r < 4; ++r) {
        int row = m0 + wm + i * 16 + quad * 4 + r;
        if (row < M) {
          float v = acc[i][j][r] + bv;
          if (act) v = v > 0.f ? v : 0.f;
          C[(size_t)row * ldc + col] = f2bf(v);
        }
      }
    }
  }
}

// ---------------- k_ff-structure GEMM, K=256 exactly: C = A @ W^T + bias ------
// A [M x 256] bf16, W [N x 256] bf16 (L2-resident), C [M x N] bf16.
// 80-row tile, 8 waves, 40 KB LDS (A staged once, full K) -> up to 4 blocks/CU.
// Wave w streams W rows (kb*256 + w*32 .. +31) from L2; swapped mfma(W, A);
// ZERO barriers after the stage (As is read-only). Output mapping identical to
// k_ff's verified Hs-write: col = kb*256+w*32+i*16+quad*4+r, row = j*16+ml.
// Measured basis: k_ff's GEMM1 structure delivers ~440 TF vs k_gemm128's ~300.

__global__ __launch_bounds__(512, 4) void k_gemmT(
    const unsigned short* __restrict__ A,
    const unsigned short* __restrict__ W,
    const float* __restrict__ bias,            // [N] or null
    unsigned short* __restrict__ C,
    int M, int N) {
  __shared__ unsigned short As[8 * 80 * 32];   // 40 KB  [kgrp][row][32]

  const int tid  = threadIdx.x;
  const int lane = tid & 63;
  const int w    = tid >> 6;        // 0..7
  const int ml   = lane & 15;
  const int quad = lane >> 4;
  const int m0   = blockIdx.x * 80;
  const int swz  = (quad ^ ((ml >> 1) & 3)) << 3;

  // ---- stage A tile 80x256 (waves 0..4; wave-uniform LDS base + lane*16B) ----
  if (tid < 320) {
    int rg = m0 + (tid >> 2); if (rg >= M) rg = M - 1;
    int cs = (tid & 3) ^ ((tid >> 3) & 3);
    const unsigned short* gsrc = A + (size_t)rg * 256 + (cs << 3);
    unsigned short* ldst = As + (size_t)(w * 64) * 8;
#pragma unroll
    for (int g = 0; g < 8; ++g)
      load_lds16(gsrc + (g << 5), ldst + (size_t)g * 2560);
  }
  __syncthreads();

  const int nkb = N >> 8;
  for (int kb = 0; kb < nkb; ++kb) {
    f32x4 acc1[2][5] = {};
    const unsigned short* Wp = W + (size_t)(kb * 256 + w * 32 + ml) * 256 + quad * 8;
#pragma unroll 2
    for (int ks = 0; ks < 8; ++ks) {
      bf16x8 af[2], bg[5];
#pragma unroll
      for (int i = 0; i < 2; ++i)
        af[i] = *reinterpret_cast<const bf16x8*>(Wp + (size_t)i * 16 * 256 + ks * 32);
#pragma unroll
      for (int j = 0; j < 5; ++j)
        bg[j] = *reinterpret_cast<const bf16x8*>(&As[ks * 2560 + (j * 16 + ml) * 32 + swz]);
#pragma unroll
      for (int i = 0; i < 2; ++i)
#pragma unroll
        for (int j = 0; j < 5; ++j)
          acc1[i][j] = __builtin_amdgcn_mfma_f32_16x16x32_bf16(af[i], bg[j], acc1[i][j], 0, 0, 0);
    }

    // bias + global store (4 consecutive cols per lane = 8 B)
#pragma unroll
    for (int i = 0; i < 2; ++i) {
      int colb = kb * 256 + w * 32 + i * 16 + quad * 4;
      float4 bv = make_float4(0.f, 0.f, 0.f, 0.f);
      if (bias) bv = *reinterpret_cast<const float4*>(bias + colb);
#pragma unroll
      for (int j = 0; j < 5; ++j) {
        int rg = m0 + j * 16 + ml;
        if (rg < M) {
          ushort4 hv;
          hv.x = f2bf(acc1[i][j][0] + bv.x);
          hv.y = f2bf(acc1[i][j][1] + bv.y);
          hv.z = f2bf(acc1[i][j][2] + bv.z);
          hv.w = f2bf(acc1[i][j][3] + bv.w);
          *reinterpret_cast<ushort4*>(C + (size_t)rg * N + colb) = hv;
        }
      }
    }
  }
}

// ---------------- fused attention + o-proj + bias + residual + LayerNorm ----------
// 48-row blocks = 16 nodes, 256 thr / 4 waves.

__global__ __launch_bounds__(256) void k_oproj(
    const unsigned short* __restrict__ qkvb,   // [M x 768] raw q|k|v
    const unsigned short* __restrict__ Wo,     // [256 x 256]
    const float* __restrict__ bo,
    const float* __restrict__ gam, const float* __restrict__ bet,
    unsigned short* __restrict__ seqc,         // residual in / out, [M x 256]
    int M) {
  __shared__ unsigned short As[8 * 48 * 32];   // 24 KB attention-out, [kgrp][row][32]
  __shared__ unsigned short Bs[2][256 * 32];   // 32 KB Wo k-panels
  __shared__ float sSum[4 * 48];
  __shared__ float sSq[4 * 48];

  const int tid  = threadIdx.x;
  const int lane = tid & 63;
  const int w    = tid >> 6;
  const int ml   = lane & 15;
  const int quad = lane >> 4;
  const int m0   = blockIdx.x * 48;
  const int swz  = (quad ^ ((ml >> 1) & 3)) * 8;

  // ---- issue Wo panel-0 stage first (latency hides under attention phase) ----
  const int kcs = ((tid & 3) ^ ((tid >> 3) & 3)) * 8;
  const unsigned short* gB0 = Wo + (size_t)((0 * 256 + tid) >> 2) * 256 + kcs;
  const unsigned short* gB1 = Wo + (size_t)((1 * 256 + tid) >> 2) * 256 + kcs;
  const unsigned short* gB2 = Wo + (size_t)((2 * 256 + tid) >> 2) * 256 + kcs;
  const unsigned short* gB3 = Wo + (size_t)((3 * 256 + tid) >> 2) * 256 + kcs;
  const int lb0 = (0 * 256 + w * 64) * 8;
  const int lb1 = (1 * 256 + w * 64) * 8;
  const int lb2 = (2 * 256 + w * 64) * 8;
  const int lb3 = (3 * 256 + w * 64) * 8;
  load_lds16(gB0, &Bs[0][lb0]);
  load_lds16(gB1, &Bs[0][lb1]);
  load_lds16(gB2, &Bs[0][lb2]);
  load_lds16(gB3, &Bs[0][lb3]);
  gB0 += 32; gB1 += 32; gB2 += 32; gB3 += 32;

  // ---- phase 1: attention for this wave's 4 nodes (lane = head-dim d) ----
  const int d = lane;
  for (int i = 0; i < 4; ++i) {
    int r0 = (w * 4 + i) * 3;                  // local row of token 0
    size_t rowg[3];
#pragma unroll
    for (int t = 0; t < 3; ++t) {
      int rg = m0 + r0 + t;
      rowg[t] = (size_t)(rg < M ? rg : M - 1);
    }
#pragma unroll
    for (int h = 0; h < 4; ++h) {
      float q[3], k[3], v[3];
#pragma unroll
      for (int t = 0; t < 3; ++t) {
        size_t base = rowg[t] * 768 + h * 64 + d;
        q[t] = bf2f(qkvb[base]);
        k[t] = bf2f(qkvb[base + 256]);
        v[t] = bf2f(qkvb[base + 512]);
      }
      float l[3][3];
#pragma unroll
      for (int a = 0; a < 3; ++a)
#pragma unroll
        for (int b = 0; b < 3; ++b)
          l[a][b] = wredsum(q[a] * k[b]) * 0.125f;
#pragma unroll
      for (int a = 0; a < 3; ++a) {
        float mx = fmaxf(l[a][0], fmaxf(l[a][1], l[a][2]));
        float e0 = __expf(l[a][0] - mx);
        float e1 = __expf(l[a][1] - mx);
        float e2 = __expf(l[a][2] - mx);
        float inv = 1.f / (e0 + e1 + e2);
        float o = (e0 * v[0] + e1 * v[1] + e2 * v[2]) * inv;
        int row = r0 + a;
        int col = h * 64 + d;
        int g = col >> 5, c = (col >> 3) & 3;
        As[((g * 48 + row) * 32) + ((c ^ ((row >> 1) & 3)) << 3) + (col & 7)] = f2bf(o);
      }
    }
  }
  __syncthreads();   // As complete; Bs[0] stage drained

  // ---- phase 2: GEMM [48 x 256] @ Wo^T, K=256 in 8 panels, dbuf B ----
  f32x4 acc[3][4] = {};
  int cur = 0;
  for (int t = 0; t < 8; ++t) {
    if (t + 1 < 8) {
      load_lds16(gB0, &Bs[cur ^ 1][lb0]);
      load_lds16(gB1, &Bs[cur ^ 1][lb1]);
      load_lds16(gB2, &Bs[cur ^ 1][lb2]);
      load_lds16(gB3, &Bs[cur ^ 1][lb3]);
      gB0 += 32; gB1 += 32; gB2 += 32; gB3 += 32;
    }
    bf16x8 af[3], bg[4];
#pragma unroll
    for (int i = 0; i < 3; ++i)
      af[i] = *reinterpret_cast<const bf16x8*>(&As[(t * 48 + i * 16 + ml) * 32 + swz]);
#pragma unroll
    for (int j = 0; j < 4; ++j)
      bg[j] = *reinterpret_cast<const bf16x8*>(&Bs[cur][(w * 64 + j * 16 + ml) * 32 + swz]);
#pragma unroll
    for (int i = 0; i < 3; ++i)
#pragma unroll
      for (int j = 0; j < 4; ++j)
        acc[i][j] = __builtin_amdgcn_mfma_f32_16x16x32_bf16(af[i], bg[j], acc[i][j], 0, 0, 0);
    __syncthreads();
    cur ^= 1;
  }

  // ---- bias + residual + per-row partial stats over this wave's 64 cols ----
  float bov[4], gv[4], btv[4];
#pragma unroll
  for (int j = 0; j < 4; ++j) {
    int col = w * 64 + j * 16 + ml;
    bov[j] = bo[col]; gv[j] = gam[col]; btv[j] = bet[col];
  }

#pragma unroll
  for (int i = 0; i < 3; ++i)
#pragma unroll
    for (int r = 0; r < 4; ++r) {
      int row = i * 16 + quad * 4 + r;
      int rg = m0 + row;
      size_t rr2 = (size_t)(rg < M ? rg : M - 1);
      float s = 0.f, s2 = 0.f;
#pragma unroll
      for (int j = 0; j < 4; ++j) {
        int col = w * 64 + j * 16 + ml;
        float t = acc[i][j][r] + bov[j] + bf2f(seqc[rr2 * 256 + col]);
        acc[i][j][r] = t;
        s += t; s2 += t * t;
      }
#pragma unroll
      for (int o = 1; o < 16; o <<= 1) { s += __shfl_xor(s, o); s2 += __shfl_xor(s2, o); }
      if (ml == 0) { sSum[w * 48 + row] = s; sSq[w * 48 + row] = s2; }
    }
  __syncthreads();

#pragma unroll
  for (int i = 0; i < 3; ++i)
#pragma unroll
    for (int r = 0; r < 4; ++r) {
      int row = i * 16 + quad * 4 + r;
      int rg = m0 + row;
      if (rg >= M) continue;
      float s  = sSum[row] + sSum[48 + row] + sSum[96 + row] + sSum[144 + row];
      float s2 = sSq[row]  + sSq[48 + row]  + sSq[96 + row]  + sSq[144 + row];
      float mean = s * (1.f / 256.f);
      float var  = s2 * (1.f / 256.f) - mean * mean;
      float inv  = rsqrtf(var + 1e-5f);
#pragma unroll
      for (int j = 0; j < 4; ++j) {
        int col = w * 64 + j * 16 + ml;
        seqc[(size_t)rg * 256 + col] = f2bf((acc[i][j][r] - mean) * inv * gv[j] + btv[j]);
      }
    }
}

// ---------------- fused FFN: relu(A@W1^T+b1)@W2^T + b2 + residual(A) + LN ----------
// 80-row tile, 8 waves, 80 KB LDS -> exactly 2 co-resident blocks/CU (verified:
// 119 -> 89 us vs 128-row, occupancy 37%). K-grouped [8 grp][80 row][32] layout.

__global__ __launch_bounds__(512, 4) void k_ff(
    unsigned short* __restrict__ A,
    const unsigned short* __restrict__ W1,
    const float* __restrict__ b1,
    const unsigned short* __restrict__ W2,
    const float* __restrict__ b2,
    const float* __restrict__ gam, const float* __restrict__ bet,
    int M) {
  __shared__ unsigned short As[8 * 80 * 32];   // 40 KB  [kgrp][row][32]
  __shared__ unsigned short Hs[8 * 80 * 32];   // 40 KB  (reused as LN scratch)

  const int tid  = threadIdx.x;
  const int lane = tid & 63;
  const int w    = tid >> 6;        // 0..7
  const int ml   = lane & 15;
  const int quad = lane >> 4;
  const int m0   = blockIdx.x * 80;
  const int swz  = (quad ^ ((ml >> 1) & 3)) << 3;

  // ---- stage A tile 80x256: threads 0..319 own (row = tid>>2, chunk = tid&3)
  if (tid < 320) {
    int rg = m0 + (tid >> 2); if (rg >= M) rg = M - 1;
    int cs = (tid & 3) ^ ((tid >> 3) & 3);
    const unsigned short* gsrc = A + (size_t)rg * 256 + (cs << 3);
    unsigned short* ldst = As + (size_t)(w * 64) * 8;   // HW adds lane*16B
#pragma unroll
    for (int g = 0; g < 8; ++g)
      load_lds16(gsrc + (g << 5), ldst + (size_t)g * 2560);
  }
  __syncthreads();

  f32x4 acc2[5][2] = {};

  for (int kb = 0; kb < 4; ++kb) {
    f32x4 acc1[2][5] = {};
    const unsigned short* W1p = W1 + (size_t)(kb * 256 + w * 32 + ml) * 256 + quad * 8;
#pragma unroll 2
    for (int ks = 0; ks < 8; ++ks) {
      bf16x8 af[2], bg[5];
#pragma unroll
      for (int i = 0; i < 2; ++i)
        af[i] = *reinterpret_cast<const bf16x8*>(W1p + (size_t)i * 16 * 256 + ks * 32);
#pragma unroll
      for (int j = 0; j < 5; ++j)
        bg[j] = *reinterpret_cast<const bf16x8*>(&As[ks * 2560 + (j * 16 + ml) * 32 + swz]);
#pragma unroll
      for (int i = 0; i < 2; ++i)
#pragma unroll
        for (int j = 0; j < 5; ++j)
          acc1[i][j] = __builtin_amdgcn_mfma_f32_16x16x32_bf16(af[i], bg[j], acc1[i][j], 0, 0, 0);
    }

    __syncthreads();   // previous GEMM2 readers of Hs are done

#pragma unroll
    for (int i = 0; i < 2; ++i) {
      float4 bv = *reinterpret_cast<const float4*>(b1 + kb * 256 + w * 32 + i * 16 + quad * 4);
      int c  = i * 2 + (quad >> 1);
      int lo = (quad & 1) * 4;
#pragma unroll
      for (int j = 0; j < 5; ++j) {
        int seqrow = j * 16 + ml;
        int chsw = c ^ ((ml >> 1) & 3);
        int addr = w * 2560 + seqrow * 32 + (chsw << 3) + lo;
        float t0 = acc1[i][j][0] + bv.x; t0 = t0 > 0.f ? t0 : 0.f;
        float t1 = acc1[i][j][1] + bv.y; t1 = t1 > 0.f ? t1 : 0.f;
        float t2 = acc1[i][j][2] + bv.z; t2 = t2 > 0.f ? t2 : 0.f;
        float t3 = acc1[i][j][3] + bv.w; t3 = t3 > 0.f ? t3 : 0.f;
        ushort4 hv;
        hv.x = f2bf(t0); hv.y = f2bf(t1); hv.z = f2bf(t2); hv.w = f2bf(t3);
        *reinterpret_cast<ushort4*>(&Hs[addr]) = hv;
      }
    }
    __syncthreads();   // Hs visible to all waves

    const unsigned short* W2p = W2 + (size_t)(w * 32 + ml) * 1024 + kb * 256 + quad * 8;
#pragma unroll 2
    for (int ks = 0; ks < 8; ++ks) {
      bf16x8 af[5], bg[2];
#pragma unroll
      for (int i = 0; i < 5; ++i)
        af[i] = *reinterpret_cast<const bf16x8*>(&Hs[ks * 2560 + (i * 16 + ml) * 32 + swz]);
#pragma unroll
      for (int j = 0; j < 2; ++j)
        bg[j] = *reinterpret_cast<const bf16x8*>(W2p + (size_t)j * 16 * 1024 + ks * 32);
#pragma unroll
      for (int i = 0; i < 5; ++i)
#pragma unroll
        for (int j = 0; j < 2; ++j)
          acc2[i][j] = __builtin_amdgcn_mfma_f32_16x16x32_bf16(af[i], bg[j], acc2[i][j], 0, 0, 0);
    }
  }

  __syncthreads();   // all Hs reads done -> reuse Hs as LN scratch
  float* sS = reinterpret_cast<float*>(Hs);   // [8][80]
  float* sQ = sS + 640;                        // [8][80]

  float b2v[2], gv[2], btv[2];
#pragma unroll
  for (int j = 0; j < 2; ++j) {
    int col = w * 32 + j * 16 + ml;
    b2v[j] = b2[col]; gv[j] = gam[col]; btv[j] = bet[col];
  }

  // bias + residual (from As LDS) + per-row partial stats over this wave's 32 cols
#pragma unroll
  for (int i = 0; i < 5; ++i)
#pragma unroll
    for (int r = 0; r < 4; ++r) {
      int row = i * 16 + quad * 4 + r;
      float s = 0.f, s2 = 0.f;
#pragma unroll
      for (int j = 0; j < 2; ++j) {
        int c_r = j * 2 + (ml >> 3);
        float t = acc2[i][j][r] + b2v[j] +
                  bf2f(As[w * 2560 + row * 32 + ((c_r ^ ((row >> 1) & 3)) << 3) + (ml & 7)]);
        acc2[i][j][r] = t;
        s += t; s2 += t * t;
      }
#pragma unroll
      for (int o = 1; o < 16; o <<= 1) { s += __shfl_xor(s, o); s2 += __shfl_xor(s2, o); }
      if (ml == 0) { sS[w * 80 + row] = s; sQ[w * 80 + row] = s2; }
    }
  __syncthreads();

#pragma unroll
  for (int i = 0; i < 5; ++i)
#pragma unroll
    for (int r = 0; r < 4; ++r) {
      int row = i * 16 + quad * 4 + r;
      int rg = m0 + row;
      if (rg >= M) continue;
      float s = 0.f, s2 = 0.f;
#pragma unroll
      for (int ww = 0; ww < 8; ++ww) { s += sS[ww * 80 + row]; s2 += sQ[ww * 80 + row]; }
      float mean = s * (1.f / 256.f);
      float var  = s2 * (1.f / 256.f) - mean * mean;
      float inv  = rsqrtf(var + 1e-5f);
#pragma unroll
      for (int j = 0; j < 2; ++j) {
        int col = w * 32 + j * 16 + ml;
        A[(size_t)rg * 256 + col] = f2bf((acc2[i][j][r] - mean) * inv * gv[j] + btv[j]);
      }
    }
}

// ---------------- transformer pieces (bf16 activations, dense layouts) ----------------

__global__ void k_seqbuild(const unsigned short* __restrict__ x1,
                           const unsigned short* __restrict__ x2,
                           const float* __restrict__ cls, const float* __restrict__ pos,
                           unsigned short* __restrict__ seqc, int n0, int cn) {
  int idx = blockIdx.x * blockDim.x + threadIdx.x;
  int total = cn * 3 * DD;
  if (idx >= total) return;
  int c = idx & (DD - 1);
  int r = idx >> 8;
  int t = r % 3, ln = r / 3;
  int n = n0 + ln;
  float v;
  if (t == 0)      v = cls[c];
  else if (t == 1) v = bf2f(x1[(size_t)n * DD + c]);
  else             v = bf2f(x2[(size_t)n * DD + c]);
  seqc[idx] = f2bf(v + pos[t * DD + c]);
}

__global__ __launch_bounds__(256) void k_final(const unsigned short* __restrict__ seqc,
                                               int n0, int cn,
                                               const float* __restrict__ g,
                                               const float* __restrict__ b,
                                               float* __restrict__ out) {
  int ln = blockIdx.x * 4 + (threadIdx.x >> 6);
  if (ln >= cn) return;
  int lane = threadIdx.x & 63;
  const unsigned short* p = seqc + (size_t)ln * 3 * DD;   // token 0 row
  float v[4];
  float s = 0.f, s2 = 0.f;
#pragma unroll
  for (int i = 0; i < 4; ++i) {
    v[i] = bf2f(p[i * 64 + lane]);
    s += v[i]; s2 += v[i] * v[i];
  }
  for (int off = 32; off; off >>= 1) { s += __shfl_xor(s, off); s2 += __shfl_xor(s2, off); }
  float mean = s * (1.f / 256.f);
  float var  = s2 * (1.f / 256.f) - mean * mean;
  float inv  = rsqrtf(var + 1e-5f);
#pragma unroll
  for (int i = 0; i < 4; ++i) {
    int c = i * 64 + lane;
    out[(size_t)(n0 + ln) * DD + c] = (v[i] - mean) * inv * g[c] + b[c];
  }
}

// ---------------- host ----------------

extern "C" void kernel_launch(void* const* d_in, const int* in_sizes, int n_in,
                              void* d_out, int out_size, void* d_ws, size_t ws_size,
                              hipStream_t stream) {
  const float* x       = (const float*)d_in[0];
  const int*   ei      = (const int*)d_in[1];
  const float* gat1_W  = (const float*)d_in[2];
  const float* gat1_b  = (const float*)d_in[3];
  const float* gat1_as = (const float*)d_in[4];
  const float* gat1_ad = (const float*)d_in[5];
  const float* gat2_W  = (const float*)d_in[6];
  const float* gat2_b  = (const float*)d_in[7];
  const float* gat2_as = (const float*)d_in[8];
  const float* gat2_ad = (const float*)d_in[9];
  const float* cls     = (const float*)d_in[10];
  const float* pos     = (const float*)d_in[11];
  const float* Wqkv    = (const float*)d_in[12];
  const float* bqkv    = (const float*)d_in[13];
  const float* Wo      = (const float*)d_in[14];
  const float* bo      = (const float*)d_in[15];
  const float* ln1_g   = (const float*)d_in[16];
  const float* ln1_b   = (const float*)d_in[17];
  const float* ln2_g   = (const float*)d_in[18];
  const float* ln2_b   = (const float*)d_in[19];
  const float* Wff1    = (const float*)d_in[20];
  const float* bff1    = (const float*)d_in[21];
  const float* Wff2    = (const float*)d_in[22];
  const float* bff2    = (const float*)d_in[23];
  const float* norm_g  = (const float*)d_in[24];
  const float* norm_b  = (const float*)d_in[25];
  float* out = (float*)d_out;

  char* ws = (char*)d_ws;
  size_t off = 0;
  auto alloc = [&](size_t bytes) -> void* {
    off = (off + 255) & ~(size_t)255;
    void* p = ws + off;
    off += bytes;
    return p;
  };

  unsigned short* wb_g1  = (unsigned short*)alloc(sizeof(unsigned short) * 256 * 128);
  unsigned short* wb_g2  = (unsigned short*)alloc(sizeof(unsigned short) * 256 * 256);
  unsigned short* wb_qkv = (unsigned short*)alloc(sizeof(unsigned short) * 2 * 768 * 256);
  unsigned short* wb_o   = (unsigned short*)alloc(sizeof(unsigned short) * 2 * 256 * 256);
  unsigned short* wb_f1  = (unsigned short*)alloc(sizeof(unsigned short) * 2 * 1024 * 256);
  unsigned short* wb_f2  = (unsigned short*)alloc(sizeof(unsigned short) * 2 * 256 * 1024);
  unsigned short* xb  = (unsigned short*)alloc(sizeof(unsigned short) * (size_t)NN * DIN);
  unsigned short* hb  = (unsigned short*)alloc(sizeof(unsigned short) * (size_t)NN * DD);
  unsigned short* x1b = (unsigned short*)alloc(sizeof(unsigned short) * (size_t)NN * DD);
  unsigned short* x2b = (unsigned short*)alloc(sizeof(unsigned short) * (size_t)NN * DD);
  float* hs  = (float*)alloc(sizeof(float) * NN);
  float* hd  = (float*)alloc(sizeof(float) * NN);
  int* deg   = (int*)alloc(sizeof(int) * NN);
  int* inc   = (int*)alloc(sizeof(int) * NN);
  int* cur   = (int*)alloc(sizeof(int) * NN);
  int* tsum  = (int*)alloc(sizeof(int) * 64);
  int* ssrc  = (int*)alloc(sizeof(int) * E2);

  // transformer chunking (L3 residency of per-chunk activations)
  size_t fixed = (off + 255) & ~(size_t)255;
  size_t rem = (ws_size > fixed + 4096) ? (ws_size - fixed - 4096) : 0;
  const size_t per_node = (size_t)3 * (256 + 768) * 2;
  size_t cn_max = rem / per_node;
  if (cn_max < 1) cn_max = 1;
  if (cn_max > 12500) cn_max = 12500;
  int nc = (int)((NN + cn_max - 1) / cn_max);
  int cn = (NN + nc - 1) / nc;
  unsigned short* seqc = (unsigned short*)alloc(sizeof(unsigned short) * (size_t)3 * cn * 256);
  unsigned short* qkvb = (unsigned short*)alloc(sizeof(unsigned short) * (size_t)3 * cn * 768);

  // ---- casts ----
  auto cast = [&](const float* src, unsigned short* dst, int n) {
    k_cast<<<(n + 255) / 256, 256, 0, stream>>>(src, dst, n);
  };
  cast(gat1_W, wb_g1, 256 * 128);
  cast(gat2_W, wb_g2, 256 * 256);
  cast(Wqkv, wb_qkv, 2 * 768 * 256);
  cast(Wo, wb_o, 2 * 256 * 256);
  cast(Wff1, wb_f1, 2 * 1024 * 256);
  cast(Wff2, wb_f2, 2 * 256 * 1024);
  cast(x, xb, NN * DIN);

  // ---- CSR build ----
  hipMemsetAsync(deg, 0, sizeof(int) * NN, stream);
  hipMemsetAsync(cur, 0, sizeof(int) * NN, stream);
  k_deg<<<(E2 + 255) / 256, 256, 0, stream>>>(ei, deg);
  int nb = (NN + 1023) / 1024;
  k_scan_tile<<<nb, 1024, 0, stream>>>(deg, inc, tsum, NN);
  k_scan_sums<<<1, 64, 0, stream>>>(tsum, nb);
  k_scan_add<<<(NN + 255) / 256, 256, 0, stream>>>(inc, tsum, NN);
  k_scatter<<<(E2 + 255) / 256, 256, 0, stream>>>(ei, deg, inc, cur, ssrc);

  auto gemm = [&](const unsigned short* A, int lda, const unsigned short* B,
                  const float* bias, unsigned short* C, int ldc,
                  int M, int N, int K, int act) {
    int nm = (M + 127) / 128;
    int nmp = (nm + 7) & ~7;
    dim3 grid(N / 128, nmp);
    k_gemm128<<<grid, 256, 0, stream>>>(A, lda, B, bias, C, ldc, M, N, K, act);
  };

  // ---- GAT layer 1: hb = xb @ W1^T (K=128) ----
  gemm(xb, DIN, wb_g1, nullptr, hb, DD, NN, DD, DIN, 0);
  k_dots<<<(NN + 3) / 4, 256, 0, stream>>>(hb, gat1_as, gat1_ad, hs, hd);
  k_gat<<<(NN + 3) / 4, 256, 0, stream>>>(hb, ssrc, deg, inc, hs, hd, gat1_b, x1b);

  // ---- GAT layer 2: hb = x1b @ W2^T (K=256, k_ff-structure) ----
  k_gemmT<<<(NN + 79) / 80, 512, 0, stream>>>(x1b, wb_g2, nullptr, hb, NN, 256);
  k_dots<<<(NN + 3) / 4, 256, 0, stream>>>(hb, gat2_as, gat2_ad, hs, hd);
  k_gat<<<(NN + 3) / 4, 256, 0, stream>>>(hb, ssrc, deg, inc, hs, hd, gat2_b, x2b);

  // ---- transformer (chunked) ----
  for (int n0 = 0; n0 < NN; n0 += cn) {
    int c = NN - n0 < cn ? NN - n0 : cn;
    int Mch = 3 * c;
    int mblk48 = (Mch + 47) / 48;
    int mblk80 = (Mch + 79) / 80;
    k_seqbuild<<<(c * 3 * DD + 255) / 256, 256, 0, stream>>>(x1b, x2b, cls, pos, seqc, n0, c);
    for (int l = 0; l < 2; ++l) {
      // qkv: N=768, K=256 via k_ff-structure GEMM (raw q|k|v + bias)
      k_gemmT<<<mblk80, 512, 0, stream>>>(
          seqc, wb_qkv + (size_t)l * 768 * 256, bqkv + l * 768, qkvb, Mch, 768);
      // fused attention + o-proj + residual + ln1
      k_oproj<<<mblk48, 256, 0, stream>>>(
          qkvb, wb_o + (size_t)l * 256 * 256, bo + l * 256,
          ln1_g + l * 256, ln1_b + l * 256, seqc, Mch);
      // fused ff1+relu+ff2+residual+ln2 (no global intermediate), 80-row tiles
      k_ff<<<mblk80, 512, 0, stream>>>(
          seqc, wb_f1 + (size_t)l * 1024 * 256, bff1 + l * 1024,
          wb_f2 + (size_t)l * 256 * 1024, bff2 + l * 256,
          ln2_g + l * 256, ln2_b + l * 256, Mch);
    }
    k_final<<<(c + 3) / 4, 256, 0, stream>>>(seqc, n0, c, norm_g, norm_b, out);
  }
}

// Round 11
// 1913.599 us; speedup vs baseline: 1.2025x; 1.0269x over previous
//
#include <hip/hip_runtime.h>
#include <hip/hip_bf16.h>

#define NN  50000
#define EE  320000
#define E2  (EE + NN)
#define DIN 128
#define DD  256

typedef __attribute__((ext_vector_type(8))) short          bf16x8;
typedef __attribute__((ext_vector_type(8))) unsigned short u16x8;
typedef __attribute__((ext_vector_type(4))) float          f32x4;

// ---------------- helpers ----------------

static __device__ __forceinline__ float bf2f(unsigned short u) {
  return __builtin_bit_cast(float, (unsigned)u << 16);
}

static __device__ __forceinline__ unsigned short f2bf(float f) {
  unsigned u = __builtin_bit_cast(unsigned, f);
  return (unsigned short)((u + 0x7fffu + ((u >> 16) & 1u)) >> 16);
}

static __device__ __forceinline__ void load_lds16(const void* g, void* l) {
  __builtin_amdgcn_global_load_lds(
      (const __attribute__((address_space(1))) void*)g,
      (__attribute__((address_space(3))) void*)l, 16, 0, 0);
}

static __device__ __forceinline__ float wredsum(float v) {
  for (int o = 32; o; o >>= 1) v += __shfl_xor(v, o);
  return v;
}

// ---------------- weight/activation cast fp32 -> bf16 ----------------

__global__ void k_cast(const float* __restrict__ in, unsigned short* __restrict__ out, int n) {
  int i = blockIdx.x * blockDim.x + threadIdx.x;
  if (i >= n) return;
  out[i] = f2bf(in[i]);
}

// ---------------- CSR build ----------------

__global__ void k_deg(const int* __restrict__ ei, int* __restrict__ deg) {
  int i = blockIdx.x * blockDim.x + threadIdx.x;
  if (i >= E2) return;
  int dst = (i < EE) ? ei[EE + i] : (i - EE);
  atomicAdd(&deg[dst], 1);
}

__global__ __launch_bounds__(1024) void k_scan_tile(const int* __restrict__ in,
                                                    int* __restrict__ out,
                                                    int* __restrict__ tsum, int n) {
  __shared__ int sm[1024];
  int tid = threadIdx.x;
  int g = blockIdx.x * 1024 + tid;
  sm[tid] = (g < n) ? in[g] : 0;
  __syncthreads();
  for (int off = 1; off < 1024; off <<= 1) {
    int t = (tid >= off) ? sm[tid - off] : 0;
    __syncthreads();
    sm[tid] += t;
    __syncthreads();
  }
  if (g < n) out[g] = sm[tid];
  if (tid == 1023) tsum[blockIdx.x] = sm[1023];
}

__global__ void k_scan_sums(int* __restrict__ tsum, int nb) {
  int tid = threadIdx.x;           // single wave of 64, nb <= 64
  int v = (tid < nb) ? tsum[tid] : 0;
  for (int off = 1; off < 64; off <<= 1) {
    int t = __shfl_up(v, off);
    if (tid >= off) v += t;
  }
  if (tid < nb) tsum[tid] = v;
}

__global__ void k_scan_add(int* __restrict__ out, const int* __restrict__ tsum, int n) {
  int g = blockIdx.x * blockDim.x + threadIdx.x;
  if (g >= n || g < 1024) return;
  out[g] += tsum[(g >> 10) - 1];
}

__global__ void k_scatter(const int* __restrict__ ei, const int* __restrict__ deg,
                          const int* __restrict__ inc, int* __restrict__ cur,
                          int* __restrict__ ssrc) {
  int i = blockIdx.x * blockDim.x + threadIdx.x;
  if (i >= E2) return;
  int src, dst;
  if (i < EE) { src = ei[i]; dst = ei[EE + i]; } else { src = dst = i - EE; }
  int pos = atomicAdd(&cur[dst], 1);
  ssrc[inc[dst] - deg[dst] + pos] = src;
}

// ---------------- GAT pieces (h in bf16) ----------------

__global__ __launch_bounds__(256) void k_dots(const unsigned short* __restrict__ hb,
                                              const float* __restrict__ asrc,
                                              const float* __restrict__ adst,
                                              float* __restrict__ hs, float* __restrict__ hd) {
  int node = blockIdx.x * 4 + (threadIdx.x >> 6);
  if (node >= NN) return;
  int lane = threadIdx.x & 63;
  ushort4 hv = *reinterpret_cast<const ushort4*>(hb + (size_t)node * DD + lane * 4);
  float v0 = bf2f(hv.x), v1 = bf2f(hv.y), v2 = bf2f(hv.z), v3 = bf2f(hv.w);
  const float* as = asrc + lane * 4;
  const float* ad = adst + lane * 4;
  float s1 = v0 * as[0] + v1 * as[1] + v2 * as[2] + v3 * as[3];
  float s2 = v0 * ad[0] + v1 * ad[1] + v2 * ad[2] + v3 * ad[3];
  for (int off = 32; off; off >>= 1) {
    s1 += __shfl_xor(s1, off);
    s2 += __shfl_xor(s2, off);
  }
  if (lane == 0) { hs[node] = s1; hd[node] = s2; }
}

// Fused edge-softmax + aggregation: one wave per dst node.
__global__ __launch_bounds__(256) void k_gat(const unsigned short* __restrict__ hb,
                                             const int* __restrict__ ssrc,
                                             const int* __restrict__ deg,
                                             const int* __restrict__ inc,
                                             const float* __restrict__ hs,
                                             const float* __restrict__ hd,
                                             const float* __restrict__ bias,
                                             unsigned short* __restrict__ out) {
  __shared__ float sE[4][256];
  __shared__ int   sI[4][256];
  int w = threadIdx.x >> 6;
  int d = blockIdx.x * 4 + w;
  if (d >= NN) return;
  int lane = threadIdx.x & 63;
  int end = inc[d], cnt = deg[d], base = end - cnt;
  if (cnt > 256) cnt = 256;
  float hdd = hd[d];

  float m = -1e30f;
  for (int i0 = 0; i0 < cnt; i0 += 64) {
    int i = i0 + lane;
    float sc = -1e30f;
    if (i < cnt) {
      int s = ssrc[base + i];
      float v = hs[s] + hdd;
      sc = (v < 0.f) ? 0.2f * v : v;
      sI[w][i] = s;
      sE[w][i] = sc;
    }
    float mm = sc;
    for (int o = 32; o; o >>= 1) mm = fmaxf(mm, __shfl_xor(mm, o));
    m = fmaxf(m, mm);
  }
  float sum = 0.f;
  for (int i0 = 0; i0 < cnt; i0 += 64) {
    int i = i0 + lane;
    float e = 0.f;
    if (i < cnt) {
      e = __expf(sE[w][i] - m);
      sE[w][i] = e;
    }
    for (int o = 32; o; o >>= 1) e += __shfl_xor(e, o);
    sum += e;
  }
  float inv = 1.f / sum;

  float a0 = 0.f, a1 = 0.f, a2 = 0.f, a3 = 0.f;
  for (int i = 0; i < cnt; ++i) {
    float a = sE[w][i];
    int s = sI[w][i];
    ushort4 hv = *reinterpret_cast<const ushort4*>(hb + (size_t)s * DD + lane * 4);
    a0 += a * bf2f(hv.x);
    a1 += a * bf2f(hv.y);
    a2 += a * bf2f(hv.z);
    a3 += a * bf2f(hv.w);
  }
  const float* bp = bias + lane * 4;
  float r0 = a0 * inv + bp[0], r1 = a1 * inv + bp[1];
  float r2 = a2 * inv + bp[2], r3 = a3 * inv + bp[3];
  ushort4 o;
  o.x = f2bf(r0 > 0.f ? r0 : 0.f);
  o.y = f2bf(r1 > 0.f ? r1 : 0.f);
  o.z = f2bf(r2 > 0.f ? r2 : 0.f);
  o.w = f2bf(r3 > 0.f ? r3 : 0.f);
  *reinterpret_cast<ushort4*>(out + (size_t)d * DD + lane * 4) = o;
}

// LDS k-chunk swizzle (bank-conflict-free fragment reads):
// LDS slot (row, c) holds global k-chunk  c ^ ((row>>1)&3)  within each 32-k group.
// Fragment read of logical chunk q at row (16-aligned base + m_lane):
//   position = q ^ ((m_lane>>1)&3).  Direct-global reads use logical chunk = quad.
// Row stride MUST be 64 B ([*][32 shorts]) for conflict-free b128 reads.

// ---------------- k_ff-structure GEMM: C = A @ W^T + bias ------
// A [M x K] bf16, W [N x K] bf16 (L2-resident), C [M x N] bf16. K in {128, 256}.
// 80-row tile, 8 waves, K/32*80*64 B LDS (A staged once, full K).
// Wave w streams W rows (kb*256 + w*32 .. +31) from L2; swapped mfma(W, A);
// ZERO barriers after the stage (As is read-only). Measured ~440 TF structure.

__global__ __launch_bounds__(512, 4) void k_gemmT(
    const unsigned short* __restrict__ A,
    const unsigned short* __restrict__ W,
    const float* __restrict__ bias,            // [N] or null
    unsigned short* __restrict__ C,
    int M, int N, int K) {
  __shared__ unsigned short As[8 * 80 * 32];   // up to 40 KB  [kgrp][row][32]

  const int tid  = threadIdx.x;
  const int lane = tid & 63;
  const int w    = tid >> 6;        // 0..7
  const int ml   = lane & 15;
  const int quad = lane >> 4;
  const int m0   = blockIdx.x * 80;
  const int swz  = (quad ^ ((ml >> 1) & 3)) << 3;
  const int KG   = K >> 5;          // kgroups (4 or 8)

  // ---- stage A tile 80xK (waves 0..4; wave-uniform LDS base + lane*16B) ----
  if (tid < 320) {
    int rg = m0 + (tid >> 2); if (rg >= M) rg = M - 1;
    int cs = (tid & 3) ^ ((tid >> 3) & 3);
    const unsigned short* gsrc = A + (size_t)rg * K + (cs << 3);
    unsigned short* ldst = As + (size_t)(w * 64) * 8;
    for (int g = 0; g < KG; ++g)
      load_lds16(gsrc + (g << 5), ldst + (size_t)g * 2560);
  }
  __syncthreads();

  const int nkb = N >> 8;
  for (int kb = 0; kb < nkb; ++kb) {
    f32x4 acc1[2][5] = {};
    const unsigned short* Wp = W + (size_t)(kb * 256 + w * 32 + ml) * K + quad * 8;
#pragma unroll 2
    for (int ks = 0; ks < KG; ++ks) {
      bf16x8 af[2], bg[5];
#pragma unroll
      for (int i = 0; i < 2; ++i)
        af[i] = *reinterpret_cast<const bf16x8*>(Wp + (size_t)i * 16 * K + ks * 32);
#pragma unroll
      for (int j = 0; j < 5; ++j)
        bg[j] = *reinterpret_cast<const bf16x8*>(&As[ks * 2560 + (j * 16 + ml) * 32 + swz]);
#pragma unroll
      for (int i = 0; i < 2; ++i)
#pragma unroll
        for (int j = 0; j < 5; ++j)
          acc1[i][j] = __builtin_amdgcn_mfma_f32_16x16x32_bf16(af[i], bg[j], acc1[i][j], 0, 0, 0);
    }

    // bias + global store (4 consecutive cols per lane = 8 B)
#pragma unroll
    for (int i = 0; i < 2; ++i) {
      int colb = kb * 256 + w * 32 + i * 16 + quad * 4;
      float4 bv = make_float4(0.f, 0.f, 0.f, 0.f);
      if (bias) bv = *reinterpret_cast<const float4*>(bias + colb);
#pragma unroll
      for (int j = 0; j < 5; ++j) {
        int rg = m0 + j * 16 + ml;
        if (rg < M) {
          ushort4 hv;
          hv.x = f2bf(acc1[i][j][0] + bv.x);
          hv.y = f2bf(acc1[i][j][1] + bv.y);
          hv.z = f2bf(acc1[i][j][2] + bv.z);
          hv.w = f2bf(acc1[i][j][3] + bv.w);
          *reinterpret_cast<ushort4*>(C + (size_t)rg * N + colb) = hv;
        }
      }
    }
  }
}

// ---------------- fused attention + o-proj + bias + residual + LayerNorm ----------
// 48-row blocks = 16 nodes, 256 thr / 4 waves.
// Phase 1: per-node 4-head 3x3 attention -> swizzled k-grouped As tile.
// Phase 2: [48x256] @ Wo^T with Wo STREAMED from L2 (k_ff GEMM2 addressing,
//          logical chunk = quad, no Bs, no inner barriers). LDS 24 KB + sums
//          -> ~5 blocks/CU (was 56 KB / 2 blocks / 8 barriers).

__global__ __launch_bounds__(256) void k_oproj(
    const unsigned short* __restrict__ qkvb,   // [M x 768] raw q|k|v
    const unsigned short* __restrict__ Wo,     // [256 x 256]
    const float* __restrict__ bo,
    const float* __restrict__ gam, const float* __restrict__ bet,
    unsigned short* __restrict__ seqc,         // residual in / out, [M x 256]
    int M) {
  __shared__ unsigned short As[8 * 48 * 32];   // 24 KB attention-out, [kgrp][row][32]
  __shared__ float sSum[4 * 48];
  __shared__ float sSq[4 * 48];

  const int tid  = threadIdx.x;
  const int lane = tid & 63;
  const int w    = tid >> 6;
  const int ml   = lane & 15;
  const int quad = lane >> 4;
  const int m0   = blockIdx.x * 48;
  const int swz  = (quad ^ ((ml >> 1) & 3)) * 8;

  // ---- phase 1: attention for this wave's 4 nodes (lane = head-dim d) ----
  const int d = lane;
  for (int i = 0; i < 4; ++i) {
    int r0 = (w * 4 + i) * 3;                  // local row of token 0
    size_t rowg[3];
#pragma unroll
    for (int t = 0; t < 3; ++t) {
      int rg = m0 + r0 + t;
      rowg[t] = (size_t)(rg < M ? rg : M - 1);
    }
#pragma unroll
    for (int h = 0; h < 4; ++h) {
      float q[3], k[3], v[3];
#pragma unroll
      for (int t = 0; t < 3; ++t) {
        size_t base = rowg[t] * 768 + h * 64 + d;
        q[t] = bf2f(qkvb[base]);
        k[t] = bf2f(qkvb[base + 256]);
        v[t] = bf2f(qkvb[base + 512]);
      }
      float l[3][3];
#pragma unroll
      for (int a = 0; a < 3; ++a)
#pragma unroll
        for (int b = 0; b < 3; ++b)
          l[a][b] = wredsum(q[a] * k[b]) * 0.125f;
#pragma unroll
      for (int a = 0; a < 3; ++a) {
        float mx = fmaxf(l[a][0], fmaxf(l[a][1], l[a][2]));
        float e0 = __expf(l[a][0] - mx);
        float e1 = __expf(l[a][1] - mx);
        float e2 = __expf(l[a][2] - mx);
        float inv = 1.f / (e0 + e1 + e2);
        float o = (e0 * v[0] + e1 * v[1] + e2 * v[2]) * inv;
        int row = r0 + a;
        int col = h * 64 + d;
        int g = col >> 5, c = (col >> 3) & 3;
        As[((g * 48 + row) * 32) + ((c ^ ((row >> 1) & 3)) << 3) + (col & 7)] = f2bf(o);
      }
    }
  }
  __syncthreads();   // As complete

  // ---- phase 2: GEMM [48 x 256] @ Wo^T, Wo rows streamed from L2, no barriers
  f32x4 acc[3][4] = {};
  const unsigned short* Wop = Wo + (size_t)(w * 64 + ml) * 256 + quad * 8;
#pragma unroll 2
  for (int t = 0; t < 8; ++t) {
    bf16x8 af[3], bg[4];
#pragma unroll
    for (int i = 0; i < 3; ++i)
      af[i] = *reinterpret_cast<const bf16x8*>(&As[(t * 48 + i * 16 + ml) * 32 + swz]);
#pragma unroll
    for (int j = 0; j < 4; ++j)
      bg[j] = *reinterpret_cast<const bf16x8*>(Wop + (size_t)j * 16 * 256 + t * 32);
#pragma unroll
    for (int i = 0; i < 3; ++i)
#pragma unroll
      for (int j = 0; j < 4; ++j)
        acc[i][j] = __builtin_amdgcn_mfma_f32_16x16x32_bf16(af[i], bg[j], acc[i][j], 0, 0, 0);
  }

  // ---- bias + residual + per-row partial stats over this wave's 64 cols ----
  float bov[4], gv[4], btv[4];
#pragma unroll
  for (int j = 0; j < 4; ++j) {
    int col = w * 64 + j * 16 + ml;
    bov[j] = bo[col]; gv[j] = gam[col]; btv[j] = bet[col];
  }

#pragma unroll
  for (int i = 0; i < 3; ++i)
#pragma unroll
    for (int r = 0; r < 4; ++r) {
      int row = i * 16 + quad * 4 + r;
      int rg = m0 + row;
      size_t rr2 = (size_t)(rg < M ? rg : M - 1);
      float s = 0.f, s2 = 0.f;
#pragma unroll
      for (int j = 0; j < 4; ++j) {
        int col = w * 64 + j * 16 + ml;
        float t = acc[i][j][r] + bov[j] + bf2f(seqc[rr2 * 256 + col]);
        acc[i][j][r] = t;
        s += t; s2 += t * t;
      }
#pragma unroll
      for (int o = 1; o < 16; o <<= 1) { s += __shfl_xor(s, o); s2 += __shfl_xor(s2, o); }
      if (ml == 0) { sSum[w * 48 + row] = s; sSq[w * 48 + row] = s2; }
    }
  __syncthreads();

#pragma unroll
  for (int i = 0; i < 3; ++i)
#pragma unroll
    for (int r = 0; r < 4; ++r) {
      int row = i * 16 + quad * 4 + r;
      int rg = m0 + row;
      if (rg >= M) continue;
      float s  = sSum[row] + sSum[48 + row] + sSum[96 + row] + sSum[144 + row];
      float s2 = sSq[row]  + sSq[48 + row]  + sSq[96 + row]  + sSq[144 + row];
      float mean = s * (1.f / 256.f);
      float var  = s2 * (1.f / 256.f) - mean * mean;
      float inv  = rsqrtf(var + 1e-5f);
#pragma unroll
      for (int j = 0; j < 4; ++j) {
        int col = w * 64 + j * 16 + ml;
        seqc[(size_t)rg * 256 + col] = f2bf((acc[i][j][r] - mean) * inv * gv[j] + btv[j]);
      }
    }
}

// ---------------- fused FFN: relu(A@W1^T+b1)@W2^T + b2 + residual(A) + LN ----------
// 80-row tile, 8 waves, 80 KB LDS -> exactly 2 co-resident blocks/CU (verified:
// 119 -> 89 us vs 128-row, occupancy 37%). K-grouped [8 grp][80 row][32] layout.

__global__ __launch_bounds__(512, 4) void k_ff(
    unsigned short* __restrict__ A,
    const unsigned short* __restrict__ W1,
    const float* __restrict__ b1,
    const unsigned short* __restrict__ W2,
    const float* __restrict__ b2,
    const float* __restrict__ gam, const float* __restrict__ bet,
    int M) {
  __shared__ unsigned short As[8 * 80 * 32];   // 40 KB  [kgrp][row][32]
  __shared__ unsigned short Hs[8 * 80 * 32];   // 40 KB  (reused as LN scratch)

  const int tid  = threadIdx.x;
  const int lane = tid & 63;
  const int w    = tid >> 6;        // 0..7
  const int ml   = lane & 15;
  const int quad = lane >> 4;
  const int m0   = blockIdx.x * 80;
  const int swz  = (quad ^ ((ml >> 1) & 3)) << 3;

  // ---- stage A tile 80x256: threads 0..319 own (row = tid>>2, chunk = tid&3)
  if (tid < 320) {
    int rg = m0 + (tid >> 2); if (rg >= M) rg = M - 1;
    int cs = (tid & 3) ^ ((tid >> 3) & 3);
    const unsigned short* gsrc = A + (size_t)rg * 256 + (cs << 3);
    unsigned short* ldst = As + (size_t)(w * 64) * 8;   // HW adds lane*16B
#pragma unroll
    for (int g = 0; g < 8; ++g)
      load_lds16(gsrc + (g << 5), ldst + (size_t)g * 2560);
  }
  __syncthreads();

  f32x4 acc2[5][2] = {};

  for (int kb = 0; kb < 4; ++kb) {
    f32x4 acc1[2][5] = {};
    const unsigned short* W1p = W1 + (size_t)(kb * 256 + w * 32 + ml) * 256 + quad * 8;
#pragma unroll 2
    for (int ks = 0; ks < 8; ++ks) {
      bf16x8 af[2], bg[5];
#pragma unroll
      for (int i = 0; i < 2; ++i)
        af[i] = *reinterpret_cast<const bf16x8*>(W1p + (size_t)i * 16 * 256 + ks * 32);
#pragma unroll
      for (int j = 0; j < 5; ++j)
        bg[j] = *reinterpret_cast<const bf16x8*>(&As[ks * 2560 + (j * 16 + ml) * 32 + swz]);
#pragma unroll
      for (int i = 0; i < 2; ++i)
#pragma unroll
        for (int j = 0; j < 5; ++j)
          acc1[i][j] = __builtin_amdgcn_mfma_f32_16x16x32_bf16(af[i], bg[j], acc1[i][j], 0, 0, 0);
    }

    __syncthreads();   // previous GEMM2 readers of Hs are done

#pragma unroll
    for (int i = 0; i < 2; ++i) {
      float4 bv = *reinterpret_cast<const float4*>(b1 + kb * 256 + w * 32 + i * 16 + quad * 4);
      int c  = i * 2 + (quad >> 1);
      int lo = (quad & 1) * 4;
#pragma unroll
      for (int j = 0; j < 5; ++j) {
        int seqrow = j * 16 + ml;
        int chsw = c ^ ((ml >> 1) & 3);
        int addr = w * 2560 + seqrow * 32 + (chsw << 3) + lo;
        float t0 = acc1[i][j][0] + bv.x; t0 = t0 > 0.f ? t0 : 0.f;
        float t1 = acc1[i][j][1] + bv.y; t1 = t1 > 0.f ? t1 : 0.f;
        float t2 = acc1[i][j][2] + bv.z; t2 = t2 > 0.f ? t2 : 0.f;
        float t3 = acc1[i][j][3] + bv.w; t3 = t3 > 0.f ? t3 : 0.f;
        ushort4 hv;
        hv.x = f2bf(t0); hv.y = f2bf(t1); hv.z = f2bf(t2); hv.w = f2bf(t3);
        *reinterpret_cast<ushort4*>(&Hs[addr]) = hv;
      }
    }
    __syncthreads();   // Hs visible to all waves

    const unsigned short* W2p = W2 + (size_t)(w * 32 + ml) * 1024 + kb * 256 + quad * 8;
#pragma unroll 2
    for (int ks = 0; ks < 8; ++ks) {
      bf16x8 af[5], bg[2];
#pragma unroll
      for (int i = 0; i < 5; ++i)
        af[i] = *reinterpret_cast<const bf16x8*>(&Hs[ks * 2560 + (i * 16 + ml) * 32 + swz]);
#pragma unroll
      for (int j = 0; j < 2; ++j)
        bg[j] = *reinterpret_cast<const bf16x8*>(W2p + (size_t)j * 16 * 1024 + ks * 32);
#pragma unroll
      for (int i = 0; i < 5; ++i)
#pragma unroll
        for (int j = 0; j < 2; ++j)
          acc2[i][j] = __builtin_amdgcn_mfma_f32_16x16x32_bf16(af[i], bg[j], acc2[i][j], 0, 0, 0);
    }
  }

  __syncthreads();   // all Hs reads done -> reuse Hs as LN scratch
  float* sS = reinterpret_cast<float*>(Hs);   // [8][80]
  float* sQ = sS + 640;                        // [8][80]

  float b2v[2], gv[2], btv[2];
#pragma unroll
  for (int j = 0; j < 2; ++j) {
    int col = w * 32 + j * 16 + ml;
    b2v[j] = b2[col]; gv[j] = gam[col]; btv[j] = bet[col];
  }

  // bias + residual (from As LDS) + per-row partial stats over this wave's 32 cols
#pragma unroll
  for (int i = 0; i < 5; ++i)
#pragma unroll
    for (int r = 0; r < 4; ++r) {
      int row = i * 16 + quad * 4 + r;
      float s = 0.f, s2 = 0.f;
#pragma unroll
      for (int j = 0; j < 2; ++j) {
        int c_r = j * 2 + (ml >> 3);
        float t = acc2[i][j][r] + b2v[j] +
                  bf2f(As[w * 2560 + row * 32 + ((c_r ^ ((row >> 1) & 3)) << 3) + (ml & 7)]);
        acc2[i][j][r] = t;
        s += t; s2 += t * t;
      }
#pragma unroll
      for (int o = 1; o < 16; o <<= 1) { s += __shfl_xor(s, o); s2 += __shfl_xor(s2, o); }
      if (ml == 0) { sS[w * 80 + row] = s; sQ[w * 80 + row] = s2; }
    }
  __syncthreads();

#pragma unroll
  for (int i = 0; i < 5; ++i)
#pragma unroll
    for (int r = 0; r < 4; ++r) {
      int row = i * 16 + quad * 4 + r;
      int rg = m0 + row;
      if (rg >= M) continue;
      float s = 0.f, s2 = 0.f;
#pragma unroll
      for (int ww = 0; ww < 8; ++ww) { s += sS[ww * 80 + row]; s2 += sQ[ww * 80 + row]; }
      float mean = s * (1.f / 256.f);
      float var  = s2 * (1.f / 256.f) - mean * mean;
      float inv  = rsqrtf(var + 1e-5f);
#pragma unroll
      for (int j = 0; j < 2; ++j) {
        int col = w * 32 + j * 16 + ml;
        A[(size_t)rg * 256 + col] = f2bf((acc2[i][j][r] - mean) * inv * gv[j] + btv[j]);
      }
    }
}

// ---------------- transformer pieces (bf16 activations, dense layouts) ----------------

__global__ void k_seqbuild(const unsigned short* __restrict__ x1,
                           const unsigned short* __restrict__ x2,
                           const float* __restrict__ cls, const float* __restrict__ pos,
                           unsigned short* __restrict__ seqc, int n0, int cn) {
  int idx = blockIdx.x * blockDim.x + threadIdx.x;
  int total = cn * 3 * DD;
  if (idx >= total) return;
  int c = idx & (DD - 1);
  int r = idx >> 8;
  int t = r % 3, ln = r / 3;
  int n = n0 + ln;
  float v;
  if (t == 0)      v = cls[c];
  else if (t == 1) v = bf2f(x1[(size_t)n * DD + c]);
  else             v = bf2f(x2[(size_t)n * DD + c]);
  seqc[idx] = f2bf(v + pos[t * DD + c]);
}

__global__ __launch_bounds__(256) void k_final(const unsigned short* __restrict__ seqc,
                                               int n0, int cn,
                                               const float* __restrict__ g,
                                               const float* __restrict__ b,
                                               float* __restrict__ out) {
  int ln = blockIdx.x * 4 + (threadIdx.x >> 6);
  if (ln >= cn) return;
  int lane = threadIdx.x & 63;
  const unsigned short* p = seqc + (size_t)ln * 3 * DD;   // token 0 row
  float v[4];
  float s = 0.f, s2 = 0.f;
#pragma unroll
  for (int i = 0; i < 4; ++i) {
    v[i] = bf2f(p[i * 64 + lane]);
    s += v[i]; s2 += v[i] * v[i];
  }
  for (int off = 32; off; off >>= 1) { s += __shfl_xor(s, off); s2 += __shfl_xor(s2, off); }
  float mean = s * (1.f / 256.f);
  float var  = s2 * (1.f / 256.f) - mean * mean;
  float inv  = rsqrtf(var + 1e-5f);
#pragma unroll
  for (int i = 0; i < 4; ++i) {
    int c = i * 64 + lane;
    out[(size_t)(n0 + ln) * DD + c] = (v[i] - mean) * inv * g[c] + b[c];
  }
}

// ---------------- host ----------------

extern "C" void kernel_launch(void* const* d_in, const int* in_sizes, int n_in,
                              void* d_out, int out_size, void* d_ws, size_t ws_size,
                              hipStream_t stream) {
  const float* x       = (const float*)d_in[0];
  const int*   ei      = (const int*)d_in[1];
  const float* gat1_W  = (const float*)d_in[2];
  const float* gat1_b  = (const float*)d_in[3];
  const float* gat1_as = (const float*)d_in[4];
  const float* gat1_ad = (const float*)d_in[5];
  const float* gat2_W  = (const float*)d_in[6];
  const float* gat2_b  = (const float*)d_in[7];
  const float* gat2_as = (const float*)d_in[8];
  const float* gat2_ad = (const float*)d_in[9];
  const float* cls     = (const float*)d_in[10];
  const float* pos     = (const float*)d_in[11];
  const float* Wqkv    = (const float*)d_in[12];
  const float* bqkv    = (const float*)d_in[13];
  const float* Wo      = (const float*)d_in[14];
  const float* bo      = (const float*)d_in[15];
  const float* ln1_g   = (const float*)d_in[16];
  const float* ln1_b   = (const float*)d_in[17];
  const float* ln2_g   = (const float*)d_in[18];
  const float* ln2_b   = (const float*)d_in[19];
  const float* Wff1    = (const float*)d_in[20];
  const float* bff1    = (const float*)d_in[21];
  const float* Wff2    = (const float*)d_in[22];
  const float* bff2    = (const float*)d_in[23];
  const float* norm_g  = (const float*)d_in[24];
  const float* norm_b  = (const float*)d_in[25];
  float* out = (float*)d_out;

  char* ws = (char*)d_ws;
  size_t off = 0;
  auto alloc = [&](size_t bytes) -> void* {
    off = (off + 255) & ~(size_t)255;
    void* p = ws + off;
    off += bytes;
    return p;
  };

  unsigned short* wb_g1  = (unsigned short*)alloc(sizeof(unsigned short) * 256 * 128);
  unsigned short* wb_g2  = (unsigned short*)alloc(sizeof(unsigned short) * 256 * 256);
  unsigned short* wb_qkv = (unsigned short*)alloc(sizeof(unsigned short) * 2 * 768 * 256);
  unsigned short* wb_o   = (unsigned short*)alloc(sizeof(unsigned short) * 2 * 256 * 256);
  unsigned short* wb_f1  = (unsigned short*)alloc(sizeof(unsigned short) * 2 * 1024 * 256);
  unsigned short* wb_f2  = (unsigned short*)alloc(sizeof(unsigned short) * 2 * 256 * 1024);
  unsigned short* xb  = (unsigned short*)alloc(sizeof(unsigned short) * (size_t)NN * DIN);
  unsigned short* hb  = (unsigned short*)alloc(sizeof(unsigned short) * (size_t)NN * DD);
  unsigned short* x1b = (unsigned short*)alloc(sizeof(unsigned short) * (size_t)NN * DD);
  unsigned short* x2b = (unsigned short*)alloc(sizeof(unsigned short) * (size_t)NN * DD);
  float* hs  = (float*)alloc(sizeof(float) * NN);
  float* hd  = (float*)alloc(sizeof(float) * NN);
  int* deg   = (int*)alloc(sizeof(int) * NN);
  int* inc   = (int*)alloc(sizeof(int) * NN);
  int* cur   = (int*)alloc(sizeof(int) * NN);
  int* tsum  = (int*)alloc(sizeof(int) * 64);
  int* ssrc  = (int*)alloc(sizeof(int) * E2);

  // transformer chunking (L3 residency of per-chunk activations)
  size_t fixed = (off + 255) & ~(size_t)255;
  size_t rem = (ws_size > fixed + 4096) ? (ws_size - fixed - 4096) : 0;
  const size_t per_node = (size_t)3 * (256 + 768) * 2;
  size_t cn_max = rem / per_node;
  if (cn_max < 1) cn_max = 1;
  if (cn_max > 12500) cn_max = 12500;
  int nc = (int)((NN + cn_max - 1) / cn_max);
  int cn = (NN + nc - 1) / nc;
  unsigned short* seqc = (unsigned short*)alloc(sizeof(unsigned short) * (size_t)3 * cn * 256);
  unsigned short* qkvb = (unsigned short*)alloc(sizeof(unsigned short) * (size_t)3 * cn * 768);

  // ---- casts ----
  auto cast = [&](const float* src, unsigned short* dst, int n) {
    k_cast<<<(n + 255) / 256, 256, 0, stream>>>(src, dst, n);
  };
  cast(gat1_W, wb_g1, 256 * 128);
  cast(gat2_W, wb_g2, 256 * 256);
  cast(Wqkv, wb_qkv, 2 * 768 * 256);
  cast(Wo, wb_o, 2 * 256 * 256);
  cast(Wff1, wb_f1, 2 * 1024 * 256);
  cast(Wff2, wb_f2, 2 * 256 * 1024);
  cast(x, xb, NN * DIN);

  // ---- CSR build ----
  hipMemsetAsync(deg, 0, sizeof(int) * NN, stream);
  hipMemsetAsync(cur, 0, sizeof(int) * NN, stream);
  k_deg<<<(E2 + 255) / 256, 256, 0, stream>>>(ei, deg);
  int nb = (NN + 1023) / 1024;
  k_scan_tile<<<nb, 1024, 0, stream>>>(deg, inc, tsum, NN);
  k_scan_sums<<<1, 64, 0, stream>>>(tsum, nb);
  k_scan_add<<<(NN + 255) / 256, 256, 0, stream>>>(inc, tsum, NN);
  k_scatter<<<(E2 + 255) / 256, 256, 0, stream>>>(ei, deg, inc, cur, ssrc);

  // ---- GAT layer 1: hb = xb @ W1^T (K=128, k_ff-structure) ----
  k_gemmT<<<(NN + 79) / 80, 512, 0, stream>>>(xb, wb_g1, nullptr, hb, NN, 256, 128);
  k_dots<<<(NN + 3) / 4, 256, 0, stream>>>(hb, gat1_as, gat1_ad, hs, hd);
  k_gat<<<(NN + 3) / 4, 256, 0, stream>>>(hb, ssrc, deg, inc, hs, hd, gat1_b, x1b);

  // ---- GAT layer 2: hb = x1b @ W2^T (K=256, k_ff-structure) ----
  k_gemmT<<<(NN + 79) / 80, 512, 0, stream>>>(x1b, wb_g2, nullptr, hb, NN, 256, 256);
  k_dots<<<(NN + 3) / 4, 256, 0, stream>>>(hb, gat2_as, gat2_ad, hs, hd);
  k_gat<<<(NN + 3) / 4, 256, 0, stream>>>(hb, ssrc, deg, inc, hs, hd, gat2_b, x2b);

  // ---- transformer (chunked) ----
  for (int n0 = 0; n0 < NN; n0 += cn) {
    int c = NN - n0 < cn ? NN - n0 : cn;
    int Mch = 3 * c;
    int mblk48 = (Mch + 47) / 48;
    int mblk80 = (Mch + 79) / 80;
    k_seqbuild<<<(c * 3 * DD + 255) / 256, 256, 0, stream>>>(x1b, x2b, cls, pos, seqc, n0, c);
    for (int l = 0; l < 2; ++l) {
      // qkv: N=768, K=256 via k_ff-structure GEMM (raw q|k|v + bias)
      k_gemmT<<<mblk80, 512, 0, stream>>>(
          seqc, wb_qkv + (size_t)l * 768 * 256, bqkv + l * 768, qkvb, Mch, 768, 256);
      // fused attention + o-proj + residual + ln1 (Wo streamed, no Bs)
      k_oproj<<<mblk48, 256, 0, stream>>>(
          qkvb, wb_o + (size_t)l * 256 * 256, bo + l * 256,
          ln1_g + l * 256, ln1_b + l * 256, seqc, Mch);
      // fused ff1+relu+ff2+residual+ln2 (no global intermediate), 80-row tiles
      k_ff<<<mblk80, 512, 0, stream>>>(
          seqc, wb_f1 + (size_t)l * 1024 * 256, bff1 + l * 1024,
          wb_f2 + (size_t)l * 256 * 1024, bff2 + l * 256,
          ln2_g + l * 256, ln2_b + l * 256, Mch);
    }
    k_final<<<(c + 3) / 4, 256, 0, stream>>>(seqc, n0, c, norm_g, norm_b, out);
  }
}

// Round 12
// 1739.334 us; speedup vs baseline: 1.3230x; 1.1002x over previous
//
#include <hip/hip_runtime.h>
#include <hip/hip_bf16.h>

#define NN  50000
#define EE  320000
#define E2  (EE + NN)
#define DIN 128
#define DD  256

typedef __attribute__((ext_vector_type(8))) short          bf16x8;
typedef __attribute__((ext_vector_type(8))) unsigned short u16x8;
typedef __attribute__((ext_vector_type(4))) float          f32x4;

// ---------------- helpers ----------------

static __device__ __forceinline__ float bf2f(unsigned short u) {
  return __builtin_bit_cast(float, (unsigned)u << 16);
}

static __device__ __forceinline__ unsigned short f2bf(float f) {
  unsigned u = __builtin_bit_cast(unsigned, f);
  return (unsigned short)((u + 0x7fffu + ((u >> 16) & 1u)) >> 16);
}

static __device__ __forceinline__ void load_lds16(const void* g, void* l) {
  __builtin_amdgcn_global_load_lds(
      (const __attribute__((address_space(1))) void*)g,
      (__attribute__((address_space(3))) void*)l, 16, 0, 0);
}

// ---------------- weight/activation cast fp32 -> bf16 ----------------

__global__ void k_cast(const float* __restrict__ in, unsigned short* __restrict__ out, int n) {
  int i = blockIdx.x * blockDim.x + threadIdx.x;
  if (i >= n) return;
  out[i] = f2bf(in[i]);
}

// ---------------- CSR build ----------------

__global__ void k_deg(const int* __restrict__ ei, int* __restrict__ deg) {
  int i = blockIdx.x * blockDim.x + threadIdx.x;
  if (i >= E2) return;
  int dst = (i < EE) ? ei[EE + i] : (i - EE);
  atomicAdd(&deg[dst], 1);
}

__global__ __launch_bounds__(1024) void k_scan_tile(const int* __restrict__ in,
                                                    int* __restrict__ out,
                                                    int* __restrict__ tsum, int n) {
  __shared__ int sm[1024];
  int tid = threadIdx.x;
  int g = blockIdx.x * 1024 + tid;
  sm[tid] = (g < n) ? in[g] : 0;
  __syncthreads();
  for (int off = 1; off < 1024; off <<= 1) {
    int t = (tid >= off) ? sm[tid - off] : 0;
    __syncthreads();
    sm[tid] += t;
    __syncthreads();
  }
  if (g < n) out[g] = sm[tid];
  if (tid == 1023) tsum[blockIdx.x] = sm[1023];
}

__global__ void k_scan_sums(int* __restrict__ tsum, int nb) {
  int tid = threadIdx.x;           // single wave of 64, nb <= 64
  int v = (tid < nb) ? tsum[tid] : 0;
  for (int off = 1; off < 64; off <<= 1) {
    int t = __shfl_up(v, off);
    if (tid >= off) v += t;
  }
  if (tid < nb) tsum[tid] = v;
}

__global__ void k_scan_add(int* __restrict__ out, const int* __restrict__ tsum, int n) {
  int g = blockIdx.x * blockDim.x + threadIdx.x;
  if (g >= n || g < 1024) return;
  out[g] += tsum[(g >> 10) - 1];
}

__global__ void k_scatter(const int* __restrict__ ei, const int* __restrict__ deg,
                          const int* __restrict__ inc, int* __restrict__ cur,
                          int* __restrict__ ssrc) {
  int i = blockIdx.x * blockDim.x + threadIdx.x;
  if (i >= E2) return;
  int src, dst;
  if (i < EE) { src = ei[i]; dst = ei[EE + i]; } else { src = dst = i - EE; }
  int pos = atomicAdd(&cur[dst], 1);
  ssrc[inc[dst] - deg[dst] + pos] = src;
}

// ---------------- GAT pieces (h in bf16) ----------------

__global__ __launch_bounds__(256) void k_dots(const unsigned short* __restrict__ hb,
                                              const float* __restrict__ asrc,
                                              const float* __restrict__ adst,
                                              float* __restrict__ hs, float* __restrict__ hd) {
  int node = blockIdx.x * 4 + (threadIdx.x >> 6);
  if (node >= NN) return;
  int lane = threadIdx.x & 63;
  ushort4 hv = *reinterpret_cast<const ushort4*>(hb + (size_t)node * DD + lane * 4);
  float v0 = bf2f(hv.x), v1 = bf2f(hv.y), v2 = bf2f(hv.z), v3 = bf2f(hv.w);
  const float* as = asrc + lane * 4;
  const float* ad = adst + lane * 4;
  float s1 = v0 * as[0] + v1 * as[1] + v2 * as[2] + v3 * as[3];
  float s2 = v0 * ad[0] + v1 * ad[1] + v2 * ad[2] + v3 * ad[3];
  for (int off = 32; off; off >>= 1) {
    s1 += __shfl_xor(s1, off);
    s2 += __shfl_xor(s2, off);
  }
  if (lane == 0) { hs[node] = s1; hd[node] = s2; }
}

// Fused edge-softmax + aggregation: one wave per dst node.
__global__ __launch_bounds__(256) void k_gat(const unsigned short* __restrict__ hb,
                                             const int* __restrict__ ssrc,
                                             const int* __restrict__ deg,
                                             const int* __restrict__ inc,
                                             const float* __restrict__ hs,
                                             const float* __restrict__ hd,
                                             const float* __restrict__ bias,
                                             unsigned short* __restrict__ out) {
  __shared__ float sE[4][256];
  __shared__ int   sI[4][256];
  int w = threadIdx.x >> 6;
  int d = blockIdx.x * 4 + w;
  if (d >= NN) return;
  int lane = threadIdx.x & 63;
  int end = inc[d], cnt = deg[d], base = end - cnt;
  if (cnt > 256) cnt = 256;
  float hdd = hd[d];

  float m = -1e30f;
  for (int i0 = 0; i0 < cnt; i0 += 64) {
    int i = i0 + lane;
    float sc = -1e30f;
    if (i < cnt) {
      int s = ssrc[base + i];
      float v = hs[s] + hdd;
      sc = (v < 0.f) ? 0.2f * v : v;
      sI[w][i] = s;
      sE[w][i] = sc;
    }
    float mm = sc;
    for (int o = 32; o; o >>= 1) mm = fmaxf(mm, __shfl_xor(mm, o));
    m = fmaxf(m, mm);
  }
  float sum = 0.f;
  for (int i0 = 0; i0 < cnt; i0 += 64) {
    int i = i0 + lane;
    float e = 0.f;
    if (i < cnt) {
      e = __expf(sE[w][i] - m);
      sE[w][i] = e;
    }
    for (int o = 32; o; o >>= 1) e += __shfl_xor(e, o);
    sum += e;
  }
  float inv = 1.f / sum;

  float a0 = 0.f, a1 = 0.f, a2 = 0.f, a3 = 0.f;
  for (int i = 0; i < cnt; ++i) {
    float a = sE[w][i];
    int s = sI[w][i];
    ushort4 hv = *reinterpret_cast<const ushort4*>(hb + (size_t)s * DD + lane * 4);
    a0 += a * bf2f(hv.x);
    a1 += a * bf2f(hv.y);
    a2 += a * bf2f(hv.z);
    a3 += a * bf2f(hv.w);
  }
  const float* bp = bias + lane * 4;
  float r0 = a0 * inv + bp[0], r1 = a1 * inv + bp[1];
  float r2 = a2 * inv + bp[2], r3 = a3 * inv + bp[3];
  ushort4 o;
  o.x = f2bf(r0 > 0.f ? r0 : 0.f);
  o.y = f2bf(r1 > 0.f ? r1 : 0.f);
  o.z = f2bf(r2 > 0.f ? r2 : 0.f);
  o.w = f2bf(r3 > 0.f ? r3 : 0.f);
  *reinterpret_cast<ushort4*>(out + (size_t)d * DD + lane * 4) = o;
}

// LDS k-chunk swizzle (bank-conflict-free fragment reads):
// LDS slot (row, c) holds global k-chunk  c ^ ((row>>1)&3)  within each 32-k group.
// Fragment read of logical chunk q at row (16-aligned base + m_lane):
//   position = q ^ ((m_lane>>1)&3).  Direct-global reads use logical chunk = quad.
// Row stride MUST be 64 B ([*][32 shorts]) for conflict-free b128 reads.

// ---------------- k_ff-structure GEMM: C = A @ W^T + bias ------
// A [M x K] bf16, W [N x K] bf16 (L2-resident), C [M x N] bf16. K in {128, 256}.
// 80-row tile, 8 waves. Wave w stages k-group w (all waves participate),
// then streams W rows from L2; swapped mfma(W, A); no barriers after stage.

__global__ __launch_bounds__(512, 4) void k_gemmT(
    const unsigned short* __restrict__ A,
    const unsigned short* __restrict__ W,
    const float* __restrict__ bias,            // [N] or null
    unsigned short* __restrict__ C,
    int M, int N, int K) {
  __shared__ unsigned short As[8 * 80 * 32];   // up to 40 KB  [kgrp][row][32]

  const int tid  = threadIdx.x;
  const int lane = tid & 63;
  const int w    = tid >> 6;        // 0..7
  const int ml   = lane & 15;
  const int quad = lane >> 4;
  const int m0   = blockIdx.x * 80;
  const int swz  = (quad ^ ((ml >> 1) & 3)) << 3;
  const int KG   = K >> 5;          // kgroups (4 or 8)

  // ---- stage A tile 80xK: wave w stages k-group w (5 rounds of 64 lanes) ----
  if (w < KG) {
#pragma unroll
    for (int r = 0; r < 5; ++r) {
      int e = r * 64 + lane;          // 0..319 within kgroup
      int row = e >> 2, ch = e & 3;
      int rg = m0 + row; if (rg >= M) rg = M - 1;
      int cs = ch ^ ((row >> 1) & 3);
      load_lds16(A + (size_t)rg * K + w * 32 + (cs << 3),
                 As + (size_t)(w * 320 + r * 64) * 8);   // HW adds lane*16B
    }
  }
  __syncthreads();

  const int nkb = N >> 8;
  for (int kb = 0; kb < nkb; ++kb) {
    f32x4 acc1[2][5] = {};
    const unsigned short* Wp = W + (size_t)(kb * 256 + w * 32 + ml) * K + quad * 8;
    __builtin_amdgcn_s_setprio(1);
#pragma unroll 2
    for (int ks = 0; ks < KG; ++ks) {
      bf16x8 af[2], bg[5];
#pragma unroll
      for (int i = 0; i < 2; ++i)
        af[i] = *reinterpret_cast<const bf16x8*>(Wp + (size_t)i * 16 * K + ks * 32);
#pragma unroll
      for (int j = 0; j < 5; ++j)
        bg[j] = *reinterpret_cast<const bf16x8*>(&As[ks * 2560 + (j * 16 + ml) * 32 + swz]);
#pragma unroll
      for (int i = 0; i < 2; ++i)
#pragma unroll
        for (int j = 0; j < 5; ++j)
          acc1[i][j] = __builtin_amdgcn_mfma_f32_16x16x32_bf16(af[i], bg[j], acc1[i][j], 0, 0, 0);
    }
    __builtin_amdgcn_s_setprio(0);

    // bias + global store (4 consecutive cols per lane = 8 B)
#pragma unroll
    for (int i = 0; i < 2; ++i) {
      int colb = kb * 256 + w * 32 + i * 16 + quad * 4;
      float4 bv = make_float4(0.f, 0.f, 0.f, 0.f);
      if (bias) bv = *reinterpret_cast<const float4*>(bias + colb);
#pragma unroll
      for (int j = 0; j < 5; ++j) {
        int rg = m0 + j * 16 + ml;
        if (rg < M) {
          ushort4 hv;
          hv.x = f2bf(acc1[i][j][0] + bv.x);
          hv.y = f2bf(acc1[i][j][1] + bv.y);
          hv.z = f2bf(acc1[i][j][2] + bv.z);
          hv.w = f2bf(acc1[i][j][3] + bv.w);
          *reinterpret_cast<ushort4*>(C + (size_t)rg * N + colb) = hv;
        }
      }
    }
  }
}

// ---------------- fused attention + o-proj + bias + residual + LayerNorm ----------
// 48-row blocks = 16 nodes, 256 thr / 4 waves.
// Phase 1 (vectorized): lane l owns cols 4l..4l+3 of the 256-wide q/k/v rows
//   (covers ALL 4 heads at once; head = l>>4). 9 ushort4 loads per node.
//   Logit reduce = 4-step shfl_xor within 16-lane head-group (all lanes get
//   the sum -> softmax computed redundantly, no broadcast). 8B packed As writes.
// Phase 2: [48x256] @ Wo^T with Wo streamed from L2, no inner barriers.

__global__ __launch_bounds__(256) void k_oproj(
    const unsigned short* __restrict__ qkvb,   // [M x 768] raw q|k|v
    const unsigned short* __restrict__ Wo,     // [256 x 256]
    const float* __restrict__ bo,
    const float* __restrict__ gam, const float* __restrict__ bet,
    unsigned short* __restrict__ seqc,         // residual in / out, [M x 256]
    int M) {
  __shared__ unsigned short As[8 * 48 * 32];   // 24 KB attention-out, [kgrp][row][32]
  __shared__ float sSum[4 * 48];
  __shared__ float sSq[4 * 48];

  const int tid  = threadIdx.x;
  const int lane = tid & 63;
  const int w    = tid >> 6;
  const int ml   = lane & 15;
  const int quad = lane >> 4;
  const int m0   = blockIdx.x * 48;
  const int swz  = (quad ^ ((ml >> 1) & 3)) * 8;

  // ---- phase 1: attention, lane owns 4 consecutive cols across all heads ----
  const int c0 = lane * 4;
  for (int i = 0; i < 4; ++i) {
    int r0 = (w * 4 + i) * 3;                  // local row of token 0
    size_t rowg[3];
#pragma unroll
    for (int t = 0; t < 3; ++t) {
      int rg = m0 + r0 + t;
      rowg[t] = (size_t)(rg < M ? rg : M - 1);
    }
    float q[3][4], k[3][4], v[3][4];
#pragma unroll
    for (int t = 0; t < 3; ++t) {
      size_t base = rowg[t] * 768 + c0;
      ushort4 uq = *reinterpret_cast<const ushort4*>(qkvb + base);
      ushort4 uk = *reinterpret_cast<const ushort4*>(qkvb + base + 256);
      ushort4 uv = *reinterpret_cast<const ushort4*>(qkvb + base + 512);
      q[t][0] = bf2f(uq.x); q[t][1] = bf2f(uq.y); q[t][2] = bf2f(uq.z); q[t][3] = bf2f(uq.w);
      k[t][0] = bf2f(uk.x); k[t][1] = bf2f(uk.y); k[t][2] = bf2f(uk.z); k[t][3] = bf2f(uk.w);
      v[t][0] = bf2f(uv.x); v[t][1] = bf2f(uv.y); v[t][2] = bf2f(uv.z); v[t][3] = bf2f(uv.w);
    }
    float lg[3][3];
#pragma unroll
    for (int a = 0; a < 3; ++a)
#pragma unroll
      for (int b = 0; b < 3; ++b) {
        float p = q[a][0] * k[b][0] + q[a][1] * k[b][1] +
                  q[a][2] * k[b][2] + q[a][3] * k[b][3];
        p += __shfl_xor(p, 1);
        p += __shfl_xor(p, 2);
        p += __shfl_xor(p, 4);
        p += __shfl_xor(p, 8);     // sum over 16-lane head-group
        lg[a][b] = p * 0.125f;
      }
#pragma unroll
    for (int a = 0; a < 3; ++a) {
      float mx = fmaxf(lg[a][0], fmaxf(lg[a][1], lg[a][2]));
      float e0 = __expf(lg[a][0] - mx);
      float e1 = __expf(lg[a][1] - mx);
      float e2 = __expf(lg[a][2] - mx);
      float inv = 1.f / (e0 + e1 + e2);
      int row = r0 + a;
      int g = lane >> 3;               // (4*lane)>>5
      int cch = (lane >> 1) & 3;       // ((4*lane)>>3)&3
      int addr = (g * 48 + row) * 32 + ((cch ^ ((row >> 1) & 3)) << 3) + ((lane & 1) << 2);
      ushort4 hv;
      hv.x = f2bf((e0 * v[0][0] + e1 * v[1][0] + e2 * v[2][0]) * inv);
      hv.y = f2bf((e0 * v[0][1] + e1 * v[1][1] + e2 * v[2][1]) * inv);
      hv.z = f2bf((e0 * v[0][2] + e1 * v[1][2] + e2 * v[2][2]) * inv);
      hv.w = f2bf((e0 * v[0][3] + e1 * v[1][3] + e2 * v[2][3]) * inv);
      *reinterpret_cast<ushort4*>(&As[addr]) = hv;
    }
  }
  __syncthreads();   // As complete

  // ---- phase 2: GEMM [48 x 256] @ Wo^T, Wo rows streamed from L2, no barriers
  f32x4 acc[3][4] = {};
  const unsigned short* Wop = Wo + (size_t)(w * 64 + ml) * 256 + quad * 8;
  __builtin_amdgcn_s_setprio(1);
#pragma unroll 2
  for (int t = 0; t < 8; ++t) {
    bf16x8 af[3], bg[4];
#pragma unroll
    for (int i = 0; i < 3; ++i)
      af[i] = *reinterpret_cast<const bf16x8*>(&As[(t * 48 + i * 16 + ml) * 32 + swz]);
#pragma unroll
    for (int j = 0; j < 4; ++j)
      bg[j] = *reinterpret_cast<const bf16x8*>(Wop + (size_t)j * 16 * 256 + t * 32);
#pragma unroll
    for (int i = 0; i < 3; ++i)
#pragma unroll
      for (int j = 0; j < 4; ++j)
        acc[i][j] = __builtin_amdgcn_mfma_f32_16x16x32_bf16(af[i], bg[j], acc[i][j], 0, 0, 0);
  }
  __builtin_amdgcn_s_setprio(0);

  // ---- bias + residual + per-row partial stats over this wave's 64 cols ----
  float bov[4], gv[4], btv[4];
#pragma unroll
  for (int j = 0; j < 4; ++j) {
    int col = w * 64 + j * 16 + ml;
    bov[j] = bo[col]; gv[j] = gam[col]; btv[j] = bet[col];
  }

#pragma unroll
  for (int i = 0; i < 3; ++i)
#pragma unroll
    for (int r = 0; r < 4; ++r) {
      int row = i * 16 + quad * 4 + r;
      int rg = m0 + row;
      size_t rr2 = (size_t)(rg < M ? rg : M - 1);
      float s = 0.f, s2 = 0.f;
#pragma unroll
      for (int j = 0; j < 4; ++j) {
        int col = w * 64 + j * 16 + ml;
        float t = acc[i][j][r] + bov[j] + bf2f(seqc[rr2 * 256 + col]);
        acc[i][j][r] = t;
        s += t; s2 += t * t;
      }
#pragma unroll
      for (int o = 1; o < 16; o <<= 1) { s += __shfl_xor(s, o); s2 += __shfl_xor(s2, o); }
      if (ml == 0) { sSum[w * 48 + row] = s; sSq[w * 48 + row] = s2; }
    }
  __syncthreads();

#pragma unroll
  for (int i = 0; i < 3; ++i)
#pragma unroll
    for (int r = 0; r < 4; ++r) {
      int row = i * 16 + quad * 4 + r;
      int rg = m0 + row;
      if (rg >= M) continue;
      float s  = sSum[row] + sSum[48 + row] + sSum[96 + row] + sSum[144 + row];
      float s2 = sSq[row]  + sSq[48 + row]  + sSq[96 + row]  + sSq[144 + row];
      float mean = s * (1.f / 256.f);
      float var  = s2 * (1.f / 256.f) - mean * mean;
      float inv  = rsqrtf(var + 1e-5f);
#pragma unroll
      for (int j = 0; j < 4; ++j) {
        int col = w * 64 + j * 16 + ml;
        seqc[(size_t)rg * 256 + col] = f2bf((acc[i][j][r] - mean) * inv * gv[j] + btv[j]);
      }
    }
}

// ---------------- fused FFN: relu(A@W1^T+b1)@W2^T + b2 + residual(A) + LN ----------
// 80-row tile, 8 waves, 80 KB LDS -> exactly 2 co-resident blocks/CU (verified:
// 119 -> 89 us vs 128-row). All-wave staging (wave w stages k-group w);
// setprio(1) around MFMA clusters (T5: 2-block phase diversity).

__global__ __launch_bounds__(512, 4) void k_ff(
    unsigned short* __restrict__ A,
    const unsigned short* __restrict__ W1,
    const float* __restrict__ b1,
    const unsigned short* __restrict__ W2,
    const float* __restrict__ b2,
    const float* __restrict__ gam, const float* __restrict__ bet,
    int M) {
  __shared__ unsigned short As[8 * 80 * 32];   // 40 KB  [kgrp][row][32]
  __shared__ unsigned short Hs[8 * 80 * 32];   // 40 KB  (reused as LN scratch)

  const int tid  = threadIdx.x;
  const int lane = tid & 63;
  const int w    = tid >> 6;        // 0..7
  const int ml   = lane & 15;
  const int quad = lane >> 4;
  const int m0   = blockIdx.x * 80;
  const int swz  = (quad ^ ((ml >> 1) & 3)) << 3;

  // ---- stage A tile 80x256: wave w stages k-group w (5 rounds of 64 lanes) ----
  {
#pragma unroll
    for (int r = 0; r < 5; ++r) {
      int e = r * 64 + lane;
      int row = e >> 2, ch = e & 3;
      int rg = m0 + row; if (rg >= M) rg = M - 1;
      int cs = ch ^ ((row >> 1) & 3);
      load_lds16(A + (size_t)rg * 256 + w * 32 + (cs << 3),
                 As + (size_t)(w * 320 + r * 64) * 8);   // HW adds lane*16B
    }
  }
  __syncthreads();

  f32x4 acc2[5][2] = {};

  for (int kb = 0; kb < 4; ++kb) {
    f32x4 acc1[2][5] = {};
    const unsigned short* W1p = W1 + (size_t)(kb * 256 + w * 32 + ml) * 256 + quad * 8;
    __builtin_amdgcn_s_setprio(1);
#pragma unroll 2
    for (int ks = 0; ks < 8; ++ks) {
      bf16x8 af[2], bg[5];
#pragma unroll
      for (int i = 0; i < 2; ++i)
        af[i] = *reinterpret_cast<const bf16x8*>(W1p + (size_t)i * 16 * 256 + ks * 32);
#pragma unroll
      for (int j = 0; j < 5; ++j)
        bg[j] = *reinterpret_cast<const bf16x8*>(&As[ks * 2560 + (j * 16 + ml) * 32 + swz]);
#pragma unroll
      for (int i = 0; i < 2; ++i)
#pragma unroll
        for (int j = 0; j < 5; ++j)
          acc1[i][j] = __builtin_amdgcn_mfma_f32_16x16x32_bf16(af[i], bg[j], acc1[i][j], 0, 0, 0);
    }
    __builtin_amdgcn_s_setprio(0);

    __syncthreads();   // previous GEMM2 readers of Hs are done

#pragma unroll
    for (int i = 0; i < 2; ++i) {
      float4 bv = *reinterpret_cast<const float4*>(b1 + kb * 256 + w * 32 + i * 16 + quad * 4);
      int c  = i * 2 + (quad >> 1);
      int lo = (quad & 1) * 4;
#pragma unroll
      for (int j = 0; j < 5; ++j) {
        int seqrow = j * 16 + ml;
        int chsw = c ^ ((ml >> 1) & 3);
        int addr = w * 2560 + seqrow * 32 + (chsw << 3) + lo;
        float t0 = acc1[i][j][0] + bv.x; t0 = t0 > 0.f ? t0 : 0.f;
        float t1 = acc1[i][j][1] + bv.y; t1 = t1 > 0.f ? t1 : 0.f;
        float t2 = acc1[i][j][2] + bv.z; t2 = t2 > 0.f ? t2 : 0.f;
        float t3 = acc1[i][j][3] + bv.w; t3 = t3 > 0.f ? t3 : 0.f;
        ushort4 hv;
        hv.x = f2bf(t0); hv.y = f2bf(t1); hv.z = f2bf(t2); hv.w = f2bf(t3);
        *reinterpret_cast<ushort4*>(&Hs[addr]) = hv;
      }
    }
    __syncthreads();   // Hs visible to all waves

    const unsigned short* W2p = W2 + (size_t)(w * 32 + ml) * 1024 + kb * 256 + quad * 8;
    __builtin_amdgcn_s_setprio(1);
#pragma unroll 2
    for (int ks = 0; ks < 8; ++ks) {
      bf16x8 af[5], bg[2];
#pragma unroll
      for (int i = 0; i < 5; ++i)
        af[i] = *reinterpret_cast<const bf16x8*>(&Hs[ks * 2560 + (i * 16 + ml) * 32 + swz]);
#pragma unroll
      for (int j = 0; j < 2; ++j)
        bg[j] = *reinterpret_cast<const bf16x8*>(W2p + (size_t)j * 16 * 1024 + ks * 32);
#pragma unroll
      for (int i = 0; i < 5; ++i)
#pragma unroll
        for (int j = 0; j < 2; ++j)
          acc2[i][j] = __builtin_amdgcn_mfma_f32_16x16x32_bf16(af[i], bg[j], acc2[i][j], 0, 0, 0);
    }
    __builtin_amdgcn_s_setprio(0);
  }

  __syncthreads();   // all Hs reads done -> reuse Hs as LN scratch
  float* sS = reinterpret_cast<float*>(Hs);   // [8][80]
  float* sQ = sS + 640;                        // [8][80]

  float b2v[2], gv[2], btv[2];
#pragma unroll
  for (int j = 0; j < 2; ++j) {
    int col = w * 32 + j * 16 + ml;
    b2v[j] = b2[col]; gv[j] = gam[col]; btv[j] = bet[col];
  }

  // bias + residual (from As LDS) + per-row partial stats over this wave's 32 cols
#pragma unroll
  for (int i = 0; i < 5; ++i)
#pragma unroll
    for (int r = 0; r < 4; ++r) {
      int row = i * 16 + quad * 4 + r;
      float s = 0.f, s2 = 0.f;
#pragma unroll
      for (int j = 0; j < 2; ++j) {
        int c_r = j * 2 + (ml >> 3);
        float t = acc2[i][j][r] + b2v[j] +
                  bf2f(As[w * 2560 + row * 32 + ((c_r ^ ((row >> 1) & 3)) << 3) + (ml & 7)]);
        acc2[i][j][r] = t;
        s += t; s2 += t * t;
      }
#pragma unroll
      for (int o = 1; o < 16; o <<= 1) { s += __shfl_xor(s, o); s2 += __shfl_xor(s2, o); }
      if (ml == 0) { sS[w * 80 + row] = s; sQ[w * 80 + row] = s2; }
    }
  __syncthreads();

#pragma unroll
  for (int i = 0; i < 5; ++i)
#pragma unroll
    for (int r = 0; r < 4; ++r) {
      int row = i * 16 + quad * 4 + r;
      int rg = m0 + row;
      if (rg >= M) continue;
      float s = 0.f, s2 = 0.f;
#pragma unroll
      for (int ww = 0; ww < 8; ++ww) { s += sS[ww * 80 + row]; s2 += sQ[ww * 80 + row]; }
      float mean = s * (1.f / 256.f);
      float var  = s2 * (1.f / 256.f) - mean * mean;
      float inv  = rsqrtf(var + 1e-5f);
#pragma unroll
      for (int j = 0; j < 2; ++j) {
        int col = w * 32 + j * 16 + ml;
        A[(size_t)rg * 256 + col] = f2bf((acc2[i][j][r] - mean) * inv * gv[j] + btv[j]);
      }
    }
}

// ---------------- transformer pieces (bf16 activations, dense layouts) ----------------

__global__ void k_seqbuild(const unsigned short* __restrict__ x1,
                           const unsigned short* __restrict__ x2,
                           const float* __restrict__ cls, const float* __restrict__ pos,
                           unsigned short* __restrict__ seqc, int n0, int cn) {
  int idx = blockIdx.x * blockDim.x + threadIdx.x;
  int total = cn * 3 * DD;
  if (idx >= total) return;
  int c = idx & (DD - 1);
  int r = idx >> 8;
  int t = r % 3, ln = r / 3;
  int n = n0 + ln;
  float v;
  if (t == 0)      v = cls[c];
  else if (t == 1) v = bf2f(x1[(size_t)n * DD + c]);
  else             v = bf2f(x2[(size_t)n * DD + c]);
  seqc[idx] = f2bf(v + pos[t * DD + c]);
}

__global__ __launch_bounds__(256) void k_final(const unsigned short* __restrict__ seqc,
                                               int n0, int cn,
                                               const float* __restrict__ g,
                                               const float* __restrict__ b,
                                               float* __restrict__ out) {
  int ln = blockIdx.x * 4 + (threadIdx.x >> 6);
  if (ln >= cn) return;
  int lane = threadIdx.x & 63;
  const unsigned short* p = seqc + (size_t)ln * 3 * DD;   // token 0 row
  float v[4];
  float s = 0.f, s2 = 0.f;
#pragma unroll
  for (int i = 0; i < 4; ++i) {
    v[i] = bf2f(p[i * 64 + lane]);
    s += v[i]; s2 += v[i] * v[i];
  }
  for (int off = 32; off; off >>= 1) { s += __shfl_xor(s, off); s2 += __shfl_xor(s2, off); }
  float mean = s * (1.f / 256.f);
  float var  = s2 * (1.f / 256.f) - mean * mean;
  float inv  = rsqrtf(var + 1e-5f);
#pragma unroll
  for (int i = 0; i < 4; ++i) {
    int c = i * 64 + lane;
    out[(size_t)(n0 + ln) * DD + c] = (v[i] - mean) * inv * g[c] + b[c];
  }
}

// ---------------- host ----------------

extern "C" void kernel_launch(void* const* d_in, const int* in_sizes, int n_in,
                              void* d_out, int out_size, void* d_ws, size_t ws_size,
                              hipStream_t stream) {
  const float* x       = (const float*)d_in[0];
  const int*   ei      = (const int*)d_in[1];
  const float* gat1_W  = (const float*)d_in[2];
  const float* gat1_b  = (const float*)d_in[3];
  const float* gat1_as = (const float*)d_in[4];
  const float* gat1_ad = (const float*)d_in[5];
  const float* gat2_W  = (const float*)d_in[6];
  const float* gat2_b  = (const float*)d_in[7];
  const float* gat2_as = (const float*)d_in[8];
  const float* gat2_ad = (const float*)d_in[9];
  const float* cls     = (const float*)d_in[10];
  const float* pos     = (const float*)d_in[11];
  const float* Wqkv    = (const float*)d_in[12];
  const float* bqkv    = (const float*)d_in[13];
  const float* Wo      = (const float*)d_in[14];
  const float* bo      = (const float*)d_in[15];
  const float* ln1_g   = (const float*)d_in[16];
  const float* ln1_b   = (const float*)d_in[17];
  const float* ln2_g   = (const float*)d_in[18];
  const float* ln2_b   = (const float*)d_in[19];
  const float* Wff1    = (const float*)d_in[20];
  const float* bff1    = (const float*)d_in[21];
  const float* Wff2    = (const float*)d_in[22];
  const float* bff2    = (const float*)d_in[23];
  const float* norm_g  = (const float*)d_in[24];
  const float* norm_b  = (const float*)d_in[25];
  float* out = (float*)d_out;

  char* ws = (char*)d_ws;
  size_t off = 0;
  auto alloc = [&](size_t bytes) -> void* {
    off = (off + 255) & ~(size_t)255;
    void* p = ws + off;
    off += bytes;
    return p;
  };

  unsigned short* wb_g1  = (unsigned short*)alloc(sizeof(unsigned short) * 256 * 128);
  unsigned short* wb_g2  = (unsigned short*)alloc(sizeof(unsigned short) * 256 * 256);
  unsigned short* wb_qkv = (unsigned short*)alloc(sizeof(unsigned short) * 2 * 768 * 256);
  unsigned short* wb_o   = (unsigned short*)alloc(sizeof(unsigned short) * 2 * 256 * 256);
  unsigned short* wb_f1  = (unsigned short*)alloc(sizeof(unsigned short) * 2 * 1024 * 256);
  unsigned short* wb_f2  = (unsigned short*)alloc(sizeof(unsigned short) * 2 * 256 * 1024);
  unsigned short* xb  = (unsigned short*)alloc(sizeof(unsigned short) * (size_t)NN * DIN);
  unsigned short* hb  = (unsigned short*)alloc(sizeof(unsigned short) * (size_t)NN * DD);
  unsigned short* x1b = (unsigned short*)alloc(sizeof(unsigned short) * (size_t)NN * DD);
  unsigned short* x2b = (unsigned short*)alloc(sizeof(unsigned short) * (size_t)NN * DD);
  float* hs  = (float*)alloc(sizeof(float) * NN);
  float* hd  = (float*)alloc(sizeof(float) * NN);
  int* deg   = (int*)alloc(sizeof(int) * NN);
  int* inc   = (int*)alloc(sizeof(int) * NN);
  int* cur   = (int*)alloc(sizeof(int) * NN);
  int* tsum  = (int*)alloc(sizeof(int) * 64);
  int* ssrc  = (int*)alloc(sizeof(int) * E2);

  // transformer chunking (L3 residency of per-chunk activations)
  size_t fixed = (off + 255) & ~(size_t)255;
  size_t rem = (ws_size > fixed + 4096) ? (ws_size - fixed - 4096) : 0;
  const size_t per_node = (size_t)3 * (256 + 768) * 2;
  size_t cn_max = rem / per_node;
  if (cn_max < 1) cn_max = 1;
  if (cn_max > 12500) cn_max = 12500;
  int nc = (int)((NN + cn_max - 1) / cn_max);
  int cn = (NN + nc - 1) / nc;
  unsigned short* seqc = (unsigned short*)alloc(sizeof(unsigned short) * (size_t)3 * cn * 256);
  unsigned short* qkvb = (unsigned short*)alloc(sizeof(unsigned short) * (size_t)3 * cn * 768);

  // ---- casts ----
  auto cast = [&](const float* src, unsigned short* dst, int n) {
    k_cast<<<(n + 255) / 256, 256, 0, stream>>>(src, dst, n);
  };
  cast(gat1_W, wb_g1, 256 * 128);
  cast(gat2_W, wb_g2, 256 * 256);
  cast(Wqkv, wb_qkv, 2 * 768 * 256);
  cast(Wo, wb_o, 2 * 256 * 256);
  cast(Wff1, wb_f1, 2 * 1024 * 256);
  cast(Wff2, wb_f2, 2 * 256 * 1024);
  cast(x, xb, NN * DIN);

  // ---- CSR build ----
  hipMemsetAsync(deg, 0, sizeof(int) * NN, stream);
  hipMemsetAsync(cur, 0, sizeof(int) * NN, stream);
  k_deg<<<(E2 + 255) / 256, 256, 0, stream>>>(ei, deg);
  int nb = (NN + 1023) / 1024;
  k_scan_tile<<<nb, 1024, 0, stream>>>(deg, inc, tsum, NN);
  k_scan_sums<<<1, 64, 0, stream>>>(tsum, nb);
  k_scan_add<<<(NN + 255) / 256, 256, 0, stream>>>(inc, tsum, NN);
  k_scatter<<<(E2 + 255) / 256, 256, 0, stream>>>(ei, deg, inc, cur, ssrc);

  // ---- GAT layer 1: hb = xb @ W1^T (K=128, k_ff-structure) ----
  k_gemmT<<<(NN + 79) / 80, 512, 0, stream>>>(xb, wb_g1, nullptr, hb, NN, 256, 128);
  k_dots<<<(NN + 3) / 4, 256, 0, stream>>>(hb, gat1_as, gat1_ad, hs, hd);
  k_gat<<<(NN + 3) / 4, 256, 0, stream>>>(hb, ssrc, deg, inc, hs, hd, gat1_b, x1b);

  // ---- GAT layer 2: hb = x1b @ W2^T (K=256, k_ff-structure) ----
  k_gemmT<<<(NN + 79) / 80, 512, 0, stream>>>(x1b, wb_g2, nullptr, hb, NN, 256, 256);
  k_dots<<<(NN + 3) / 4, 256, 0, stream>>>(hb, gat2_as, gat2_ad, hs, hd);
  k_gat<<<(NN + 3) / 4, 256, 0, stream>>>(hb, ssrc, deg, inc, hs, hd, gat2_b, x2b);

  // ---- transformer (chunked) ----
  for (int n0 = 0; n0 < NN; n0 += cn) {
    int c = NN - n0 < cn ? NN - n0 : cn;
    int Mch = 3 * c;
    int mblk48 = (Mch + 47) / 48;
    int mblk80 = (Mch + 79) / 80;
    k_seqbuild<<<(c * 3 * DD + 255) / 256, 256, 0, stream>>>(x1b, x2b, cls, pos, seqc, n0, c);
    for (int l = 0; l < 2; ++l) {
      // qkv: N=768, K=256 via k_ff-structure GEMM (raw q|k|v + bias)
      k_gemmT<<<mblk80, 512, 0, stream>>>(
          seqc, wb_qkv + (size_t)l * 768 * 256, bqkv + l * 768, qkvb, Mch, 768, 256);
      // fused attention + o-proj + residual + ln1 (Wo streamed, vectorized attn)
      k_oproj<<<mblk48, 256, 0, stream>>>(
          qkvb, wb_o + (size_t)l * 256 * 256, bo + l * 256,
          ln1_g + l * 256, ln1_b + l * 256, seqc, Mch);
      // fused ff1+relu+ff2+residual+ln2 (no global intermediate), 80-row tiles
      k_ff<<<mblk80, 512, 0, stream>>>(
          seqc, wb_f1 + (size_t)l * 1024 * 256, bff1 + l * 1024,
          wb_f2 + (size_t)l * 256 * 1024, bff2 + l * 256,
          ln2_g + l * 256, ln2_b + l * 256, Mch);
    }
    k_final<<<(c + 3) / 4, 256, 0, stream>>>(seqc, n0, c, norm_g, norm_b, out);
  }
}

// Round 13
// 1728.788 us; speedup vs baseline: 1.3311x; 1.0061x over previous
//
#include <hip/hip_runtime.h>
#include <hip/hip_bf16.h>

#define NN  50000
#define EE  320000
#define E2  (EE + NN)
#define DIN 128
#define DD  256

typedef __attribute__((ext_vector_type(8))) short          bf16x8;
typedef __attribute__((ext_vector_type(8))) unsigned short u16x8;
typedef __attribute__((ext_vector_type(4))) float          f32x4;

// ---------------- helpers ----------------

static __device__ __forceinline__ float bf2f(unsigned short u) {
  return __builtin_bit_cast(float, (unsigned)u << 16);
}

static __device__ __forceinline__ unsigned short f2bf(float f) {
  unsigned u = __builtin_bit_cast(unsigned, f);
  return (unsigned short)((u + 0x7fffu + ((u >> 16) & 1u)) >> 16);
}

static __device__ __forceinline__ void load_lds16(const void* g, void* l) {
  __builtin_amdgcn_global_load_lds(
      (const __attribute__((address_space(1))) void*)g,
      (__attribute__((address_space(3))) void*)l, 16, 0, 0);
}

// ---------------- weight/activation cast fp32 -> bf16 ----------------

__global__ void k_cast(const float* __restrict__ in, unsigned short* __restrict__ out, int n) {
  int i = blockIdx.x * blockDim.x + threadIdx.x;
  if (i >= n) return;
  out[i] = f2bf(in[i]);
}

// ---------------- CSR build ----------------

__global__ void k_deg(const int* __restrict__ ei, int* __restrict__ deg) {
  int i = blockIdx.x * blockDim.x + threadIdx.x;
  if (i >= E2) return;
  int dst = (i < EE) ? ei[EE + i] : (i - EE);
  atomicAdd(&deg[dst], 1);
}

__global__ __launch_bounds__(1024) void k_scan_tile(const int* __restrict__ in,
                                                    int* __restrict__ out,
                                                    int* __restrict__ tsum, int n) {
  __shared__ int sm[1024];
  int tid = threadIdx.x;
  int g = blockIdx.x * 1024 + tid;
  sm[tid] = (g < n) ? in[g] : 0;
  __syncthreads();
  for (int off = 1; off < 1024; off <<= 1) {
    int t = (tid >= off) ? sm[tid - off] : 0;
    __syncthreads();
    sm[tid] += t;
    __syncthreads();
  }
  if (g < n) out[g] = sm[tid];
  if (tid == 1023) tsum[blockIdx.x] = sm[1023];
}

__global__ void k_scan_sums(int* __restrict__ tsum, int nb) {
  int tid = threadIdx.x;           // single wave of 64, nb <= 64
  int v = (tid < nb) ? tsum[tid] : 0;
  for (int off = 1; off < 64; off <<= 1) {
    int t = __shfl_up(v, off);
    if (tid >= off) v += t;
  }
  if (tid < nb) tsum[tid] = v;
}

__global__ void k_scan_add(int* __restrict__ out, const int* __restrict__ tsum, int n) {
  int g = blockIdx.x * blockDim.x + threadIdx.x;
  if (g >= n || g < 1024) return;
  out[g] += tsum[(g >> 10) - 1];
}

__global__ void k_scatter(const int* __restrict__ ei, const int* __restrict__ deg,
                          const int* __restrict__ inc, int* __restrict__ cur,
                          int* __restrict__ ssrc) {
  int i = blockIdx.x * blockDim.x + threadIdx.x;
  if (i >= E2) return;
  int src, dst;
  if (i < EE) { src = ei[i]; dst = ei[EE + i]; } else { src = dst = i - EE; }
  int pos = atomicAdd(&cur[dst], 1);
  ssrc[inc[dst] - deg[dst] + pos] = src;
}

// ---------------- GAT pieces (h in bf16) ----------------

// Fused edge-softmax + aggregation: one wave per dst node.
__global__ __launch_bounds__(256) void k_gat(const unsigned short* __restrict__ hb,
                                             const int* __restrict__ ssrc,
                                             const int* __restrict__ deg,
                                             const int* __restrict__ inc,
                                             const float* __restrict__ hs,
                                             const float* __restrict__ hd,
                                             const float* __restrict__ bias,
                                             unsigned short* __restrict__ out) {
  __shared__ float sE[4][256];
  __shared__ int   sI[4][256];
  int w = threadIdx.x >> 6;
  int d = blockIdx.x * 4 + w;
  if (d >= NN) return;
  int lane = threadIdx.x & 63;
  int end = inc[d], cnt = deg[d], base = end - cnt;
  if (cnt > 256) cnt = 256;
  float hdd = hd[d];

  float m = -1e30f;
  for (int i0 = 0; i0 < cnt; i0 += 64) {
    int i = i0 + lane;
    float sc = -1e30f;
    if (i < cnt) {
      int s = ssrc[base + i];
      float v = hs[s] + hdd;
      sc = (v < 0.f) ? 0.2f * v : v;
      sI[w][i] = s;
      sE[w][i] = sc;
    }
    float mm = sc;
    for (int o = 32; o; o >>= 1) mm = fmaxf(mm, __shfl_xor(mm, o));
    m = fmaxf(m, mm);
  }
  float sum = 0.f;
  for (int i0 = 0; i0 < cnt; i0 += 64) {
    int i = i0 + lane;
    float e = 0.f;
    if (i < cnt) {
      e = __expf(sE[w][i] - m);
      sE[w][i] = e;
    }
    for (int o = 32; o; o >>= 1) e += __shfl_xor(e, o);
    sum += e;
  }
  float inv = 1.f / sum;

  float a0 = 0.f, a1 = 0.f, a2 = 0.f, a3 = 0.f;
  for (int i = 0; i < cnt; ++i) {
    float a = sE[w][i];
    int s = sI[w][i];
    ushort4 hv = *reinterpret_cast<const ushort4*>(hb + (size_t)s * DD + lane * 4);
    a0 += a * bf2f(hv.x);
    a1 += a * bf2f(hv.y);
    a2 += a * bf2f(hv.z);
    a3 += a * bf2f(hv.w);
  }
  const float* bp = bias + lane * 4;
  float r0 = a0 * inv + bp[0], r1 = a1 * inv + bp[1];
  float r2 = a2 * inv + bp[2], r3 = a3 * inv + bp[3];
  ushort4 o;
  o.x = f2bf(r0 > 0.f ? r0 : 0.f);
  o.y = f2bf(r1 > 0.f ? r1 : 0.f);
  o.z = f2bf(r2 > 0.f ? r2 : 0.f);
  o.w = f2bf(r3 > 0.f ? r3 : 0.f);
  *reinterpret_cast<ushort4*>(out + (size_t)d * DD + lane * 4) = o;
}

// LDS k-chunk swizzle (bank-conflict-free fragment reads):
// LDS slot (row, c) holds global k-chunk  c ^ ((row>>1)&3)  within each 32-k group.
// Fragment read of logical chunk q at row (16-aligned base + m_lane):
//   position = q ^ ((m_lane>>1)&3).  Direct-global reads use logical chunk = quad.
// Row stride MUST be 64 B ([*][32 shorts]) for conflict-free b128 reads.

// ---------------- k_ff-structure GEMM: C = A @ W^T + bias ------
// A [M x K] bf16, W [N x K] bf16 (L2-resident), C [M x N] bf16. K in {128, 256}.
// 80-row tile, 8 waves. Wave w stages k-group w, then streams W rows from L2;
// swapped mfma(W, A); no barriers after stage.

__global__ __launch_bounds__(512, 4) void k_gemmT(
    const unsigned short* __restrict__ A,
    const unsigned short* __restrict__ W,
    const float* __restrict__ bias,            // [N] or null
    unsigned short* __restrict__ C,
    int M, int N, int K) {
  __shared__ unsigned short As[8 * 80 * 32];   // up to 40 KB  [kgrp][row][32]

  const int tid  = threadIdx.x;
  const int lane = tid & 63;
  const int w    = tid >> 6;        // 0..7
  const int ml   = lane & 15;
  const int quad = lane >> 4;
  const int m0   = blockIdx.x * 80;
  const int swz  = (quad ^ ((ml >> 1) & 3)) << 3;
  const int KG   = K >> 5;          // kgroups (4 or 8)

  // ---- stage A tile 80xK: wave w stages k-group w (5 rounds of 64 lanes) ----
  if (w < KG) {
#pragma unroll
    for (int r = 0; r < 5; ++r) {
      int e = r * 64 + lane;          // 0..319 within kgroup
      int row = e >> 2, ch = e & 3;
      int rg = m0 + row; if (rg >= M) rg = M - 1;
      int cs = ch ^ ((row >> 1) & 3);
      load_lds16(A + (size_t)rg * K + w * 32 + (cs << 3),
                 As + (size_t)(w * 320 + r * 64) * 8);   // HW adds lane*16B
    }
  }
  __syncthreads();

  const int nkb = N >> 8;
  for (int kb = 0; kb < nkb; ++kb) {
    f32x4 acc1[2][5] = {};
    const unsigned short* Wp = W + (size_t)(kb * 256 + w * 32 + ml) * K + quad * 8;
    __builtin_amdgcn_s_setprio(1);
#pragma unroll 2
    for (int ks = 0; ks < KG; ++ks) {
      bf16x8 af[2], bg[5];
#pragma unroll
      for (int i = 0; i < 2; ++i)
        af[i] = *reinterpret_cast<const bf16x8*>(Wp + (size_t)i * 16 * K + ks * 32);
#pragma unroll
      for (int j = 0; j < 5; ++j)
        bg[j] = *reinterpret_cast<const bf16x8*>(&As[ks * 2560 + (j * 16 + ml) * 32 + swz]);
#pragma unroll
      for (int i = 0; i < 2; ++i)
#pragma unroll
        for (int j = 0; j < 5; ++j)
          acc1[i][j] = __builtin_amdgcn_mfma_f32_16x16x32_bf16(af[i], bg[j], acc1[i][j], 0, 0, 0);
    }
    __builtin_amdgcn_s_setprio(0);

    // bias + global store (4 consecutive cols per lane = 8 B)
#pragma unroll
    for (int i = 0; i < 2; ++i) {
      int colb = kb * 256 + w * 32 + i * 16 + quad * 4;
      float4 bv = make_float4(0.f, 0.f, 0.f, 0.f);
      if (bias) bv = *reinterpret_cast<const float4*>(bias + colb);
#pragma unroll
      for (int j = 0; j < 5; ++j) {
        int rg = m0 + j * 16 + ml;
        if (rg < M) {
          ushort4 hv;
          hv.x = f2bf(acc1[i][j][0] + bv.x);
          hv.y = f2bf(acc1[i][j][1] + bv.y);
          hv.z = f2bf(acc1[i][j][2] + bv.z);
          hv.w = f2bf(acc1[i][j][3] + bv.w);
          *reinterpret_cast<ushort4*>(C + (size_t)rg * N + colb) = hv;
        }
      }
    }
  }
}

// ---------------- GAT projection GEMM + fused attention-dot epilogue ----------
// Same structure as k_gemmT with N=256 fixed; additionally computes
// hs[row] = h . asrc, hd[row] = h . adst (k_dots fused: per-lane partials over
// its 8 cols -> quad shfl reduce -> cross-wave LDS reduce, k_ff-LN pattern).

__global__ __launch_bounds__(512, 4) void k_gemmD(
    const unsigned short* __restrict__ A,
    const unsigned short* __restrict__ W,
    unsigned short* __restrict__ C,            // hb [M x 256]
    const float* __restrict__ asrc, const float* __restrict__ adst,
    float* __restrict__ hs, float* __restrict__ hd,
    int M, int K) {
  __shared__ unsigned short As[8 * 80 * 32];   // up to 40 KB

  const int tid  = threadIdx.x;
  const int lane = tid & 63;
  const int w    = tid >> 6;
  const int ml   = lane & 15;
  const int quad = lane >> 4;
  const int m0   = blockIdx.x * 80;
  const int swz  = (quad ^ ((ml >> 1) & 3)) << 3;
  const int KG   = K >> 5;

  if (w < KG) {
#pragma unroll
    for (int r = 0; r < 5; ++r) {
      int e = r * 64 + lane;
      int row = e >> 2, ch = e & 3;
      int rg = m0 + row; if (rg >= M) rg = M - 1;
      int cs = ch ^ ((row >> 1) & 3);
      load_lds16(A + (size_t)rg * K + w * 32 + (cs << 3),
                 As + (size_t)(w * 320 + r * 64) * 8);
    }
  }
  __syncthreads();

  f32x4 acc1[2][5] = {};
  const unsigned short* Wp = W + (size_t)(w * 32 + ml) * K + quad * 8;
#pragma unroll 2
  for (int ks = 0; ks < KG; ++ks) {
    bf16x8 af[2], bg[5];
#pragma unroll
    for (int i = 0; i < 2; ++i)
      af[i] = *reinterpret_cast<const bf16x8*>(Wp + (size_t)i * 16 * K + ks * 32);
#pragma unroll
    for (int j = 0; j < 5; ++j)
      bg[j] = *reinterpret_cast<const bf16x8*>(&As[ks * 2560 + (j * 16 + ml) * 32 + swz]);
#pragma unroll
    for (int i = 0; i < 2; ++i)
#pragma unroll
      for (int j = 0; j < 5; ++j)
        acc1[i][j] = __builtin_amdgcn_mfma_f32_16x16x32_bf16(af[i], bg[j], acc1[i][j], 0, 0, 0);
  }

  // store + per-lane partial dots over this lane's 8 cols
  float s1[5] = {0.f, 0.f, 0.f, 0.f, 0.f};
  float s2[5] = {0.f, 0.f, 0.f, 0.f, 0.f};
#pragma unroll
  for (int i = 0; i < 2; ++i) {
    int colb = w * 32 + i * 16 + quad * 4;
    float4 av = *reinterpret_cast<const float4*>(asrc + colb);
    float4 dv = *reinterpret_cast<const float4*>(adst + colb);
#pragma unroll
    for (int j = 0; j < 5; ++j) {
      int rg = m0 + j * 16 + ml;
      if (rg < M) {
        ushort4 hv;
        hv.x = f2bf(acc1[i][j][0]);
        hv.y = f2bf(acc1[i][j][1]);
        hv.z = f2bf(acc1[i][j][2]);
        hv.w = f2bf(acc1[i][j][3]);
        *reinterpret_cast<ushort4*>(C + (size_t)rg * 256 + colb) = hv;
      }
      s1[j] += acc1[i][j][0] * av.x + acc1[i][j][1] * av.y +
               acc1[i][j][2] * av.z + acc1[i][j][3] * av.w;
      s2[j] += acc1[i][j][0] * dv.x + acc1[i][j][1] * dv.y +
               acc1[i][j][2] * dv.z + acc1[i][j][3] * dv.w;
    }
  }
#pragma unroll
  for (int j = 0; j < 5; ++j) {
    s1[j] += __shfl_xor(s1[j], 16); s1[j] += __shfl_xor(s1[j], 32);
    s2[j] += __shfl_xor(s2[j], 16); s2[j] += __shfl_xor(s2[j], 32);
  }
  __syncthreads();   // all As reads done -> reuse as float scratch
  float* sS = reinterpret_cast<float*>(As);   // [8][80]
  float* sQ = sS + 640;
  if (quad == 0) {
#pragma unroll
    for (int j = 0; j < 5; ++j) {
      int row = j * 16 + ml;
      sS[w * 80 + row] = s1[j];
      sQ[w * 80 + row] = s2[j];
    }
  }
  __syncthreads();
  if (tid < 80) {
    int rg = m0 + tid;
    if (rg < M) {
      float a = 0.f, b = 0.f;
#pragma unroll
      for (int ww = 0; ww < 8; ++ww) { a += sS[ww * 80 + tid]; b += sQ[ww * 80 + tid]; }
      hs[rg] = a; hd[rg] = b;
    }
  }
}

// ---------------- fused attention + o-proj + bias + residual + LayerNorm ----------
// 48-row blocks = 16 nodes, 256 thr / 4 waves. Vectorized phase 1 (lane owns
// 4 consecutive cols across all heads); phase 2 streams Wo from L2.

__global__ __launch_bounds__(256) void k_oproj(
    const unsigned short* __restrict__ qkvb,   // [M x 768] raw q|k|v
    const unsigned short* __restrict__ Wo,     // [256 x 256]
    const float* __restrict__ bo,
    const float* __restrict__ gam, const float* __restrict__ bet,
    unsigned short* __restrict__ seqc,         // residual in / out, [M x 256]
    int M) {
  __shared__ unsigned short As[8 * 48 * 32];   // 24 KB attention-out, [kgrp][row][32]
  __shared__ float sSum[4 * 48];
  __shared__ float sSq[4 * 48];

  const int tid  = threadIdx.x;
  const int lane = tid & 63;
  const int w    = tid >> 6;
  const int ml   = lane & 15;
  const int quad = lane >> 4;
  const int m0   = blockIdx.x * 48;
  const int swz  = (quad ^ ((ml >> 1) & 3)) * 8;

  // ---- phase 1: attention, lane owns 4 consecutive cols across all heads ----
  const int c0 = lane * 4;
  for (int i = 0; i < 4; ++i) {
    int r0 = (w * 4 + i) * 3;                  // local row of token 0
    size_t rowg[3];
#pragma unroll
    for (int t = 0; t < 3; ++t) {
      int rg = m0 + r0 + t;
      rowg[t] = (size_t)(rg < M ? rg : M - 1);
    }
    float q[3][4], k[3][4], v[3][4];
#pragma unroll
    for (int t = 0; t < 3; ++t) {
      size_t base = rowg[t] * 768 + c0;
      ushort4 uq = *reinterpret_cast<const ushort4*>(qkvb + base);
      ushort4 uk = *reinterpret_cast<const ushort4*>(qkvb + base + 256);
      ushort4 uv = *reinterpret_cast<const ushort4*>(qkvb + base + 512);
      q[t][0] = bf2f(uq.x); q[t][1] = bf2f(uq.y); q[t][2] = bf2f(uq.z); q[t][3] = bf2f(uq.w);
      k[t][0] = bf2f(uk.x); k[t][1] = bf2f(uk.y); k[t][2] = bf2f(uk.z); k[t][3] = bf2f(uk.w);
      v[t][0] = bf2f(uv.x); v[t][1] = bf2f(uv.y); v[t][2] = bf2f(uv.z); v[t][3] = bf2f(uv.w);
    }
    float lg[3][3];
#pragma unroll
    for (int a = 0; a < 3; ++a)
#pragma unroll
      for (int b = 0; b < 3; ++b) {
        float p = q[a][0] * k[b][0] + q[a][1] * k[b][1] +
                  q[a][2] * k[b][2] + q[a][3] * k[b][3];
        p += __shfl_xor(p, 1);
        p += __shfl_xor(p, 2);
        p += __shfl_xor(p, 4);
        p += __shfl_xor(p, 8);     // sum over 16-lane head-group
        lg[a][b] = p * 0.125f;
      }
#pragma unroll
    for (int a = 0; a < 3; ++a) {
      float mx = fmaxf(lg[a][0], fmaxf(lg[a][1], lg[a][2]));
      float e0 = __expf(lg[a][0] - mx);
      float e1 = __expf(lg[a][1] - mx);
      float e2 = __expf(lg[a][2] - mx);
      float inv = 1.f / (e0 + e1 + e2);
      int row = r0 + a;
      int g = lane >> 3;               // (4*lane)>>5
      int cch = (lane >> 1) & 3;       // ((4*lane)>>3)&3
      int addr = (g * 48 + row) * 32 + ((cch ^ ((row >> 1) & 3)) << 3) + ((lane & 1) << 2);
      ushort4 hv;
      hv.x = f2bf((e0 * v[0][0] + e1 * v[1][0] + e2 * v[2][0]) * inv);
      hv.y = f2bf((e0 * v[0][1] + e1 * v[1][1] + e2 * v[2][1]) * inv);
      hv.z = f2bf((e0 * v[0][2] + e1 * v[1][2] + e2 * v[2][2]) * inv);
      hv.w = f2bf((e0 * v[0][3] + e1 * v[1][3] + e2 * v[2][3]) * inv);
      *reinterpret_cast<ushort4*>(&As[addr]) = hv;
    }
  }
  __syncthreads();   // As complete

  // ---- phase 2: GEMM [48 x 256] @ Wo^T, Wo rows streamed from L2, no barriers
  f32x4 acc[3][4] = {};
  const unsigned short* Wop = Wo + (size_t)(w * 64 + ml) * 256 + quad * 8;
  __builtin_amdgcn_s_setprio(1);
#pragma unroll 4
  for (int t = 0; t < 8; ++t) {
    bf16x8 af[3], bg[4];
#pragma unroll
    for (int i = 0; i < 3; ++i)
      af[i] = *reinterpret_cast<const bf16x8*>(&As[(t * 48 + i * 16 + ml) * 32 + swz]);
#pragma unroll
    for (int j = 0; j < 4; ++j)
      bg[j] = *reinterpret_cast<const bf16x8*>(Wop + (size_t)j * 16 * 256 + t * 32);
#pragma unroll
    for (int i = 0; i < 3; ++i)
#pragma unroll
      for (int j = 0; j < 4; ++j)
        acc[i][j] = __builtin_amdgcn_mfma_f32_16x16x32_bf16(af[i], bg[j], acc[i][j], 0, 0, 0);
  }
  __builtin_amdgcn_s_setprio(0);

  // ---- bias + residual + per-row partial stats over this wave's 64 cols ----
  float bov[4], gv[4], btv[4];
#pragma unroll
  for (int j = 0; j < 4; ++j) {
    int col = w * 64 + j * 16 + ml;
    bov[j] = bo[col]; gv[j] = gam[col]; btv[j] = bet[col];
  }

#pragma unroll
  for (int i = 0; i < 3; ++i)
#pragma unroll
    for (int r = 0; r < 4; ++r) {
      int row = i * 16 + quad * 4 + r;
      int rg = m0 + row;
      size_t rr2 = (size_t)(rg < M ? rg : M - 1);
      float s = 0.f, s2 = 0.f;
#pragma unroll
      for (int j = 0; j < 4; ++j) {
        int col = w * 64 + j * 16 + ml;
        float t = acc[i][j][r] + bov[j] + bf2f(seqc[rr2 * 256 + col]);
        acc[i][j][r] = t;
        s += t; s2 += t * t;
      }
#pragma unroll
      for (int o = 1; o < 16; o <<= 1) { s += __shfl_xor(s, o); s2 += __shfl_xor(s2, o); }
      if (ml == 0) { sSum[w * 48 + row] = s; sSq[w * 48 + row] = s2; }
    }
  __syncthreads();

#pragma unroll
  for (int i = 0; i < 3; ++i)
#pragma unroll
    for (int r = 0; r < 4; ++r) {
      int row = i * 16 + quad * 4 + r;
      int rg = m0 + row;
      if (rg >= M) continue;
      float s  = sSum[row] + sSum[48 + row] + sSum[96 + row] + sSum[144 + row];
      float s2 = sSq[row]  + sSq[48 + row]  + sSq[96 + row]  + sSq[144 + row];
      float mean = s * (1.f / 256.f);
      float var  = s2 * (1.f / 256.f) - mean * mean;
      float inv  = rsqrtf(var + 1e-5f);
#pragma unroll
      for (int j = 0; j < 4; ++j) {
        int col = w * 64 + j * 16 + ml;
        seqc[(size_t)rg * 256 + col] = f2bf((acc[i][j][r] - mean) * inv * gv[j] + btv[j]);
      }
    }
}

// ---------------- fused FFN: relu(A@W1^T+b1)@W2^T + b2 + residual(A) + LN ----------
// 80-row tile, 8 waves, 80 KB LDS -> exactly 2 co-resident blocks/CU.
// unroll 4 on ks loops: more W-loads in flight to hide L2 latency
// (VGPR headroom 64 -> <=128 at the LDS-capped 4 waves/SIMD).

__global__ __launch_bounds__(512, 4) void k_ff(
    unsigned short* __restrict__ A,
    const unsigned short* __restrict__ W1,
    const float* __restrict__ b1,
    const unsigned short* __restrict__ W2,
    const float* __restrict__ b2,
    const float* __restrict__ gam, const float* __restrict__ bet,
    int M) {
  __shared__ unsigned short As[8 * 80 * 32];   // 40 KB  [kgrp][row][32]
  __shared__ unsigned short Hs[8 * 80 * 32];   // 40 KB  (reused as LN scratch)

  const int tid  = threadIdx.x;
  const int lane = tid & 63;
  const int w    = tid >> 6;        // 0..7
  const int ml   = lane & 15;
  const int quad = lane >> 4;
  const int m0   = blockIdx.x * 80;
  const int swz  = (quad ^ ((ml >> 1) & 3)) << 3;

  // ---- stage A tile 80x256: wave w stages k-group w (5 rounds of 64 lanes) ----
  {
#pragma unroll
    for (int r = 0; r < 5; ++r) {
      int e = r * 64 + lane;
      int row = e >> 2, ch = e & 3;
      int rg = m0 + row; if (rg >= M) rg = M - 1;
      int cs = ch ^ ((row >> 1) & 3);
      load_lds16(A + (size_t)rg * 256 + w * 32 + (cs << 3),
                 As + (size_t)(w * 320 + r * 64) * 8);   // HW adds lane*16B
    }
  }
  __syncthreads();

  f32x4 acc2[5][2] = {};

  for (int kb = 0; kb < 4; ++kb) {
    f32x4 acc1[2][5] = {};
    const unsigned short* W1p = W1 + (size_t)(kb * 256 + w * 32 + ml) * 256 + quad * 8;
    __builtin_amdgcn_s_setprio(1);
#pragma unroll 4
    for (int ks = 0; ks < 8; ++ks) {
      bf16x8 af[2], bg[5];
#pragma unroll
      for (int i = 0; i < 2; ++i)
        af[i] = *reinterpret_cast<const bf16x8*>(W1p + (size_t)i * 16 * 256 + ks * 32);
#pragma unroll
      for (int j = 0; j < 5; ++j)
        bg[j] = *reinterpret_cast<const bf16x8*>(&As[ks * 2560 + (j * 16 + ml) * 32 + swz]);
#pragma unroll
      for (int i = 0; i < 2; ++i)
#pragma unroll
        for (int j = 0; j < 5; ++j)
          acc1[i][j] = __builtin_amdgcn_mfma_f32_16x16x32_bf16(af[i], bg[j], acc1[i][j], 0, 0, 0);
    }
    __builtin_amdgcn_s_setprio(0);

    __syncthreads();   // previous GEMM2 readers of Hs are done

#pragma unroll
    for (int i = 0; i < 2; ++i) {
      float4 bv = *reinterpret_cast<const float4*>(b1 + kb * 256 + w * 32 + i * 16 + quad * 4);
      int c  = i * 2 + (quad >> 1);
      int lo = (quad & 1) * 4;
#pragma unroll
      for (int j = 0; j < 5; ++j) {
        int seqrow = j * 16 + ml;
        int chsw = c ^ ((ml >> 1) & 3);
        int addr = w * 2560 + seqrow * 32 + (chsw << 3) + lo;
        float t0 = acc1[i][j][0] + bv.x; t0 = t0 > 0.f ? t0 : 0.f;
        float t1 = acc1[i][j][1] + bv.y; t1 = t1 > 0.f ? t1 : 0.f;
        float t2 = acc1[i][j][2] + bv.z; t2 = t2 > 0.f ? t2 : 0.f;
        float t3 = acc1[i][j][3] + bv.w; t3 = t3 > 0.f ? t3 : 0.f;
        ushort4 hv;
        hv.x = f2bf(t0); hv.y = f2bf(t1); hv.z = f2bf(t2); hv.w = f2bf(t3);
        *reinterpret_cast<ushort4*>(&Hs[addr]) = hv;
      }
    }
    __syncthreads();   // Hs visible to all waves

    const unsigned short* W2p = W2 + (size_t)(w * 32 + ml) * 1024 + kb * 256 + quad * 8;
    __builtin_amdgcn_s_setprio(1);
#pragma unroll 4
    for (int ks = 0; ks < 8; ++ks) {
      bf16x8 af[5], bg[2];
#pragma unroll
      for (int i = 0; i < 5; ++i)
        af[i] = *reinterpret_cast<const bf16x8*>(&Hs[ks * 2560 + (i * 16 + ml) * 32 + swz]);
#pragma unroll
      for (int j = 0; j < 2; ++j)
        bg[j] = *reinterpret_cast<const bf16x8*>(W2p + (size_t)j * 16 * 1024 + ks * 32);
#pragma unroll
      for (int i = 0; i < 5; ++i)
#pragma unroll
        for (int j = 0; j < 2; ++j)
          acc2[i][j] = __builtin_amdgcn_mfma_f32_16x16x32_bf16(af[i], bg[j], acc2[i][j], 0, 0, 0);
    }
    __builtin_amdgcn_s_setprio(0);
  }

  __syncthreads();   // all Hs reads done -> reuse Hs as LN scratch
  float* sS = reinterpret_cast<float*>(Hs);   // [8][80]
  float* sQ = sS + 640;                        // [8][80]

  float b2v[2], gv[2], btv[2];
#pragma unroll
  for (int j = 0; j < 2; ++j) {
    int col = w * 32 + j * 16 + ml;
    b2v[j] = b2[col]; gv[j] = gam[col]; btv[j] = bet[col];
  }

  // bias + residual (from As LDS) + per-row partial stats over this wave's 32 cols
#pragma unroll
  for (int i = 0; i < 5; ++i)
#pragma unroll
    for (int r = 0; r < 4; ++r) {
      int row = i * 16 + quad * 4 + r;
      float s = 0.f, s2 = 0.f;
#pragma unroll
      for (int j = 0; j < 2; ++j) {
        int c_r = j * 2 + (ml >> 3);
        float t = acc2[i][j][r] + b2v[j] +
                  bf2f(As[w * 2560 + row * 32 + ((c_r ^ ((row >> 1) & 3)) << 3) + (ml & 7)]);
        acc2[i][j][r] = t;
        s += t; s2 += t * t;
      }
#pragma unroll
      for (int o = 1; o < 16; o <<= 1) { s += __shfl_xor(s, o); s2 += __shfl_xor(s2, o); }
      if (ml == 0) { sS[w * 80 + row] = s; sQ[w * 80 + row] = s2; }
    }
  __syncthreads();

#pragma unroll
  for (int i = 0; i < 5; ++i)
#pragma unroll
    for (int r = 0; r < 4; ++r) {
      int row = i * 16 + quad * 4 + r;
      int rg = m0 + row;
      if (rg >= M) continue;
      float s = 0.f, s2 = 0.f;
#pragma unroll
      for (int ww = 0; ww < 8; ++ww) { s += sS[ww * 80 + row]; s2 += sQ[ww * 80 + row]; }
      float mean = s * (1.f / 256.f);
      float var  = s2 * (1.f / 256.f) - mean * mean;
      float inv  = rsqrtf(var + 1e-5f);
#pragma unroll
      for (int j = 0; j < 2; ++j) {
        int col = w * 32 + j * 16 + ml;
        A[(size_t)rg * 256 + col] = f2bf((acc2[i][j][r] - mean) * inv * gv[j] + btv[j]);
      }
    }
}

// ---------------- transformer pieces (bf16 activations, dense layouts) ----------------

__global__ void k_seqbuild(const unsigned short* __restrict__ x1,
                           const unsigned short* __restrict__ x2,
                           const float* __restrict__ cls, const float* __restrict__ pos,
                           unsigned short* __restrict__ seqc, int n0, int cn) {
  int idx = blockIdx.x * blockDim.x + threadIdx.x;
  int total = cn * 3 * DD;
  if (idx >= total) return;
  int c = idx & (DD - 1);
  int r = idx >> 8;
  int t = r % 3, ln = r / 3;
  int n = n0 + ln;
  float v;
  if (t == 0)      v = cls[c];
  else if (t == 1) v = bf2f(x1[(size_t)n * DD + c]);
  else             v = bf2f(x2[(size_t)n * DD + c]);
  seqc[idx] = f2bf(v + pos[t * DD + c]);
}

__global__ __launch_bounds__(256) void k_final(const unsigned short* __restrict__ seqc,
                                               int n0, int cn,
                                               const float* __restrict__ g,
                                               const float* __restrict__ b,
                                               float* __restrict__ out) {
  int ln = blockIdx.x * 4 + (threadIdx.x >> 6);
  if (ln >= cn) return;
  int lane = threadIdx.x & 63;
  const unsigned short* p = seqc + (size_t)ln * 3 * DD;   // token 0 row
  float v[4];
  float s = 0.f, s2 = 0.f;
#pragma unroll
  for (int i = 0; i < 4; ++i) {
    v[i] = bf2f(p[i * 64 + lane]);
    s += v[i]; s2 += v[i] * v[i];
  }
  for (int off = 32; off; off >>= 1) { s += __shfl_xor(s, off); s2 += __shfl_xor(s2, off); }
  float mean = s * (1.f / 256.f);
  float var  = s2 * (1.f / 256.f) - mean * mean;
  float inv  = rsqrtf(var + 1e-5f);
#pragma unroll
  for (int i = 0; i < 4; ++i) {
    int c = i * 64 + lane;
    out[(size_t)(n0 + ln) * DD + c] = (v[i] - mean) * inv * g[c] + b[c];
  }
}

// ---------------- host ----------------

extern "C" void kernel_launch(void* const* d_in, const int* in_sizes, int n_in,
                              void* d_out, int out_size, void* d_ws, size_t ws_size,
                              hipStream_t stream) {
  const float* x       = (const float*)d_in[0];
  const int*   ei      = (const int*)d_in[1];
  const float* gat1_W  = (const float*)d_in[2];
  const float* gat1_b  = (const float*)d_in[3];
  const float* gat1_as = (const float*)d_in[4];
  const float* gat1_ad = (const float*)d_in[5];
  const float* gat2_W  = (const float*)d_in[6];
  const float* gat2_b  = (const float*)d_in[7];
  const float* gat2_as = (const float*)d_in[8];
  const float* gat2_ad = (const float*)d_in[9];
  const float* cls     = (const float*)d_in[10];
  const float* pos     = (const float*)d_in[11];
  const float* Wqkv    = (const float*)d_in[12];
  const float* bqkv    = (const float*)d_in[13];
  const float* Wo      = (const float*)d_in[14];
  const float* bo      = (const float*)d_in[15];
  const float* ln1_g   = (const float*)d_in[16];
  const float* ln1_b   = (const float*)d_in[17];
  const float* ln2_g   = (const float*)d_in[18];
  const float* ln2_b   = (const float*)d_in[19];
  const float* Wff1    = (const float*)d_in[20];
  const float* bff1    = (const float*)d_in[21];
  const float* Wff2    = (const float*)d_in[22];
  const float* bff2    = (const float*)d_in[23];
  const float* norm_g  = (const float*)d_in[24];
  const float* norm_b  = (const float*)d_in[25];
  float* out = (float*)d_out;

  char* ws = (char*)d_ws;
  size_t off = 0;
  auto alloc = [&](size_t bytes) -> void* {
    off = (off + 255) & ~(size_t)255;
    void* p = ws + off;
    off += bytes;
    return p;
  };

  unsigned short* wb_g1  = (unsigned short*)alloc(sizeof(unsigned short) * 256 * 128);
  unsigned short* wb_g2  = (unsigned short*)alloc(sizeof(unsigned short) * 256 * 256);
  unsigned short* wb_qkv = (unsigned short*)alloc(sizeof(unsigned short) * 2 * 768 * 256);
  unsigned short* wb_o   = (unsigned short*)alloc(sizeof(unsigned short) * 2 * 256 * 256);
  unsigned short* wb_f1  = (unsigned short*)alloc(sizeof(unsigned short) * 2 * 1024 * 256);
  unsigned short* wb_f2  = (unsigned short*)alloc(sizeof(unsigned short) * 2 * 256 * 1024);
  unsigned short* xb  = (unsigned short*)alloc(sizeof(unsigned short) * (size_t)NN * DIN);
  unsigned short* hb  = (unsigned short*)alloc(sizeof(unsigned short) * (size_t)NN * DD);
  unsigned short* x1b = (unsigned short*)alloc(sizeof(unsigned short) * (size_t)NN * DD);
  unsigned short* x2b = (unsigned short*)alloc(sizeof(unsigned short) * (size_t)NN * DD);
  float* hs  = (float*)alloc(sizeof(float) * NN);
  float* hd  = (float*)alloc(sizeof(float) * NN);
  int* deg   = (int*)alloc(sizeof(int) * NN);
  int* inc   = (int*)alloc(sizeof(int) * NN);
  int* cur   = (int*)alloc(sizeof(int) * NN);
  int* tsum  = (int*)alloc(sizeof(int) * 64);
  int* ssrc  = (int*)alloc(sizeof(int) * E2);

  // transformer chunking (L3 residency of per-chunk activations)
  size_t fixed = (off + 255) & ~(size_t)255;
  size_t rem = (ws_size > fixed + 4096) ? (ws_size - fixed - 4096) : 0;
  const size_t per_node = (size_t)3 * (256 + 768) * 2;
  size_t cn_max = rem / per_node;
  if (cn_max < 1) cn_max = 1;
  if (cn_max > 12500) cn_max = 12500;
  int nc = (int)((NN + cn_max - 1) / cn_max);
  int cn = (NN + nc - 1) / nc;
  unsigned short* seqc = (unsigned short*)alloc(sizeof(unsigned short) * (size_t)3 * cn * 256);
  unsigned short* qkvb = (unsigned short*)alloc(sizeof(unsigned short) * (size_t)3 * cn * 768);

  // ---- casts ----
  auto cast = [&](const float* src, unsigned short* dst, int n) {
    k_cast<<<(n + 255) / 256, 256, 0, stream>>>(src, dst, n);
  };
  cast(gat1_W, wb_g1, 256 * 128);
  cast(gat2_W, wb_g2, 256 * 256);
  cast(Wqkv, wb_qkv, 2 * 768 * 256);
  cast(Wo, wb_o, 2 * 256 * 256);
  cast(Wff1, wb_f1, 2 * 1024 * 256);
  cast(Wff2, wb_f2, 2 * 256 * 1024);
  cast(x, xb, NN * DIN);

  // ---- CSR build ----
  hipMemsetAsync(deg, 0, sizeof(int) * NN, stream);
  hipMemsetAsync(cur, 0, sizeof(int) * NN, stream);
  k_deg<<<(E2 + 255) / 256, 256, 0, stream>>>(ei, deg);
  int nb = (NN + 1023) / 1024;
  k_scan_tile<<<nb, 1024, 0, stream>>>(deg, inc, tsum, NN);
  k_scan_sums<<<1, 64, 0, stream>>>(tsum, nb);
  k_scan_add<<<(NN + 255) / 256, 256, 0, stream>>>(inc, tsum, NN);
  k_scatter<<<(E2 + 255) / 256, 256, 0, stream>>>(ei, deg, inc, cur, ssrc);

  // ---- GAT layer 1: hb = xb @ W1^T (K=128) + fused dots ----
  k_gemmD<<<(NN + 79) / 80, 512, 0, stream>>>(xb, wb_g1, hb, gat1_as, gat1_ad,
                                              hs, hd, NN, 128);
  k_gat<<<(NN + 3) / 4, 256, 0, stream>>>(hb, ssrc, deg, inc, hs, hd, gat1_b, x1b);

  // ---- GAT layer 2: hb = x1b @ W2^T (K=256) + fused dots ----
  k_gemmD<<<(NN + 79) / 80, 512, 0, stream>>>(x1b, wb_g2, hb, gat2_as, gat2_ad,
                                              hs, hd, NN, 256);
  k_gat<<<(NN + 3) / 4, 256, 0, stream>>>(hb, ssrc, deg, inc, hs, hd, gat2_b, x2b);

  // ---- transformer (chunked) ----
  for (int n0 = 0; n0 < NN; n0 += cn) {
    int c = NN - n0 < cn ? NN - n0 : cn;
    int Mch = 3 * c;
    int mblk48 = (Mch + 47) / 48;
    int mblk80 = (Mch + 79) / 80;
    k_seqbuild<<<(c * 3 * DD + 255) / 256, 256, 0, stream>>>(x1b, x2b, cls, pos, seqc, n0, c);
    for (int l = 0; l < 2; ++l) {
      // qkv: N=768, K=256 via k_ff-structure GEMM (raw q|k|v + bias)
      k_gemmT<<<mblk80, 512, 0, stream>>>(
          seqc, wb_qkv + (size_t)l * 768 * 256, bqkv + l * 768, qkvb, Mch, 768, 256);
      // fused attention + o-proj + residual + ln1 (Wo streamed, vectorized attn)
      k_oproj<<<mblk48, 256, 0, stream>>>(
          qkvb, wb_o + (size_t)l * 256 * 256, bo + l * 256,
          ln1_g + l * 256, ln1_b + l * 256, seqc, Mch);
      // fused ff1+relu+ff2+residual+ln2 (no global intermediate), 80-row tiles
      k_ff<<<mblk80, 512, 0, stream>>>(
          seqc, wb_f1 + (size_t)l * 1024 * 256, bff1 + l * 1024,
          wb_f2 + (size_t)l * 256 * 1024, bff2 + l * 256,
          ln2_g + l * 256, ln2_b + l * 256, Mch);
    }
    k_final<<<(c + 3) / 4, 256, 0, stream>>>(seqc, n0, c, norm_g, norm_b, out);
  }
}

// Round 14
// 1613.777 us; speedup vs baseline: 1.4259x; 1.0713x over previous
//
#include <hip/hip_runtime.h>
#include <hip/hip_bf16.h>

#define NN  50000
#define EE  320000
#define E2  (EE + NN)
#define DIN 128
#define DD  256

typedef __attribute__((ext_vector_type(8))) short          bf16x8;
typedef __attribute__((ext_vector_type(8))) unsigned short u16x8;
typedef __attribute__((ext_vector_type(4))) float          f32x4;

// ---------------- helpers ----------------

static __device__ __forceinline__ float bf2f(unsigned short u) {
  return __builtin_bit_cast(float, (unsigned)u << 16);
}

static __device__ __forceinline__ unsigned short f2bf(float f) {
  unsigned u = __builtin_bit_cast(unsigned, f);
  return (unsigned short)((u + 0x7fffu + ((u >> 16) & 1u)) >> 16);
}

static __device__ __forceinline__ void load_lds16(const void* g, void* l) {
  __builtin_amdgcn_global_load_lds(
      (const __attribute__((address_space(1))) void*)g,
      (__attribute__((address_space(3))) void*)l, 16, 0, 0);
}

// ---------------- weight/activation cast fp32 -> bf16 ----------------

__global__ void k_cast(const float* __restrict__ in, unsigned short* __restrict__ out, int n) {
  int i = blockIdx.x * blockDim.x + threadIdx.x;
  if (i >= n) return;
  out[i] = f2bf(in[i]);
}

// ---------------- CSR build ----------------

__global__ void k_deg(const int* __restrict__ ei, int* __restrict__ deg) {
  int i = blockIdx.x * blockDim.x + threadIdx.x;
  if (i >= E2) return;
  int dst = (i < EE) ? ei[EE + i] : (i - EE);
  atomicAdd(&deg[dst], 1);
}

__global__ __launch_bounds__(1024) void k_scan_tile(const int* __restrict__ in,
                                                    int* __restrict__ out,
                                                    int* __restrict__ tsum, int n) {
  __shared__ int sm[1024];
  int tid = threadIdx.x;
  int g = blockIdx.x * 1024 + tid;
  sm[tid] = (g < n) ? in[g] : 0;
  __syncthreads();
  for (int off = 1; off < 1024; off <<= 1) {
    int t = (tid >= off) ? sm[tid - off] : 0;
    __syncthreads();
    sm[tid] += t;
    __syncthreads();
  }
  if (g < n) out[g] = sm[tid];
  if (tid == 1023) tsum[blockIdx.x] = sm[1023];
}

__global__ void k_scan_sums(int* __restrict__ tsum, int nb) {
  int tid = threadIdx.x;           // single wave of 64, nb <= 64
  int v = (tid < nb) ? tsum[tid] : 0;
  for (int off = 1; off < 64; off <<= 1) {
    int t = __shfl_up(v, off);
    if (tid >= off) v += t;
  }
  if (tid < nb) tsum[tid] = v;
}

__global__ void k_scan_add(int* __restrict__ out, const int* __restrict__ tsum, int n) {
  int g = blockIdx.x * blockDim.x + threadIdx.x;
  if (g >= n || g < 1024) return;
  out[g] += tsum[(g >> 10) - 1];
}

__global__ void k_scatter(const int* __restrict__ ei, const int* __restrict__ deg,
                          const int* __restrict__ inc, int* __restrict__ cur,
                          int* __restrict__ ssrc) {
  int i = blockIdx.x * blockDim.x + threadIdx.x;
  if (i >= E2) return;
  int src, dst;
  if (i < EE) { src = ei[i]; dst = ei[EE + i]; } else { src = dst = i - EE; }
  int pos = atomicAdd(&cur[dst], 1);
  ssrc[inc[dst] - deg[dst] + pos] = src;
}

// ---------------- GAT pieces (h in bf16) ----------------

// Fused edge-softmax + aggregation: one wave per dst node.
__global__ __launch_bounds__(256) void k_gat(const unsigned short* __restrict__ hb,
                                             const int* __restrict__ ssrc,
                                             const int* __restrict__ deg,
                                             const int* __restrict__ inc,
                                             const float* __restrict__ hs,
                                             const float* __restrict__ hd,
                                             const float* __restrict__ bias,
                                             unsigned short* __restrict__ out) {
  __shared__ float sE[4][256];
  __shared__ int   sI[4][256];
  int w = threadIdx.x >> 6;
  int d = blockIdx.x * 4 + w;
  if (d >= NN) return;
  int lane = threadIdx.x & 63;
  int end = inc[d], cnt = deg[d], base = end - cnt;
  if (cnt > 256) cnt = 256;
  float hdd = hd[d];

  float m = -1e30f;
  for (int i0 = 0; i0 < cnt; i0 += 64) {
    int i = i0 + lane;
    float sc = -1e30f;
    if (i < cnt) {
      int s = ssrc[base + i];
      float v = hs[s] + hdd;
      sc = (v < 0.f) ? 0.2f * v : v;
      sI[w][i] = s;
      sE[w][i] = sc;
    }
    float mm = sc;
    for (int o = 32; o; o >>= 1) mm = fmaxf(mm, __shfl_xor(mm, o));
    m = fmaxf(m, mm);
  }
  float sum = 0.f;
  for (int i0 = 0; i0 < cnt; i0 += 64) {
    int i = i0 + lane;
    float e = 0.f;
    if (i < cnt) {
      e = __expf(sE[w][i] - m);
      sE[w][i] = e;
    }
    for (int o = 32; o; o >>= 1) e += __shfl_xor(e, o);
    sum += e;
  }
  float inv = 1.f / sum;

  float a0 = 0.f, a1 = 0.f, a2 = 0.f, a3 = 0.f;
  for (int i = 0; i < cnt; ++i) {
    float a = sE[w][i];
    int s = sI[w][i];
    ushort4 hv = *reinterpret_cast<const ushort4*>(hb + (size_t)s * DD + lane * 4);
    a0 += a * bf2f(hv.x);
    a1 += a * bf2f(hv.y);
    a2 += a * bf2f(hv.z);
    a3 += a * bf2f(hv.w);
  }
  const float* bp = bias + lane * 4;
  float r0 = a0 * inv + bp[0], r1 = a1 * inv + bp[1];
  float r2 = a2 * inv + bp[2], r3 = a3 * inv + bp[3];
  ushort4 o;
  o.x = f2bf(r0 > 0.f ? r0 : 0.f);
  o.y = f2bf(r1 > 0.f ? r1 : 0.f);
  o.z = f2bf(r2 > 0.f ? r2 : 0.f);
  o.w = f2bf(r3 > 0.f ? r3 : 0.f);
  *reinterpret_cast<ushort4*>(out + (size_t)d * DD + lane * 4) = o;
}

// LDS k-chunk swizzle (bank-conflict-free fragment reads):
// LDS slot (row, c) holds global k-chunk  c ^ ((row>>1)&3)  within each 32-k group.
// Fragment read of logical chunk q at row (16-aligned base + m_lane):
//   position = q ^ ((m_lane>>1)&3).  Direct-global reads use logical chunk = quad.
// Row stride MUST be 64 B ([*][32 shorts]) for conflict-free b128 reads.

// ---------------- k_ff-structure GEMM: C = A @ W^T + bias ------
// A [M x K] bf16, W [N x K] bf16 (L2-resident), C [M x N] bf16. K in {128, 256}.
// 80-row tile, 8 waves. Wave w stages k-group w, then streams W rows from L2;
// swapped mfma(W, A); no barriers after stage.

__global__ __launch_bounds__(512, 4) void k_gemmT(
    const unsigned short* __restrict__ A,
    const unsigned short* __restrict__ W,
    const float* __restrict__ bias,            // [N] or null
    unsigned short* __restrict__ C,
    int M, int N, int K) {
  __shared__ unsigned short As[8 * 80 * 32];   // up to 40 KB  [kgrp][row][32]

  const int tid  = threadIdx.x;
  const int lane = tid & 63;
  const int w    = tid >> 6;        // 0..7
  const int ml   = lane & 15;
  const int quad = lane >> 4;
  const int m0   = blockIdx.x * 80;
  const int swz  = (quad ^ ((ml >> 1) & 3)) << 3;
  const int KG   = K >> 5;          // kgroups (4 or 8)

  // ---- stage A tile 80xK: wave w stages k-group w (5 rounds of 64 lanes) ----
  if (w < KG) {
#pragma unroll
    for (int r = 0; r < 5; ++r) {
      int e = r * 64 + lane;          // 0..319 within kgroup
      int row = e >> 2, ch = e & 3;
      int rg = m0 + row; if (rg >= M) rg = M - 1;
      int cs = ch ^ ((row >> 1) & 3);
      load_lds16(A + (size_t)rg * K + w * 32 + (cs << 3),
                 As + (size_t)(w * 320 + r * 64) * 8);   // HW adds lane*16B
    }
  }
  __syncthreads();

  const int nkb = N >> 8;
  for (int kb = 0; kb < nkb; ++kb) {
    f32x4 acc1[2][5] = {};
    const unsigned short* Wp = W + (size_t)(kb * 256 + w * 32 + ml) * K + quad * 8;
    __builtin_amdgcn_s_setprio(1);
#pragma unroll 2
    for (int ks = 0; ks < KG; ++ks) {
      bf16x8 af[2], bg[5];
#pragma unroll
      for (int i = 0; i < 2; ++i)
        af[i] = *reinterpret_cast<const bf16x8*>(Wp + (size_t)i * 16 * K + ks * 32);
#pragma unroll
      for (int j = 0; j < 5; ++j)
        bg[j] = *reinterpret_cast<const bf16x8*>(&As[ks * 2560 + (j * 16 + ml) * 32 + swz]);
#pragma unroll
      for (int i = 0; i < 2; ++i)
#pragma unroll
        for (int j = 0; j < 5; ++j)
          acc1[i][j] = __builtin_amdgcn_mfma_f32_16x16x32_bf16(af[i], bg[j], acc1[i][j], 0, 0, 0);
    }
    __builtin_amdgcn_s_setprio(0);

    // bias + global store (4 consecutive cols per lane = 8 B)
#pragma unroll
    for (int i = 0; i < 2; ++i) {
      int colb = kb * 256 + w * 32 + i * 16 + quad * 4;
      float4 bv = make_float4(0.f, 0.f, 0.f, 0.f);
      if (bias) bv = *reinterpret_cast<const float4*>(bias + colb);
#pragma unroll
      for (int j = 0; j < 5; ++j) {
        int rg = m0 + j * 16 + ml;
        if (rg < M) {
          ushort4 hv;
          hv.x = f2bf(acc1[i][j][0] + bv.x);
          hv.y = f2bf(acc1[i][j][1] + bv.y);
          hv.z = f2bf(acc1[i][j][2] + bv.z);
          hv.w = f2bf(acc1[i][j][3] + bv.w);
          *reinterpret_cast<ushort4*>(C + (size_t)rg * N + colb) = hv;
        }
      }
    }
  }
}

// ---------------- GAT projection GEMM + fused attention-dot epilogue ----------
// Same structure as k_gemmT with N=256 fixed; additionally computes
// hs[row] = h . asrc, hd[row] = h . adst (k_dots fused).

__global__ __launch_bounds__(512, 4) void k_gemmD(
    const unsigned short* __restrict__ A,
    const unsigned short* __restrict__ W,
    unsigned short* __restrict__ C,            // hb [M x 256]
    const float* __restrict__ asrc, const float* __restrict__ adst,
    float* __restrict__ hs, float* __restrict__ hd,
    int M, int K) {
  __shared__ unsigned short As[8 * 80 * 32];   // up to 40 KB

  const int tid  = threadIdx.x;
  const int lane = tid & 63;
  const int w    = tid >> 6;
  const int ml   = lane & 15;
  const int quad = lane >> 4;
  const int m0   = blockIdx.x * 80;
  const int swz  = (quad ^ ((ml >> 1) & 3)) << 3;
  const int KG   = K >> 5;

  if (w < KG) {
#pragma unroll
    for (int r = 0; r < 5; ++r) {
      int e = r * 64 + lane;
      int row = e >> 2, ch = e & 3;
      int rg = m0 + row; if (rg >= M) rg = M - 1;
      int cs = ch ^ ((row >> 1) & 3);
      load_lds16(A + (size_t)rg * K + w * 32 + (cs << 3),
                 As + (size_t)(w * 320 + r * 64) * 8);
    }
  }
  __syncthreads();

  f32x4 acc1[2][5] = {};
  const unsigned short* Wp = W + (size_t)(w * 32 + ml) * K + quad * 8;
#pragma unroll 2
  for (int ks = 0; ks < KG; ++ks) {
    bf16x8 af[2], bg[5];
#pragma unroll
    for (int i = 0; i < 2; ++i)
      af[i] = *reinterpret_cast<const bf16x8*>(Wp + (size_t)i * 16 * K + ks * 32);
#pragma unroll
    for (int j = 0; j < 5; ++j)
      bg[j] = *reinterpret_cast<const bf16x8*>(&As[ks * 2560 + (j * 16 + ml) * 32 + swz]);
#pragma unroll
    for (int i = 0; i < 2; ++i)
#pragma unroll
      for (int j = 0; j < 5; ++j)
        acc1[i][j] = __builtin_amdgcn_mfma_f32_16x16x32_bf16(af[i], bg[j], acc1[i][j], 0, 0, 0);
  }

  // store + per-lane partial dots over this lane's 8 cols
  float s1[5] = {0.f, 0.f, 0.f, 0.f, 0.f};
  float s2[5] = {0.f, 0.f, 0.f, 0.f, 0.f};
#pragma unroll
  for (int i = 0; i < 2; ++i) {
    int colb = w * 32 + i * 16 + quad * 4;
    float4 av = *reinterpret_cast<const float4*>(asrc + colb);
    float4 dv = *reinterpret_cast<const float4*>(adst + colb);
#pragma unroll
    for (int j = 0; j < 5; ++j) {
      int rg = m0 + j * 16 + ml;
      if (rg < M) {
        ushort4 hv;
        hv.x = f2bf(acc1[i][j][0]);
        hv.y = f2bf(acc1[i][j][1]);
        hv.z = f2bf(acc1[i][j][2]);
        hv.w = f2bf(acc1[i][j][3]);
        *reinterpret_cast<ushort4*>(C + (size_t)rg * 256 + colb) = hv;
      }
      s1[j] += acc1[i][j][0] * av.x + acc1[i][j][1] * av.y +
               acc1[i][j][2] * av.z + acc1[i][j][3] * av.w;
      s2[j] += acc1[i][j][0] * dv.x + acc1[i][j][1] * dv.y +
               acc1[i][j][2] * dv.z + acc1[i][j][3] * dv.w;
    }
  }
#pragma unroll
  for (int j = 0; j < 5; ++j) {
    s1[j] += __shfl_xor(s1[j], 16); s1[j] += __shfl_xor(s1[j], 32);
    s2[j] += __shfl_xor(s2[j], 16); s2[j] += __shfl_xor(s2[j], 32);
  }
  __syncthreads();   // all As reads done -> reuse as float scratch
  float* sS = reinterpret_cast<float*>(As);   // [8][80]
  float* sQ = sS + 640;
  if (quad == 0) {
#pragma unroll
    for (int j = 0; j < 5; ++j) {
      int row = j * 16 + ml;
      sS[w * 80 + row] = s1[j];
      sQ[w * 80 + row] = s2[j];
    }
  }
  __syncthreads();
  if (tid < 80) {
    int rg = m0 + tid;
    if (rg < M) {
      float a = 0.f, b = 0.f;
#pragma unroll
      for (int ww = 0; ww < 8; ++ww) { a += sS[ww * 80 + tid]; b += sQ[ww * 80 + tid]; }
      hs[rg] = a; hd[rg] = b;
    }
  }
}

// ---------------- fused attention + o-proj + bias + residual + LayerNorm ----------
// 48-row blocks = 16 nodes, 256 thr / 4 waves. Vectorized phase 1 (lane owns
// 4 consecutive cols across all heads); phase 2 streams Wo from L2.

__global__ __launch_bounds__(256) void k_oproj(
    const unsigned short* __restrict__ qkvb,   // [M x 768] raw q|k|v
    const unsigned short* __restrict__ Wo,     // [256 x 256]
    const float* __restrict__ bo,
    const float* __restrict__ gam, const float* __restrict__ bet,
    unsigned short* __restrict__ seqc,         // residual in / out, [M x 256]
    int M) {
  __shared__ unsigned short As[8 * 48 * 32];   // 24 KB attention-out, [kgrp][row][32]
  __shared__ float sSum[4 * 48];
  __shared__ float sSq[4 * 48];

  const int tid  = threadIdx.x;
  const int lane = tid & 63;
  const int w    = tid >> 6;
  const int ml   = lane & 15;
  const int quad = lane >> 4;
  const int m0   = blockIdx.x * 48;
  const int swz  = (quad ^ ((ml >> 1) & 3)) * 8;

  // ---- phase 1: attention, lane owns 4 consecutive cols across all heads ----
  const int c0 = lane * 4;
  for (int i = 0; i < 4; ++i) {
    int r0 = (w * 4 + i) * 3;                  // local row of token 0
    size_t rowg[3];
#pragma unroll
    for (int t = 0; t < 3; ++t) {
      int rg = m0 + r0 + t;
      rowg[t] = (size_t)(rg < M ? rg : M - 1);
    }
    float q[3][4], k[3][4], v[3][4];
#pragma unroll
    for (int t = 0; t < 3; ++t) {
      size_t base = rowg[t] * 768 + c0;
      ushort4 uq = *reinterpret_cast<const ushort4*>(qkvb + base);
      ushort4 uk = *reinterpret_cast<const ushort4*>(qkvb + base + 256);
      ushort4 uv = *reinterpret_cast<const ushort4*>(qkvb + base + 512);
      q[t][0] = bf2f(uq.x); q[t][1] = bf2f(uq.y); q[t][2] = bf2f(uq.z); q[t][3] = bf2f(uq.w);
      k[t][0] = bf2f(uk.x); k[t][1] = bf2f(uk.y); k[t][2] = bf2f(uk.z); k[t][3] = bf2f(uk.w);
      v[t][0] = bf2f(uv.x); v[t][1] = bf2f(uv.y); v[t][2] = bf2f(uv.z); v[t][3] = bf2f(uv.w);
    }
    float lg[3][3];
#pragma unroll
    for (int a = 0; a < 3; ++a)
#pragma unroll
      for (int b = 0; b < 3; ++b) {
        float p = q[a][0] * k[b][0] + q[a][1] * k[b][1] +
                  q[a][2] * k[b][2] + q[a][3] * k[b][3];
        p += __shfl_xor(p, 1);
        p += __shfl_xor(p, 2);
        p += __shfl_xor(p, 4);
        p += __shfl_xor(p, 8);     // sum over 16-lane head-group
        lg[a][b] = p * 0.125f;
      }
#pragma unroll
    for (int a = 0; a < 3; ++a) {
      float mx = fmaxf(lg[a][0], fmaxf(lg[a][1], lg[a][2]));
      float e0 = __expf(lg[a][0] - mx);
      float e1 = __expf(lg[a][1] - mx);
      float e2 = __expf(lg[a][2] - mx);
      float inv = 1.f / (e0 + e1 + e2);
      int row = r0 + a;
      int g = lane >> 3;               // (4*lane)>>5
      int cch = (lane >> 1) & 3;       // ((4*lane)>>3)&3
      int addr = (g * 48 + row) * 32 + ((cch ^ ((row >> 1) & 3)) << 3) + ((lane & 1) << 2);
      ushort4 hv;
      hv.x = f2bf((e0 * v[0][0] + e1 * v[1][0] + e2 * v[2][0]) * inv);
      hv.y = f2bf((e0 * v[0][1] + e1 * v[1][1] + e2 * v[2][1]) * inv);
      hv.z = f2bf((e0 * v[0][2] + e1 * v[1][2] + e2 * v[2][2]) * inv);
      hv.w = f2bf((e0 * v[0][3] + e1 * v[1][3] + e2 * v[2][3]) * inv);
      *reinterpret_cast<ushort4*>(&As[addr]) = hv;
    }
  }
  __syncthreads();   // As complete

  // ---- phase 2: GEMM [48 x 256] @ Wo^T, Wo rows streamed from L2, no barriers
  f32x4 acc[3][4] = {};
  const unsigned short* Wop = Wo + (size_t)(w * 64 + ml) * 256 + quad * 8;
  __builtin_amdgcn_s_setprio(1);
#pragma unroll 4
  for (int t = 0; t < 8; ++t) {
    bf16x8 af[3], bg[4];
#pragma unroll
    for (int i = 0; i < 3; ++i)
      af[i] = *reinterpret_cast<const bf16x8*>(&As[(t * 48 + i * 16 + ml) * 32 + swz]);
#pragma unroll
    for (int j = 0; j < 4; ++j)
      bg[j] = *reinterpret_cast<const bf16x8*>(Wop + (size_t)j * 16 * 256 + t * 32);
#pragma unroll
    for (int i = 0; i < 3; ++i)
#pragma unroll
      for (int j = 0; j < 4; ++j)
        acc[i][j] = __builtin_amdgcn_mfma_f32_16x16x32_bf16(af[i], bg[j], acc[i][j], 0, 0, 0);
  }
  __builtin_amdgcn_s_setprio(0);

  // ---- bias + residual + per-row partial stats over this wave's 64 cols ----
  float bov[4], gv[4], btv[4];
#pragma unroll
  for (int j = 0; j < 4; ++j) {
    int col = w * 64 + j * 16 + ml;
    bov[j] = bo[col]; gv[j] = gam[col]; btv[j] = bet[col];
  }

#pragma unroll
  for (int i = 0; i < 3; ++i)
#pragma unroll
    for (int r = 0; r < 4; ++r) {
      int row = i * 16 + quad * 4 + r;
      int rg = m0 + row;
      size_t rr2 = (size_t)(rg < M ? rg : M - 1);
      float s = 0.f, s2 = 0.f;
#pragma unroll
      for (int j = 0; j < 4; ++j) {
        int col = w * 64 + j * 16 + ml;
        float t = acc[i][j][r] + bov[j] + bf2f(seqc[rr2 * 256 + col]);
        acc[i][j][r] = t;
        s += t; s2 += t * t;
      }
#pragma unroll
      for (int o = 1; o < 16; o <<= 1) { s += __shfl_xor(s, o); s2 += __shfl_xor(s2, o); }
      if (ml == 0) { sSum[w * 48 + row] = s; sSq[w * 48 + row] = s2; }
    }
  __syncthreads();

#pragma unroll
  for (int i = 0; i < 3; ++i)
#pragma unroll
    for (int r = 0; r < 4; ++r) {
      int row = i * 16 + quad * 4 + r;
      int rg = m0 + row;
      if (rg >= M) continue;
      float s  = sSum[row] + sSum[48 + row] + sSum[96 + row] + sSum[144 + row];
      float s2 = sSq[row]  + sSq[48 + row]  + sSq[96 + row]  + sSq[144 + row];
      float mean = s * (1.f / 256.f);
      float var  = s2 * (1.f / 256.f) - mean * mean;
      float inv  = rsqrtf(var + 1e-5f);
#pragma unroll
      for (int j = 0; j < 4; ++j) {
        int col = w * 64 + j * 16 + ml;
        seqc[(size_t)rg * 256 + col] = f2bf((acc[i][j][r] - mean) * inv * gv[j] + btv[j]);
      }
    }
}

// ---------------- fused FFN: relu(A@W1^T+b1)@W2^T + b2 + residual(A) + LN ----------
// 80-row tile, 8 waves, 80 KB LDS -> exactly 2 co-resident blocks/CU.
// unroll 2 (unroll 4 measured SLOWER: 89.4 -> 93.8 us, VGPR unchanged at 64 --
// barrier-phase-bound; this is the structure's floor).

__global__ __launch_bounds__(512, 4) void k_ff(
    unsigned short* __restrict__ A,
    const unsigned short* __restrict__ W1,
    const float* __restrict__ b1,
    const unsigned short* __restrict__ W2,
    const float* __restrict__ b2,
    const float* __restrict__ gam, const float* __restrict__ bet,
    int M) {
  __shared__ unsigned short As[8 * 80 * 32];   // 40 KB  [kgrp][row][32]
  __shared__ unsigned short Hs[8 * 80 * 32];   // 40 KB  (reused as LN scratch)

  const int tid  = threadIdx.x;
  const int lane = tid & 63;
  const int w    = tid >> 6;        // 0..7
  const int ml   = lane & 15;
  const int quad = lane >> 4;
  const int m0   = blockIdx.x * 80;
  const int swz  = (quad ^ ((ml >> 1) & 3)) << 3;

  // ---- stage A tile 80x256: wave w stages k-group w (5 rounds of 64 lanes) ----
  {
#pragma unroll
    for (int r = 0; r < 5; ++r) {
      int e = r * 64 + lane;
      int row = e >> 2, ch = e & 3;
      int rg = m0 + row; if (rg >= M) rg = M - 1;
      int cs = ch ^ ((row >> 1) & 3);
      load_lds16(A + (size_t)rg * 256 + w * 32 + (cs << 3),
                 As + (size_t)(w * 320 + r * 64) * 8);   // HW adds lane*16B
    }
  }
  __syncthreads();

  f32x4 acc2[5][2] = {};

  for (int kb = 0; kb < 4; ++kb) {
    f32x4 acc1[2][5] = {};
    const unsigned short* W1p = W1 + (size_t)(kb * 256 + w * 32 + ml) * 256 + quad * 8;
    __builtin_amdgcn_s_setprio(1);
#pragma unroll 2
    for (int ks = 0; ks < 8; ++ks) {
      bf16x8 af[2], bg[5];
#pragma unroll
      for (int i = 0; i < 2; ++i)
        af[i] = *reinterpret_cast<const bf16x8*>(W1p + (size_t)i * 16 * 256 + ks * 32);
#pragma unroll
      for (int j = 0; j < 5; ++j)
        bg[j] = *reinterpret_cast<const bf16x8*>(&As[ks * 2560 + (j * 16 + ml) * 32 + swz]);
#pragma unroll
      for (int i = 0; i < 2; ++i)
#pragma unroll
        for (int j = 0; j < 5; ++j)
          acc1[i][j] = __builtin_amdgcn_mfma_f32_16x16x32_bf16(af[i], bg[j], acc1[i][j], 0, 0, 0);
    }
    __builtin_amdgcn_s_setprio(0);

    __syncthreads();   // previous GEMM2 readers of Hs are done

#pragma unroll
    for (int i = 0; i < 2; ++i) {
      float4 bv = *reinterpret_cast<const float4*>(b1 + kb * 256 + w * 32 + i * 16 + quad * 4);
      int c  = i * 2 + (quad >> 1);
      int lo = (quad & 1) * 4;
#pragma unroll
      for (int j = 0; j < 5; ++j) {
        int seqrow = j * 16 + ml;
        int chsw = c ^ ((ml >> 1) & 3);
        int addr = w * 2560 + seqrow * 32 + (chsw << 3) + lo;
        float t0 = acc1[i][j][0] + bv.x; t0 = t0 > 0.f ? t0 : 0.f;
        float t1 = acc1[i][j][1] + bv.y; t1 = t1 > 0.f ? t1 : 0.f;
        float t2 = acc1[i][j][2] + bv.z; t2 = t2 > 0.f ? t2 : 0.f;
        float t3 = acc1[i][j][3] + bv.w; t3 = t3 > 0.f ? t3 : 0.f;
        ushort4 hv;
        hv.x = f2bf(t0); hv.y = f2bf(t1); hv.z = f2bf(t2); hv.w = f2bf(t3);
        *reinterpret_cast<ushort4*>(&Hs[addr]) = hv;
      }
    }
    __syncthreads();   // Hs visible to all waves

    const unsigned short* W2p = W2 + (size_t)(w * 32 + ml) * 1024 + kb * 256 + quad * 8;
    __builtin_amdgcn_s_setprio(1);
#pragma unroll 2
    for (int ks = 0; ks < 8; ++ks) {
      bf16x8 af[5], bg[2];
#pragma unroll
      for (int i = 0; i < 5; ++i)
        af[i] = *reinterpret_cast<const bf16x8*>(&Hs[ks * 2560 + (i * 16 + ml) * 32 + swz]);
#pragma unroll
      for (int j = 0; j < 2; ++j)
        bg[j] = *reinterpret_cast<const bf16x8*>(W2p + (size_t)j * 16 * 1024 + ks * 32);
#pragma unroll
      for (int i = 0; i < 5; ++i)
#pragma unroll
        for (int j = 0; j < 2; ++j)
          acc2[i][j] = __builtin_amdgcn_mfma_f32_16x16x32_bf16(af[i], bg[j], acc2[i][j], 0, 0, 0);
    }
    __builtin_amdgcn_s_setprio(0);
  }

  __syncthreads();   // all Hs reads done -> reuse Hs as LN scratch
  float* sS = reinterpret_cast<float*>(Hs);   // [8][80]
  float* sQ = sS + 640;                        // [8][80]

  float b2v[2], gv[2], btv[2];
#pragma unroll
  for (int j = 0; j < 2; ++j) {
    int col = w * 32 + j * 16 + ml;
    b2v[j] = b2[col]; gv[j] = gam[col]; btv[j] = bet[col];
  }

  // bias + residual (from As LDS) + per-row partial stats over this wave's 32 cols
#pragma unroll
  for (int i = 0; i < 5; ++i)
#pragma unroll
    for (int r = 0; r < 4; ++r) {
      int row = i * 16 + quad * 4 + r;
      float s = 0.f, s2 = 0.f;
#pragma unroll
      for (int j = 0; j < 2; ++j) {
        int c_r = j * 2 + (ml >> 3);
        float t = acc2[i][j][r] + b2v[j] +
                  bf2f(As[w * 2560 + row * 32 + ((c_r ^ ((row >> 1) & 3)) << 3) + (ml & 7)]);
        acc2[i][j][r] = t;
        s += t; s2 += t * t;
      }
#pragma unroll
      for (int o = 1; o < 16; o <<= 1) { s += __shfl_xor(s, o); s2 += __shfl_xor(s2, o); }
      if (ml == 0) { sS[w * 80 + row] = s; sQ[w * 80 + row] = s2; }
    }
  __syncthreads();

#pragma unroll
  for (int i = 0; i < 5; ++i)
#pragma unroll
    for (int r = 0; r < 4; ++r) {
      int row = i * 16 + quad * 4 + r;
      int rg = m0 + row;
      if (rg >= M) continue;
      float s = 0.f, s2 = 0.f;
#pragma unroll
      for (int ww = 0; ww < 8; ++ww) { s += sS[ww * 80 + row]; s2 += sQ[ww * 80 + row]; }
      float mean = s * (1.f / 256.f);
      float var  = s2 * (1.f / 256.f) - mean * mean;
      float inv  = rsqrtf(var + 1e-5f);
#pragma unroll
      for (int j = 0; j < 2; ++j) {
        int col = w * 32 + j * 16 + ml;
        A[(size_t)rg * 256 + col] = f2bf((acc2[i][j][r] - mean) * inv * gv[j] + btv[j]);
      }
    }
}

// ---------------- transformer pieces (bf16 activations, dense layouts) ----------------

__global__ void k_seqbuild(const unsigned short* __restrict__ x1,
                           const unsigned short* __restrict__ x2,
                           const float* __restrict__ cls, const float* __restrict__ pos,
                           unsigned short* __restrict__ seqc, int n0, int cn) {
  int idx = blockIdx.x * blockDim.x + threadIdx.x;
  int total = cn * 3 * DD;
  if (idx >= total) return;
  int c = idx & (DD - 1);
  int r = idx >> 8;
  int t = r % 3, ln = r / 3;
  int n = n0 + ln;
  float v;
  if (t == 0)      v = cls[c];
  else if (t == 1) v = bf2f(x1[(size_t)n * DD + c]);
  else             v = bf2f(x2[(size_t)n * DD + c]);
  seqc[idx] = f2bf(v + pos[t * DD + c]);
}

__global__ __launch_bounds__(256) void k_final(const unsigned short* __restrict__ seqc,
                                               int n0, int cn,
                                               const float* __restrict__ g,
                                               const float* __restrict__ b,
                                               float* __restrict__ out) {
  int ln = blockIdx.x * 4 + (threadIdx.x >> 6);
  if (ln >= cn) return;
  int lane = threadIdx.x & 63;
  const unsigned short* p = seqc + (size_t)ln * 3 * DD;   // token 0 row
  float v[4];
  float s = 0.f, s2 = 0.f;
#pragma unroll
  for (int i = 0; i < 4; ++i) {
    v[i] = bf2f(p[i * 64 + lane]);
    s += v[i]; s2 += v[i] * v[i];
  }
  for (int off = 32; off; off >>= 1) { s += __shfl_xor(s, off); s2 += __shfl_xor(s2, off); }
  float mean = s * (1.f / 256.f);
  float var  = s2 * (1.f / 256.f) - mean * mean;
  float inv  = rsqrtf(var + 1e-5f);
#pragma unroll
  for (int i = 0; i < 4; ++i) {
    int c = i * 64 + lane;
    out[(size_t)(n0 + ln) * DD + c] = (v[i] - mean) * inv * g[c] + b[c];
  }
}

// ---------------- host ----------------

extern "C" void kernel_launch(void* const* d_in, const int* in_sizes, int n_in,
                              void* d_out, int out_size, void* d_ws, size_t ws_size,
                              hipStream_t stream) {
  const float* x       = (const float*)d_in[0];
  const int*   ei      = (const int*)d_in[1];
  const float* gat1_W  = (const float*)d_in[2];
  const float* gat1_b  = (const float*)d_in[3];
  const float* gat1_as = (const float*)d_in[4];
  const float* gat1_ad = (const float*)d_in[5];
  const float* gat2_W  = (const float*)d_in[6];
  const float* gat2_b  = (const float*)d_in[7];
  const float* gat2_as = (const float*)d_in[8];
  const float* gat2_ad = (const float*)d_in[9];
  const float* cls     = (const float*)d_in[10];
  const float* pos     = (const float*)d_in[11];
  const float* Wqkv    = (const float*)d_in[12];
  const float* bqkv    = (const float*)d_in[13];
  const float* Wo      = (const float*)d_in[14];
  const float* bo      = (const float*)d_in[15];
  const float* ln1_g   = (const float*)d_in[16];
  const float* ln1_b   = (const float*)d_in[17];
  const float* ln2_g   = (const float*)d_in[18];
  const float* ln2_b   = (const float*)d_in[19];
  const float* Wff1    = (const float*)d_in[20];
  const float* bff1    = (const float*)d_in[21];
  const float* Wff2    = (const float*)d_in[22];
  const float* bff2    = (const float*)d_in[23];
  const float* norm_g  = (const float*)d_in[24];
  const float* norm_b  = (const float*)d_in[25];
  float* out = (float*)d_out;

  char* ws = (char*)d_ws;
  size_t off = 0;
  auto alloc = [&](size_t bytes) -> void* {
    off = (off + 255) & ~(size_t)255;
    void* p = ws + off;
    off += bytes;
    return p;
  };

  unsigned short* wb_g1  = (unsigned short*)alloc(sizeof(unsigned short) * 256 * 128);
  unsigned short* wb_g2  = (unsigned short*)alloc(sizeof(unsigned short) * 256 * 256);
  unsigned short* wb_qkv = (unsigned short*)alloc(sizeof(unsigned short) * 2 * 768 * 256);
  unsigned short* wb_o   = (unsigned short*)alloc(sizeof(unsigned short) * 2 * 256 * 256);
  unsigned short* wb_f1  = (unsigned short*)alloc(sizeof(unsigned short) * 2 * 1024 * 256);
  unsigned short* wb_f2  = (unsigned short*)alloc(sizeof(unsigned short) * 2 * 256 * 1024);
  unsigned short* xb  = (unsigned short*)alloc(sizeof(unsigned short) * (size_t)NN * DIN);
  unsigned short* hb  = (unsigned short*)alloc(sizeof(unsigned short) * (size_t)NN * DD);
  unsigned short* x1b = (unsigned short*)alloc(sizeof(unsigned short) * (size_t)NN * DD);
  unsigned short* x2b = (unsigned short*)alloc(sizeof(unsigned short) * (size_t)NN * DD);
  float* hs  = (float*)alloc(sizeof(float) * NN);
  float* hd  = (float*)alloc(sizeof(float) * NN);
  int* deg   = (int*)alloc(sizeof(int) * NN);
  int* inc   = (int*)alloc(sizeof(int) * NN);
  int* cur   = (int*)alloc(sizeof(int) * NN);
  int* tsum  = (int*)alloc(sizeof(int) * 64);
  int* ssrc  = (int*)alloc(sizeof(int) * E2);

  // transformer chunking (fewer chunks -> fewer dispatches; qkvb stays L3-resident)
  size_t fixed = (off + 255) & ~(size_t)255;
  size_t rem = (ws_size > fixed + 4096) ? (ws_size - fixed - 4096) : 0;
  const size_t per_node = (size_t)3 * (256 + 768) * 2;
  size_t cn_max = rem / per_node;
  if (cn_max < 1) cn_max = 1;
  if (cn_max > 25000) cn_max = 25000;
  int nc = (int)((NN + cn_max - 1) / cn_max);
  int cn = (NN + nc - 1) / nc;
  unsigned short* seqc = (unsigned short*)alloc(sizeof(unsigned short) * (size_t)3 * cn * 256);
  unsigned short* qkvb = (unsigned short*)alloc(sizeof(unsigned short) * (size_t)3 * cn * 768);

  // ---- casts ----
  auto cast = [&](const float* src, unsigned short* dst, int n) {
    k_cast<<<(n + 255) / 256, 256, 0, stream>>>(src, dst, n);
  };
  cast(gat1_W, wb_g1, 256 * 128);
  cast(gat2_W, wb_g2, 256 * 256);
  cast(Wqkv, wb_qkv, 2 * 768 * 256);
  cast(Wo, wb_o, 2 * 256 * 256);
  cast(Wff1, wb_f1, 2 * 1024 * 256);
  cast(Wff2, wb_f2, 2 * 256 * 1024);
  cast(x, xb, NN * DIN);

  // ---- CSR build ----
  hipMemsetAsync(deg, 0, sizeof(int) * NN, stream);
  hipMemsetAsync(cur, 0, sizeof(int) * NN, stream);
  k_deg<<<(E2 + 255) / 256, 256, 0, stream>>>(ei, deg);
  int nb = (NN + 1023) / 1024;
  k_scan_tile<<<nb, 1024, 0, stream>>>(deg, inc, tsum, NN);
  k_scan_sums<<<1, 64, 0, stream>>>(tsum, nb);
  k_scan_add<<<(NN + 255) / 256, 256, 0, stream>>>(inc, tsum, NN);
  k_scatter<<<(E2 + 255) / 256, 256, 0, stream>>>(ei, deg, inc, cur, ssrc);

  // ---- GAT layer 1: hb = xb @ W1^T (K=128) + fused dots ----
  k_gemmD<<<(NN + 79) / 80, 512, 0, stream>>>(xb, wb_g1, hb, gat1_as, gat1_ad,
                                              hs, hd, NN, 128);
  k_gat<<<(NN + 3) / 4, 256, 0, stream>>>(hb, ssrc, deg, inc, hs, hd, gat1_b, x1b);

  // ---- GAT layer 2: hb = x1b @ W2^T (K=256) + fused dots ----
  k_gemmD<<<(NN + 79) / 80, 512, 0, stream>>>(x1b, wb_g2, hb, gat2_as, gat2_ad,
                                              hs, hd, NN, 256);
  k_gat<<<(NN + 3) / 4, 256, 0, stream>>>(hb, ssrc, deg, inc, hs, hd, gat2_b, x2b);

  // ---- transformer (chunked) ----
  for (int n0 = 0; n0 < NN; n0 += cn) {
    int c = NN - n0 < cn ? NN - n0 : cn;
    int Mch = 3 * c;
    int mblk48 = (Mch + 47) / 48;
    int mblk80 = (Mch + 79) / 80;
    k_seqbuild<<<(c * 3 * DD + 255) / 256, 256, 0, stream>>>(x1b, x2b, cls, pos, seqc, n0, c);
    for (int l = 0; l < 2; ++l) {
      // qkv: N=768, K=256 via k_ff-structure GEMM (raw q|k|v + bias)
      k_gemmT<<<mblk80, 512, 0, stream>>>(
          seqc, wb_qkv + (size_t)l * 768 * 256, bqkv + l * 768, qkvb, Mch, 768, 256);
      // fused attention + o-proj + residual + ln1 (Wo streamed, vectorized attn)
      k_oproj<<<mblk48, 256, 0, stream>>>(
          qkvb, wb_o + (size_t)l * 256 * 256, bo + l * 256,
          ln1_g + l * 256, ln1_b + l * 256, seqc, Mch);
      // fused ff1+relu+ff2+residual+ln2 (no global intermediate), 80-row tiles
      k_ff<<<mblk80, 512, 0, stream>>>(
          seqc, wb_f1 + (size_t)l * 1024 * 256, bff1 + l * 1024,
          wb_f2 + (size_t)l * 256 * 1024, bff2 + l * 256,
          ln2_g + l * 256, ln2_b + l * 256, Mch);
    }
    k_final<<<(c + 3) / 4, 256, 0, stream>>>(seqc, n0, c, norm_g, norm_b, out);
  }
}

// Round 15
// 1613.200 us; speedup vs baseline: 1.4264x; 1.0004x over previous
//
#include <hip/hip_runtime.h>
#include <hip/hip_bf16.h>

#define NN  50000
#define EE  320000
#define E2  (EE + NN)
#define DIN 128
#define DD  256

typedef __attribute__((ext_vector_type(8))) short          bf16x8;
typedef __attribute__((ext_vector_type(8))) unsigned short u16x8;
typedef __attribute__((ext_vector_type(4))) float          f32x4;

// ---------------- helpers ----------------

static __device__ __forceinline__ float bf2f(unsigned short u) {
  return __builtin_bit_cast(float, (unsigned)u << 16);
}

static __device__ __forceinline__ unsigned short f2bf(float f) {
  unsigned u = __builtin_bit_cast(unsigned, f);
  return (unsigned short)((u + 0x7fffu + ((u >> 16) & 1u)) >> 16);
}

static __device__ __forceinline__ void load_lds16(const void* g, void* l) {
  __builtin_amdgcn_global_load_lds(
      (const __attribute__((address_space(1))) void*)g,
      (__attribute__((address_space(3))) void*)l, 16, 0, 0);
}

// ---------------- weight/activation cast fp32 -> bf16 ----------------

__global__ void k_cast(const float* __restrict__ in, unsigned short* __restrict__ out, int n) {
  int i = blockIdx.x * blockDim.x + threadIdx.x;
  if (i >= n) return;
  out[i] = f2bf(in[i]);
}

// ---------------- CSR build ----------------

__global__ void k_deg(const int* __restrict__ ei, int* __restrict__ deg) {
  int i = blockIdx.x * blockDim.x + threadIdx.x;
  if (i >= E2) return;
  int dst = (i < EE) ? ei[EE + i] : (i - EE);
  atomicAdd(&deg[dst], 1);
}

__global__ __launch_bounds__(1024) void k_scan_tile(const int* __restrict__ in,
                                                    int* __restrict__ out,
                                                    int* __restrict__ tsum, int n) {
  __shared__ int sm[1024];
  int tid = threadIdx.x;
  int g = blockIdx.x * 1024 + tid;
  sm[tid] = (g < n) ? in[g] : 0;
  __syncthreads();
  for (int off = 1; off < 1024; off <<= 1) {
    int t = (tid >= off) ? sm[tid - off] : 0;
    __syncthreads();
    sm[tid] += t;
    __syncthreads();
  }
  if (g < n) out[g] = sm[tid];
  if (tid == 1023) tsum[blockIdx.x] = sm[1023];
}

__global__ void k_scan_sums(int* __restrict__ tsum, int nb) {
  int tid = threadIdx.x;           // single wave of 64, nb <= 64
  int v = (tid < nb) ? tsum[tid] : 0;
  for (int off = 1; off < 64; off <<= 1) {
    int t = __shfl_up(v, off);
    if (tid >= off) v += t;
  }
  if (tid < nb) tsum[tid] = v;
}

__global__ void k_scan_add(int* __restrict__ out, const int* __restrict__ tsum, int n) {
  int g = blockIdx.x * blockDim.x + threadIdx.x;
  if (g >= n || g < 1024) return;
  out[g] += tsum[(g >> 10) - 1];
}

__global__ void k_scatter(const int* __restrict__ ei, const int* __restrict__ deg,
                          const int* __restrict__ inc, int* __restrict__ cur,
                          int* __restrict__ ssrc) {
  int i = blockIdx.x * blockDim.x + threadIdx.x;
  if (i >= E2) return;
  int src, dst;
  if (i < EE) { src = ei[i]; dst = ei[EE + i]; } else { src = dst = i - EE; }
  int pos = atomicAdd(&cur[dst], 1);
  ssrc[inc[dst] - deg[dst] + pos] = src;
}

// ---------------- GAT pieces (h in bf16) ----------------

// Fused edge-softmax + aggregation: one wave per dst node.
__global__ __launch_bounds__(256) void k_gat(const unsigned short* __restrict__ hb,
                                             const int* __restrict__ ssrc,
                                             const int* __restrict__ deg,
                                             const int* __restrict__ inc,
                                             const float* __restrict__ hs,
                                             const float* __restrict__ hd,
                                             const float* __restrict__ bias,
                                             unsigned short* __restrict__ out) {
  __shared__ float sE[4][256];
  __shared__ int   sI[4][256];
  int w = threadIdx.x >> 6;
  int d = blockIdx.x * 4 + w;
  if (d >= NN) return;
  int lane = threadIdx.x & 63;
  int end = inc[d], cnt = deg[d], base = end - cnt;
  if (cnt > 256) cnt = 256;
  float hdd = hd[d];

  float m = -1e30f;
  for (int i0 = 0; i0 < cnt; i0 += 64) {
    int i = i0 + lane;
    float sc = -1e30f;
    if (i < cnt) {
      int s = ssrc[base + i];
      float v = hs[s] + hdd;
      sc = (v < 0.f) ? 0.2f * v : v;
      sI[w][i] = s;
      sE[w][i] = sc;
    }
    float mm = sc;
    for (int o = 32; o; o >>= 1) mm = fmaxf(mm, __shfl_xor(mm, o));
    m = fmaxf(m, mm);
  }
  float sum = 0.f;
  for (int i0 = 0; i0 < cnt; i0 += 64) {
    int i = i0 + lane;
    float e = 0.f;
    if (i < cnt) {
      e = __expf(sE[w][i] - m);
      sE[w][i] = e;
    }
    for (int o = 32; o; o >>= 1) e += __shfl_xor(e, o);
    sum += e;
  }
  float inv = 1.f / sum;

  float a0 = 0.f, a1 = 0.f, a2 = 0.f, a3 = 0.f;
  for (int i = 0; i < cnt; ++i) {
    float a = sE[w][i];
    int s = sI[w][i];
    ushort4 hv = *reinterpret_cast<const ushort4*>(hb + (size_t)s * DD + lane * 4);
    a0 += a * bf2f(hv.x);
    a1 += a * bf2f(hv.y);
    a2 += a * bf2f(hv.z);
    a3 += a * bf2f(hv.w);
  }
  const float* bp = bias + lane * 4;
  float r0 = a0 * inv + bp[0], r1 = a1 * inv + bp[1];
  float r2 = a2 * inv + bp[2], r3 = a3 * inv + bp[3];
  ushort4 o;
  o.x = f2bf(r0 > 0.f ? r0 : 0.f);
  o.y = f2bf(r1 > 0.f ? r1 : 0.f);
  o.z = f2bf(r2 > 0.f ? r2 : 0.f);
  o.w = f2bf(r3 > 0.f ? r3 : 0.f);
  *reinterpret_cast<ushort4*>(out + (size_t)d * DD + lane * 4) = o;
}

// LDS k-chunk swizzle (bank-conflict-free fragment reads):
// LDS slot (row, c) holds global k-chunk  c ^ ((row>>1)&3)  within each 32-k group.
// Fragment read of logical chunk q at row (16-aligned base + m_lane):
//   position = q ^ ((m_lane>>1)&3).  Direct-global reads use logical chunk = quad.
// Row stride MUST be 64 B ([*][32 shorts]) for conflict-free b128 reads.

// ---------------- k_ff-structure GEMM: C = A @ W^T + bias ------
// 80-row tile, 8 waves, up to 40 KB LDS (4 blocks/CU). K in {128, 256}.

__global__ __launch_bounds__(512, 4) void k_gemmT(
    const unsigned short* __restrict__ A,
    const unsigned short* __restrict__ W,
    const float* __restrict__ bias,            // [N] or null
    unsigned short* __restrict__ C,
    int M, int N, int K) {
  __shared__ unsigned short As[8 * 80 * 32];   // up to 40 KB  [kgrp][row][32]

  const int tid  = threadIdx.x;
  const int lane = tid & 63;
  const int w    = tid >> 6;        // 0..7
  const int ml   = lane & 15;
  const int quad = lane >> 4;
  const int m0   = blockIdx.x * 80;
  const int swz  = (quad ^ ((ml >> 1) & 3)) << 3;
  const int KG   = K >> 5;          // kgroups (4 or 8)

  // ---- stage A tile 80xK: wave w stages k-group w (5 rounds of 64 lanes) ----
  if (w < KG) {
#pragma unroll
    for (int r = 0; r < 5; ++r) {
      int e = r * 64 + lane;          // 0..319 within kgroup
      int row = e >> 2, ch = e & 3;
      int rg = m0 + row; if (rg >= M) rg = M - 1;
      int cs = ch ^ ((row >> 1) & 3);
      load_lds16(A + (size_t)rg * K + w * 32 + (cs << 3),
                 As + (size_t)(w * 320 + r * 64) * 8);   // HW adds lane*16B
    }
  }
  __syncthreads();

  const int nkb = N >> 8;
  for (int kb = 0; kb < nkb; ++kb) {
    f32x4 acc1[2][5] = {};
    const unsigned short* Wp = W + (size_t)(kb * 256 + w * 32 + ml) * K + quad * 8;
    __builtin_amdgcn_s_setprio(1);
#pragma unroll 2
    for (int ks = 0; ks < KG; ++ks) {
      bf16x8 af[2], bg[5];
#pragma unroll
      for (int i = 0; i < 2; ++i)
        af[i] = *reinterpret_cast<const bf16x8*>(Wp + (size_t)i * 16 * K + ks * 32);
#pragma unroll
      for (int j = 0; j < 5; ++j)
        bg[j] = *reinterpret_cast<const bf16x8*>(&As[ks * 2560 + (j * 16 + ml) * 32 + swz]);
#pragma unroll
      for (int i = 0; i < 2; ++i)
#pragma unroll
        for (int j = 0; j < 5; ++j)
          acc1[i][j] = __builtin_amdgcn_mfma_f32_16x16x32_bf16(af[i], bg[j], acc1[i][j], 0, 0, 0);
    }
    __builtin_amdgcn_s_setprio(0);

    // bias + global store (4 consecutive cols per lane = 8 B)
#pragma unroll
    for (int i = 0; i < 2; ++i) {
      int colb = kb * 256 + w * 32 + i * 16 + quad * 4;
      float4 bv = make_float4(0.f, 0.f, 0.f, 0.f);
      if (bias) bv = *reinterpret_cast<const float4*>(bias + colb);
#pragma unroll
      for (int j = 0; j < 5; ++j) {
        int rg = m0 + j * 16 + ml;
        if (rg < M) {
          ushort4 hv;
          hv.x = f2bf(acc1[i][j][0] + bv.x);
          hv.y = f2bf(acc1[i][j][1] + bv.y);
          hv.z = f2bf(acc1[i][j][2] + bv.z);
          hv.w = f2bf(acc1[i][j][3] + bv.w);
          *reinterpret_cast<ushort4*>(C + (size_t)rg * N + colb) = hv;
        }
      }
    }
  }
}

// ---------------- 128-row k_ff-structure GEMM, K=256 (qkv path) ------
// 8 j-frags per wave: MFMA:W-load ratio 8:1 (vs 5:1), 37% fewer blocks ->
// less W re-streaming. 64 KB LDS -> 2 blocks/CU. No inner barriers, so
// higher per-wave ILP applies (unlike barrier-bound k_ff where it was null).

__global__ __launch_bounds__(512, 2) void k_gemmT8(
    const unsigned short* __restrict__ A,
    const unsigned short* __restrict__ W,
    const float* __restrict__ bias,            // [N] or null
    unsigned short* __restrict__ C,
    int M, int N) {                            // K = 256 fixed
  __shared__ unsigned short As[8 * 128 * 32];  // 64 KB  [kgrp][row][32]

  const int tid  = threadIdx.x;
  const int lane = tid & 63;
  const int w    = tid >> 6;        // 0..7
  const int ml   = lane & 15;
  const int quad = lane >> 4;
  const int m0   = blockIdx.x * 128;
  const int swz  = (quad ^ ((ml >> 1) & 3)) << 3;

  // ---- stage A tile 128x256: wave w stages k-group w (8 rounds of 64 lanes) ----
#pragma unroll
  for (int r = 0; r < 8; ++r) {
    int e = r * 64 + lane;            // 0..511 within kgroup
    int row = e >> 2, ch = e & 3;
    int rg = m0 + row; if (rg >= M) rg = M - 1;
    int cs = ch ^ ((row >> 1) & 3);
    load_lds16(A + (size_t)rg * 256 + w * 32 + (cs << 3),
               As + (size_t)(w * 512 + r * 64) * 8);     // HW adds lane*16B
  }
  __syncthreads();

  const int nkb = N >> 8;
  for (int kb = 0; kb < nkb; ++kb) {
    f32x4 acc1[2][8] = {};
    const unsigned short* Wp = W + (size_t)(kb * 256 + w * 32 + ml) * 256 + quad * 8;
    __builtin_amdgcn_s_setprio(1);
#pragma unroll 2
    for (int ks = 0; ks < 8; ++ks) {
      bf16x8 af[2], bg[8];
#pragma unroll
      for (int i = 0; i < 2; ++i)
        af[i] = *reinterpret_cast<const bf16x8*>(Wp + (size_t)i * 16 * 256 + ks * 32);
#pragma unroll
      for (int j = 0; j < 8; ++j)
        bg[j] = *reinterpret_cast<const bf16x8*>(&As[ks * 4096 + (j * 16 + ml) * 32 + swz]);
#pragma unroll
      for (int i = 0; i < 2; ++i)
#pragma unroll
        for (int j = 0; j < 8; ++j)
          acc1[i][j] = __builtin_amdgcn_mfma_f32_16x16x32_bf16(af[i], bg[j], acc1[i][j], 0, 0, 0);
    }
    __builtin_amdgcn_s_setprio(0);

    // bias + global store (4 consecutive cols per lane = 8 B)
#pragma unroll
    for (int i = 0; i < 2; ++i) {
      int colb = kb * 256 + w * 32 + i * 16 + quad * 4;
      float4 bv = make_float4(0.f, 0.f, 0.f, 0.f);
      if (bias) bv = *reinterpret_cast<const float4*>(bias + colb);
#pragma unroll
      for (int j = 0; j < 8; ++j) {
        int rg = m0 + j * 16 + ml;
        if (rg < M) {
          ushort4 hv;
          hv.x = f2bf(acc1[i][j][0] + bv.x);
          hv.y = f2bf(acc1[i][j][1] + bv.y);
          hv.z = f2bf(acc1[i][j][2] + bv.z);
          hv.w = f2bf(acc1[i][j][3] + bv.w);
          *reinterpret_cast<ushort4*>(C + (size_t)rg * N + colb) = hv;
        }
      }
    }
  }
}

// ---------------- GAT projection GEMM + fused attention-dot epilogue ----------

__global__ __launch_bounds__(512, 4) void k_gemmD(
    const unsigned short* __restrict__ A,
    const unsigned short* __restrict__ W,
    unsigned short* __restrict__ C,            // hb [M x 256]
    const float* __restrict__ asrc, const float* __restrict__ adst,
    float* __restrict__ hs, float* __restrict__ hd,
    int M, int K) {
  __shared__ unsigned short As[8 * 80 * 32];   // up to 40 KB

  const int tid  = threadIdx.x;
  const int lane = tid & 63;
  const int w    = tid >> 6;
  const int ml   = lane & 15;
  const int quad = lane >> 4;
  const int m0   = blockIdx.x * 80;
  const int swz  = (quad ^ ((ml >> 1) & 3)) << 3;
  const int KG   = K >> 5;

  if (w < KG) {
#pragma unroll
    for (int r = 0; r < 5; ++r) {
      int e = r * 64 + lane;
      int row = e >> 2, ch = e & 3;
      int rg = m0 + row; if (rg >= M) rg = M - 1;
      int cs = ch ^ ((row >> 1) & 3);
      load_lds16(A + (size_t)rg * K + w * 32 + (cs << 3),
                 As + (size_t)(w * 320 + r * 64) * 8);
    }
  }
  __syncthreads();

  f32x4 acc1[2][5] = {};
  const unsigned short* Wp = W + (size_t)(w * 32 + ml) * K + quad * 8;
#pragma unroll 2
  for (int ks = 0; ks < KG; ++ks) {
    bf16x8 af[2], bg[5];
#pragma unroll
    for (int i = 0; i < 2; ++i)
      af[i] = *reinterpret_cast<const bf16x8*>(Wp + (size_t)i * 16 * K + ks * 32);
#pragma unroll
    for (int j = 0; j < 5; ++j)
      bg[j] = *reinterpret_cast<const bf16x8*>(&As[ks * 2560 + (j * 16 + ml) * 32 + swz]);
#pragma unroll
    for (int i = 0; i < 2; ++i)
#pragma unroll
      for (int j = 0; j < 5; ++j)
        acc1[i][j] = __builtin_amdgcn_mfma_f32_16x16x32_bf16(af[i], bg[j], acc1[i][j], 0, 0, 0);
  }

  // store + per-lane partial dots over this lane's 8 cols
  float s1[5] = {0.f, 0.f, 0.f, 0.f, 0.f};
  float s2[5] = {0.f, 0.f, 0.f, 0.f, 0.f};
#pragma unroll
  for (int i = 0; i < 2; ++i) {
    int colb = w * 32 + i * 16 + quad * 4;
    float4 av = *reinterpret_cast<const float4*>(asrc + colb);
    float4 dv = *reinterpret_cast<const float4*>(adst + colb);
#pragma unroll
    for (int j = 0; j < 5; ++j) {
      int rg = m0 + j * 16 + ml;
      if (rg < M) {
        ushort4 hv;
        hv.x = f2bf(acc1[i][j][0]);
        hv.y = f2bf(acc1[i][j][1]);
        hv.z = f2bf(acc1[i][j][2]);
        hv.w = f2bf(acc1[i][j][3]);
        *reinterpret_cast<ushort4*>(C + (size_t)rg * 256 + colb) = hv;
      }
      s1[j] += acc1[i][j][0] * av.x + acc1[i][j][1] * av.y +
               acc1[i][j][2] * av.z + acc1[i][j][3] * av.w;
      s2[j] += acc1[i][j][0] * dv.x + acc1[i][j][1] * dv.y +
               acc1[i][j][2] * dv.z + acc1[i][j][3] * dv.w;
    }
  }
#pragma unroll
  for (int j = 0; j < 5; ++j) {
    s1[j] += __shfl_xor(s1[j], 16); s1[j] += __shfl_xor(s1[j], 32);
    s2[j] += __shfl_xor(s2[j], 16); s2[j] += __shfl_xor(s2[j], 32);
  }
  __syncthreads();   // all As reads done -> reuse as float scratch
  float* sS = reinterpret_cast<float*>(As);   // [8][80]
  float* sQ = sS + 640;
  if (quad == 0) {
#pragma unroll
    for (int j = 0; j < 5; ++j) {
      int row = j * 16 + ml;
      sS[w * 80 + row] = s1[j];
      sQ[w * 80 + row] = s2[j];
    }
  }
  __syncthreads();
  if (tid < 80) {
    int rg = m0 + tid;
    if (rg < M) {
      float a = 0.f, b = 0.f;
#pragma unroll
      for (int ww = 0; ww < 8; ++ww) { a += sS[ww * 80 + tid]; b += sQ[ww * 80 + tid]; }
      hs[rg] = a; hd[rg] = b;
    }
  }
}

// ---------------- fused attention + o-proj + bias + residual + LayerNorm ----------
// 48-row blocks = 16 nodes, 256 thr / 4 waves. Vectorized phase 1 (lane owns
// 4 consecutive cols across all heads); phase 2 streams Wo from L2.

__global__ __launch_bounds__(256) void k_oproj(
    const unsigned short* __restrict__ qkvb,   // [M x 768] raw q|k|v
    const unsigned short* __restrict__ Wo,     // [256 x 256]
    const float* __restrict__ bo,
    const float* __restrict__ gam, const float* __restrict__ bet,
    unsigned short* __restrict__ seqc,         // residual in / out, [M x 256]
    int M) {
  __shared__ unsigned short As[8 * 48 * 32];   // 24 KB attention-out, [kgrp][row][32]
  __shared__ float sSum[4 * 48];
  __shared__ float sSq[4 * 48];

  const int tid  = threadIdx.x;
  const int lane = tid & 63;
  const int w    = tid >> 6;
  const int ml   = lane & 15;
  const int quad = lane >> 4;
  const int m0   = blockIdx.x * 48;
  const int swz  = (quad ^ ((ml >> 1) & 3)) * 8;

  // ---- phase 1: attention, lane owns 4 consecutive cols across all heads ----
  const int c0 = lane * 4;
  for (int i = 0; i < 4; ++i) {
    int r0 = (w * 4 + i) * 3;                  // local row of token 0
    size_t rowg[3];
#pragma unroll
    for (int t = 0; t < 3; ++t) {
      int rg = m0 + r0 + t;
      rowg[t] = (size_t)(rg < M ? rg : M - 1);
    }
    float q[3][4], k[3][4], v[3][4];
#pragma unroll
    for (int t = 0; t < 3; ++t) {
      size_t base = rowg[t] * 768 + c0;
      ushort4 uq = *reinterpret_cast<const ushort4*>(qkvb + base);
      ushort4 uk = *reinterpret_cast<const ushort4*>(qkvb + base + 256);
      ushort4 uv = *reinterpret_cast<const ushort4*>(qkvb + base + 512);
      q[t][0] = bf2f(uq.x); q[t][1] = bf2f(uq.y); q[t][2] = bf2f(uq.z); q[t][3] = bf2f(uq.w);
      k[t][0] = bf2f(uk.x); k[t][1] = bf2f(uk.y); k[t][2] = bf2f(uk.z); k[t][3] = bf2f(uk.w);
      v[t][0] = bf2f(uv.x); v[t][1] = bf2f(uv.y); v[t][2] = bf2f(uv.z); v[t][3] = bf2f(uv.w);
    }
    float lg[3][3];
#pragma unroll
    for (int a = 0; a < 3; ++a)
#pragma unroll
      for (int b = 0; b < 3; ++b) {
        float p = q[a][0] * k[b][0] + q[a][1] * k[b][1] +
                  q[a][2] * k[b][2] + q[a][3] * k[b][3];
        p += __shfl_xor(p, 1);
        p += __shfl_xor(p, 2);
        p += __shfl_xor(p, 4);
        p += __shfl_xor(p, 8);     // sum over 16-lane head-group
        lg[a][b] = p * 0.125f;
      }
#pragma unroll
    for (int a = 0; a < 3; ++a) {
      float mx = fmaxf(lg[a][0], fmaxf(lg[a][1], lg[a][2]));
      float e0 = __expf(lg[a][0] - mx);
      float e1 = __expf(lg[a][1] - mx);
      float e2 = __expf(lg[a][2] - mx);
      float inv = 1.f / (e0 + e1 + e2);
      int row = r0 + a;
      int g = lane >> 3;               // (4*lane)>>5
      int cch = (lane >> 1) & 3;       // ((4*lane)>>3)&3
      int addr = (g * 48 + row) * 32 + ((cch ^ ((row >> 1) & 3)) << 3) + ((lane & 1) << 2);
      ushort4 hv;
      hv.x = f2bf((e0 * v[0][0] + e1 * v[1][0] + e2 * v[2][0]) * inv);
      hv.y = f2bf((e0 * v[0][1] + e1 * v[1][1] + e2 * v[2][1]) * inv);
      hv.z = f2bf((e0 * v[0][2] + e1 * v[1][2] + e2 * v[2][2]) * inv);
      hv.w = f2bf((e0 * v[0][3] + e1 * v[1][3] + e2 * v[2][3]) * inv);
      *reinterpret_cast<ushort4*>(&As[addr]) = hv;
    }
  }
  __syncthreads();   // As complete

  // ---- phase 2: GEMM [48 x 256] @ Wo^T, Wo rows streamed from L2, no barriers
  f32x4 acc[3][4] = {};
  const unsigned short* Wop = Wo + (size_t)(w * 64 + ml) * 256 + quad * 8;
  __builtin_amdgcn_s_setprio(1);
#pragma unroll 4
  for (int t = 0; t < 8; ++t) {
    bf16x8 af[3], bg[4];
#pragma unroll
    for (int i = 0; i < 3; ++i)
      af[i] = *reinterpret_cast<const bf16x8*>(&As[(t * 48 + i * 16 + ml) * 32 + swz]);
#pragma unroll
    for (int j = 0; j < 4; ++j)
      bg[j] = *reinterpret_cast<const bf16x8*>(Wop + (size_t)j * 16 * 256 + t * 32);
#pragma unroll
    for (int i = 0; i < 3; ++i)
#pragma unroll
      for (int j = 0; j < 4; ++j)
        acc[i][j] = __builtin_amdgcn_mfma_f32_16x16x32_bf16(af[i], bg[j], acc[i][j], 0, 0, 0);
  }
  __builtin_amdgcn_s_setprio(0);

  // ---- bias + residual + per-row partial stats over this wave's 64 cols ----
  float bov[4], gv[4], btv[4];
#pragma unroll
  for (int j = 0; j < 4; ++j) {
    int col = w * 64 + j * 16 + ml;
    bov[j] = bo[col]; gv[j] = gam[col]; btv[j] = bet[col];
  }

#pragma unroll
  for (int i = 0; i < 3; ++i)
#pragma unroll
    for (int r = 0; r < 4; ++r) {
      int row = i * 16 + quad * 4 + r;
      int rg = m0 + row;
      size_t rr2 = (size_t)(rg < M ? rg : M - 1);
      float s = 0.f, s2 = 0.f;
#pragma unroll
      for (int j = 0; j < 4; ++j) {
        int col = w * 64 + j * 16 + ml;
        float t = acc[i][j][r] + bov[j] + bf2f(seqc[rr2 * 256 + col]);
        acc[i][j][r] = t;
        s += t; s2 += t * t;
      }
#pragma unroll
      for (int o = 1; o < 16; o <<= 1) { s += __shfl_xor(s, o); s2 += __shfl_xor(s2, o); }
      if (ml == 0) { sSum[w * 48 + row] = s; sSq[w * 48 + row] = s2; }
    }
  __syncthreads();

#pragma unroll
  for (int i = 0; i < 3; ++i)
#pragma unroll
    for (int r = 0; r < 4; ++r) {
      int row = i * 16 + quad * 4 + r;
      int rg = m0 + row;
      if (rg >= M) continue;
      float s  = sSum[row] + sSum[48 + row] + sSum[96 + row] + sSum[144 + row];
      float s2 = sSq[row]  + sSq[48 + row]  + sSq[96 + row]  + sSq[144 + row];
      float mean = s * (1.f / 256.f);
      float var  = s2 * (1.f / 256.f) - mean * mean;
      float inv  = rsqrtf(var + 1e-5f);
#pragma unroll
      for (int j = 0; j < 4; ++j) {
        int col = w * 64 + j * 16 + ml;
        seqc[(size_t)rg * 256 + col] = f2bf((acc[i][j][r] - mean) * inv * gv[j] + btv[j]);
      }
    }
}

// ---------------- fused FFN: relu(A@W1^T+b1)@W2^T + b2 + residual(A) + LN ----------
// 80-row tile, 8 waves, 80 KB LDS -> exactly 2 co-resident blocks/CU.
// unroll 2 (unroll 4 measured SLOWER; barrier-phase-bound floor).

__global__ __launch_bounds__(512, 4) void k_ff(
    unsigned short* __restrict__ A,
    const unsigned short* __restrict__ W1,
    const float* __restrict__ b1,
    const unsigned short* __restrict__ W2,
    const float* __restrict__ b2,
    const float* __restrict__ gam, const float* __restrict__ bet,
    int M) {
  __shared__ unsigned short As[8 * 80 * 32];   // 40 KB  [kgrp][row][32]
  __shared__ unsigned short Hs[8 * 80 * 32];   // 40 KB  (reused as LN scratch)

  const int tid  = threadIdx.x;
  const int lane = tid & 63;
  const int w    = tid >> 6;        // 0..7
  const int ml   = lane & 15;
  const int quad = lane >> 4;
  const int m0   = blockIdx.x * 80;
  const int swz  = (quad ^ ((ml >> 1) & 3)) << 3;

  // ---- stage A tile 80x256: wave w stages k-group w (5 rounds of 64 lanes) ----
  {
#pragma unroll
    for (int r = 0; r < 5; ++r) {
      int e = r * 64 + lane;
      int row = e >> 2, ch = e & 3;
      int rg = m0 + row; if (rg >= M) rg = M - 1;
      int cs = ch ^ ((row >> 1) & 3);
      load_lds16(A + (size_t)rg * 256 + w * 32 + (cs << 3),
                 As + (size_t)(w * 320 + r * 64) * 8);   // HW adds lane*16B
    }
  }
  __syncthreads();

  f32x4 acc2[5][2] = {};

  for (int kb = 0; kb < 4; ++kb) {
    f32x4 acc1[2][5] = {};
    const unsigned short* W1p = W1 + (size_t)(kb * 256 + w * 32 + ml) * 256 + quad * 8;
    __builtin_amdgcn_s_setprio(1);
#pragma unroll 2
    for (int ks = 0; ks < 8; ++ks) {
      bf16x8 af[2], bg[5];
#pragma unroll
      for (int i = 0; i < 2; ++i)
        af[i] = *reinterpret_cast<const bf16x8*>(W1p + (size_t)i * 16 * 256 + ks * 32);
#pragma unroll
      for (int j = 0; j < 5; ++j)
        bg[j] = *reinterpret_cast<const bf16x8*>(&As[ks * 2560 + (j * 16 + ml) * 32 + swz]);
#pragma unroll
      for (int i = 0; i < 2; ++i)
#pragma unroll
        for (int j = 0; j < 5; ++j)
          acc1[i][j] = __builtin_amdgcn_mfma_f32_16x16x32_bf16(af[i], bg[j], acc1[i][j], 0, 0, 0);
    }
    __builtin_amdgcn_s_setprio(0);

    __syncthreads();   // previous GEMM2 readers of Hs are done

#pragma unroll
    for (int i = 0; i < 2; ++i) {
      float4 bv = *reinterpret_cast<const float4*>(b1 + kb * 256 + w * 32 + i * 16 + quad * 4);
      int c  = i * 2 + (quad >> 1);
      int lo = (quad & 1) * 4;
#pragma unroll
      for (int j = 0; j < 5; ++j) {
        int seqrow = j * 16 + ml;
        int chsw = c ^ ((ml >> 1) & 3);
        int addr = w * 2560 + seqrow * 32 + (chsw << 3) + lo;
        float t0 = acc1[i][j][0] + bv.x; t0 = t0 > 0.f ? t0 : 0.f;
        float t1 = acc1[i][j][1] + bv.y; t1 = t1 > 0.f ? t1 : 0.f;
        float t2 = acc1[i][j][2] + bv.z; t2 = t2 > 0.f ? t2 : 0.f;
        float t3 = acc1[i][j][3] + bv.w; t3 = t3 > 0.f ? t3 : 0.f;
        ushort4 hv;
        hv.x = f2bf(t0); hv.y = f2bf(t1); hv.z = f2bf(t2); hv.w = f2bf(t3);
        *reinterpret_cast<ushort4*>(&Hs[addr]) = hv;
      }
    }
    __syncthreads();   // Hs visible to all waves

    const unsigned short* W2p = W2 + (size_t)(w * 32 + ml) * 1024 + kb * 256 + quad * 8;
    __builtin_amdgcn_s_setprio(1);
#pragma unroll 2
    for (int ks = 0; ks < 8; ++ks) {
      bf16x8 af[5], bg[2];
#pragma unroll
      for (int i = 0; i < 5; ++i)
        af[i] = *reinterpret_cast<const bf16x8*>(&Hs[ks * 2560 + (i * 16 + ml) * 32 + swz]);
#pragma unroll
      for (int j = 0; j < 2; ++j)
        bg[j] = *reinterpret_cast<const bf16x8*>(W2p + (size_t)j * 16 * 1024 + ks * 32);
#pragma unroll
      for (int i = 0; i < 5; ++i)
#pragma unroll
        for (int j = 0; j < 2; ++j)
          acc2[i][j] = __builtin_amdgcn_mfma_f32_16x16x32_bf16(af[i], bg[j], acc2[i][j], 0, 0, 0);
    }
    __builtin_amdgcn_s_setprio(0);
  }

  __syncthreads();   // all Hs reads done -> reuse Hs as LN scratch
  float* sS = reinterpret_cast<float*>(Hs);   // [8][80]
  float* sQ = sS + 640;                        // [8][80]

  float b2v[2], gv[2], btv[2];
#pragma unroll
  for (int j = 0; j < 2; ++j) {
    int col = w * 32 + j * 16 + ml;
    b2v[j] = b2[col]; gv[j] = gam[col]; btv[j] = bet[col];
  }

  // bias + residual (from As LDS) + per-row partial stats over this wave's 32 cols
#pragma unroll
  for (int i = 0; i < 5; ++i)
#pragma unroll
    for (int r = 0; r < 4; ++r) {
      int row = i * 16 + quad * 4 + r;
      float s = 0.f, s2 = 0.f;
#pragma unroll
      for (int j = 0; j < 2; ++j) {
        int c_r = j * 2 + (ml >> 3);
        float t = acc2[i][j][r] + b2v[j] +
                  bf2f(As[w * 2560 + row * 32 + ((c_r ^ ((row >> 1) & 3)) << 3) + (ml & 7)]);
        acc2[i][j][r] = t;
        s += t; s2 += t * t;
      }
#pragma unroll
      for (int o = 1; o < 16; o <<= 1) { s += __shfl_xor(s, o); s2 += __shfl_xor(s2, o); }
      if (ml == 0) { sS[w * 80 + row] = s; sQ[w * 80 + row] = s2; }
    }
  __syncthreads();

#pragma unroll
  for (int i = 0; i < 5; ++i)
#pragma unroll
    for (int r = 0; r < 4; ++r) {
      int row = i * 16 + quad * 4 + r;
      int rg = m0 + row;
      if (rg >= M) continue;
      float s = 0.f, s2 = 0.f;
#pragma unroll
      for (int ww = 0; ww < 8; ++ww) { s += sS[ww * 80 + row]; s2 += sQ[ww * 80 + row]; }
      float mean = s * (1.f / 256.f);
      float var  = s2 * (1.f / 256.f) - mean * mean;
      float inv  = rsqrtf(var + 1e-5f);
#pragma unroll
      for (int j = 0; j < 2; ++j) {
        int col = w * 32 + j * 16 + ml;
        A[(size_t)rg * 256 + col] = f2bf((acc2[i][j][r] - mean) * inv * gv[j] + btv[j]);
      }
    }
}

// ---------------- transformer pieces (bf16 activations, dense layouts) ----------------

__global__ void k_seqbuild(const unsigned short* __restrict__ x1,
                           const unsigned short* __restrict__ x2,
                           const float* __restrict__ cls, const float* __restrict__ pos,
                           unsigned short* __restrict__ seqc, int n0, int cn) {
  int idx = blockIdx.x * blockDim.x + threadIdx.x;
  int total = cn * 3 * DD;
  if (idx >= total) return;
  int c = idx & (DD - 1);
  int r = idx >> 8;
  int t = r % 3, ln = r / 3;
  int n = n0 + ln;
  float v;
  if (t == 0)      v = cls[c];
  else if (t == 1) v = bf2f(x1[(size_t)n * DD + c]);
  else             v = bf2f(x2[(size_t)n * DD + c]);
  seqc[idx] = f2bf(v + pos[t * DD + c]);
}

__global__ __launch_bounds__(256) void k_final(const unsigned short* __restrict__ seqc,
                                               int n0, int cn,
                                               const float* __restrict__ g,
                                               const float* __restrict__ b,
                                               float* __restrict__ out) {
  int ln = blockIdx.x * 4 + (threadIdx.x >> 6);
  if (ln >= cn) return;
  int lane = threadIdx.x & 63;
  const unsigned short* p = seqc + (size_t)ln * 3 * DD;   // token 0 row
  float v[4];
  float s = 0.f, s2 = 0.f;
#pragma unroll
  for (int i = 0; i < 4; ++i) {
    v[i] = bf2f(p[i * 64 + lane]);
    s += v[i]; s2 += v[i] * v[i];
  }
  for (int off = 32; off; off >>= 1) { s += __shfl_xor(s, off); s2 += __shfl_xor(s2, off); }
  float mean = s * (1.f / 256.f);
  float var  = s2 * (1.f / 256.f) - mean * mean;
  float inv  = rsqrtf(var + 1e-5f);
#pragma unroll
  for (int i = 0; i < 4; ++i) {
    int c = i * 64 + lane;
    out[(size_t)(n0 + ln) * DD + c] = (v[i] - mean) * inv * g[c] + b[c];
  }
}

// ---------------- host ----------------

extern "C" void kernel_launch(void* const* d_in, const int* in_sizes, int n_in,
                              void* d_out, int out_size, void* d_ws, size_t ws_size,
                              hipStream_t stream) {
  const float* x       = (const float*)d_in[0];
  const int*   ei      = (const int*)d_in[1];
  const float* gat1_W  = (const float*)d_in[2];
  const float* gat1_b  = (const float*)d_in[3];
  const float* gat1_as = (const float*)d_in[4];
  const float* gat1_ad = (const float*)d_in[5];
  const float* gat2_W  = (const float*)d_in[6];
  const float* gat2_b  = (const float*)d_in[7];
  const float* gat2_as = (const float*)d_in[8];
  const float* gat2_ad = (const float*)d_in[9];
  const float* cls     = (const float*)d_in[10];
  const float* pos     = (const float*)d_in[11];
  const float* Wqkv    = (const float*)d_in[12];
  const float* bqkv    = (const float*)d_in[13];
  const float* Wo      = (const float*)d_in[14];
  const float* bo      = (const float*)d_in[15];
  const float* ln1_g   = (const float*)d_in[16];
  const float* ln1_b   = (const float*)d_in[17];
  const float* ln2_g   = (const float*)d_in[18];
  const float* ln2_b   = (const float*)d_in[19];
  const float* Wff1    = (const float*)d_in[20];
  const float* bff1    = (const float*)d_in[21];
  const float* Wff2    = (const float*)d_in[22];
  const float* bff2    = (const float*)d_in[23];
  const float* norm_g  = (const float*)d_in[24];
  const float* norm_b  = (const float*)d_in[25];
  float* out = (float*)d_out;

  char* ws = (char*)d_ws;
  size_t off = 0;
  auto alloc = [&](size_t bytes) -> void* {
    off = (off + 255) & ~(size_t)255;
    void* p = ws + off;
    off += bytes;
    return p;
  };

  unsigned short* wb_g1  = (unsigned short*)alloc(sizeof(unsigned short) * 256 * 128);
  unsigned short* wb_g2  = (unsigned short*)alloc(sizeof(unsigned short) * 256 * 256);
  unsigned short* wb_qkv = (unsigned short*)alloc(sizeof(unsigned short) * 2 * 768 * 256);
  unsigned short* wb_o   = (unsigned short*)alloc(sizeof(unsigned short) * 2 * 256 * 256);
  unsigned short* wb_f1  = (unsigned short*)alloc(sizeof(unsigned short) * 2 * 1024 * 256);
  unsigned short* wb_f2  = (unsigned short*)alloc(sizeof(unsigned short) * 2 * 256 * 1024);
  unsigned short* xb  = (unsigned short*)alloc(sizeof(unsigned short) * (size_t)NN * DIN);
  unsigned short* hb  = (unsigned short*)alloc(sizeof(unsigned short) * (size_t)NN * DD);
  unsigned short* x1b = (unsigned short*)alloc(sizeof(unsigned short) * (size_t)NN * DD);
  unsigned short* x2b = (unsigned short*)alloc(sizeof(unsigned short) * (size_t)NN * DD);
  float* hs  = (float*)alloc(sizeof(float) * NN);
  float* hd  = (float*)alloc(sizeof(float) * NN);
  int* deg   = (int*)alloc(sizeof(int) * NN);
  int* inc   = (int*)alloc(sizeof(int) * NN);
  int* cur   = (int*)alloc(sizeof(int) * NN);
  int* tsum  = (int*)alloc(sizeof(int) * 64);
  int* ssrc  = (int*)alloc(sizeof(int) * E2);

  // transformer chunking (fewer chunks -> fewer dispatches; qkvb stays L3-resident)
  size_t fixed = (off + 255) & ~(size_t)255;
  size_t rem = (ws_size > fixed + 4096) ? (ws_size - fixed - 4096) : 0;
  const size_t per_node = (size_t)3 * (256 + 768) * 2;
  size_t cn_max = rem / per_node;
  if (cn_max < 1) cn_max = 1;
  if (cn_max > 25000) cn_max = 25000;
  int nc = (int)((NN + cn_max - 1) / cn_max);
  int cn = (NN + nc - 1) / nc;
  unsigned short* seqc = (unsigned short*)alloc(sizeof(unsigned short) * (size_t)3 * cn * 256);
  unsigned short* qkvb = (unsigned short*)alloc(sizeof(unsigned short) * (size_t)3 * cn * 768);

  // ---- casts ----
  auto cast = [&](const float* src, unsigned short* dst, int n) {
    k_cast<<<(n + 255) / 256, 256, 0, stream>>>(src, dst, n);
  };
  cast(gat1_W, wb_g1, 256 * 128);
  cast(gat2_W, wb_g2, 256 * 256);
  cast(Wqkv, wb_qkv, 2 * 768 * 256);
  cast(Wo, wb_o, 2 * 256 * 256);
  cast(Wff1, wb_f1, 2 * 1024 * 256);
  cast(Wff2, wb_f2, 2 * 256 * 1024);
  cast(x, xb, NN * DIN);

  // ---- CSR build ----
  hipMemsetAsync(deg, 0, sizeof(int) * NN, stream);
  hipMemsetAsync(cur, 0, sizeof(int) * NN, stream);
  k_deg<<<(E2 + 255) / 256, 256, 0, stream>>>(ei, deg);
  int nb = (NN + 1023) / 1024;
  k_scan_tile<<<nb, 1024, 0, stream>>>(deg, inc, tsum, NN);
  k_scan_sums<<<1, 64, 0, stream>>>(tsum, nb);
  k_scan_add<<<(NN + 255) / 256, 256, 0, stream>>>(inc, tsum, NN);
  k_scatter<<<(E2 + 255) / 256, 256, 0, stream>>>(ei, deg, inc, cur, ssrc);

  // ---- GAT layer 1: hb = xb @ W1^T (K=128) + fused dots ----
  k_gemmD<<<(NN + 79) / 80, 512, 0, stream>>>(xb, wb_g1, hb, gat1_as, gat1_ad,
                                              hs, hd, NN, 128);
  k_gat<<<(NN + 3) / 4, 256, 0, stream>>>(hb, ssrc, deg, inc, hs, hd, gat1_b, x1b);

  // ---- GAT layer 2: hb = x1b @ W2^T (K=256) + fused dots ----
  k_gemmD<<<(NN + 79) / 80, 512, 0, stream>>>(x1b, wb_g2, hb, gat2_as, gat2_ad,
                                              hs, hd, NN, 256);
  k_gat<<<(NN + 3) / 4, 256, 0, stream>>>(hb, ssrc, deg, inc, hs, hd, gat2_b, x2b);

  // ---- transformer (chunked) ----
  for (int n0 = 0; n0 < NN; n0 += cn) {
    int c = NN - n0 < cn ? NN - n0 : cn;
    int Mch = 3 * c;
    int mblk48 = (Mch + 47) / 48;
    int mblk80 = (Mch + 79) / 80;
    int mblk128 = (Mch + 127) / 128;
    k_seqbuild<<<(c * 3 * DD + 255) / 256, 256, 0, stream>>>(x1b, x2b, cls, pos, seqc, n0, c);
    for (int l = 0; l < 2; ++l) {
      // qkv: N=768, K=256 via 128-row k_ff-structure GEMM (raw q|k|v + bias)
      k_gemmT8<<<mblk128, 512, 0, stream>>>(
          seqc, wb_qkv + (size_t)l * 768 * 256, bqkv + l * 768, qkvb, Mch, 768);
      // fused attention + o-proj + residual + ln1 (Wo streamed, vectorized attn)
      k_oproj<<<mblk48, 256, 0, stream>>>(
          qkvb, wb_o + (size_t)l * 256 * 256, bo + l * 256,
          ln1_g + l * 256, ln1_b + l * 256, seqc, Mch);
      // fused ff1+relu+ff2+residual+ln2 (no global intermediate), 80-row tiles
      k_ff<<<mblk80, 512, 0, stream>>>(
          seqc, wb_f1 + (size_t)l * 1024 * 256, bff1 + l * 1024,
          wb_f2 + (size_t)l * 256 * 1024, bff2 + l * 256,
          ln2_g + l * 256, ln2_b + l * 256, Mch);
    }
    k_final<<<(c + 3) / 4, 256, 0, stream>>>(seqc, n0, c, norm_g, norm_b, out);
  }
}